// Round 1
// baseline (928.054 us; speedup 1.0000x reference)
//
#include <hip/hip_runtime.h>
#include <hip/hip_bf16.h>

// Problem constants
#define Lc 256
#define Bc 64
#define Dc 1024
#define Hc 512
#define Rc 8
#define Cc 6
#define WINc 10
#define NWc 21
#define Nc (Bc*Lc)        // 16384
#define DHc (Dc+Hc)       // 1536
#define CH 8192           // RGCN chunk (32 conversations)

typedef __attribute__((ext_vector_type(8))) short short8;
typedef __attribute__((ext_vector_type(4))) float floatx4;

__device__ inline unsigned short f2b(float x) {
    __hip_bfloat16 h = __float2bfloat16(x);
    return *reinterpret_cast<unsigned short*>(&h);
}
__device__ inline float bf2f(unsigned short u) {
    __hip_bfloat16 h;
    *reinterpret_cast<unsigned short*>(&h) = u;
    return __bfloat162float(h);
}

// node id n = b*256+s  ->  feats row s*64+b
__device__ inline long remap_row(int node) { return (long)(((node & 255) << 6) + (node >> 8)); }

typedef __attribute__((address_space(3))) unsigned int lds_u32;
typedef __attribute__((address_space(1))) unsigned int glb_u32;
__device__ inline void glds16(const unsigned short* g, unsigned short* l) {
    __builtin_amdgcn_global_load_lds((const glb_u32*)g, (lds_u32*)l, 16, 0, 0);
}

// ---------------- all weight transposes in ONE launch (fp32 [K][N] -> bf16 [N][K]) ----------------
__global__ __launch_bounds__(256) void transpose_all(
    const float* __restrict__ Wscalar, const float* __restrict__ W_rel,
    const float* __restrict__ W_root, const float* __restrict__ W_nbr,
    const float* __restrict__ W_self, const float* __restrict__ W_match,
    const float* __restrict__ W_lin, unsigned short* __restrict__ WT)
{
    int t = blockIdx.x;
    const float* in; unsigned short* out; int N, ldo, n0, k0;
    if (t < 256) {                       // Wscalar [1024][256] -> [256][1024]
        in = Wscalar; out = WT; N = 256; ldo = 1024;
        n0 = (t & 7) * 32; k0 = (t >> 3) * 32;
    } else if (t < 4352) {               // W_rel 8x[1024][512] -> rows r*512..
        int u = t - 256; int r = u >> 9; u &= 511;
        in = W_rel + (long)r * 524288; out = WT + 262144 + (long)r * 524288; N = 512; ldo = 1024;
        n0 = (u & 15) * 32; k0 = (u >> 4) * 32;
    } else if (t < 4864) {               // W_root -> WrelT rows 4096..4608
        int u = t - 4352;
        in = W_root; out = WT + 262144 + 4096 * 1024; N = 512; ldo = 1024;
        n0 = (u & 15) * 32; k0 = (u >> 4) * 32;
    } else if (t < 5120) {               // W_nbr -> WgcT k 0..512
        int u = t - 4864;
        in = W_nbr; out = WT + 4980736; N = 512; ldo = 1024;
        n0 = (u & 15) * 32; k0 = (u >> 4) * 32;
    } else if (t < 5376) {               // W_self -> WgcT k 512..1024
        int u = t - 5120;
        in = W_self; out = WT + 4980736 + 512; N = 512; ldo = 1024;
        n0 = (u & 15) * 32; k0 = (u >> 4) * 32;
    } else if (t < 7680) {               // W_match [1536][1536]
        int u = t - 5376;
        in = W_match; out = WT + 5505024; N = 1536; ldo = 1536;
        n0 = (u % 48) * 32; k0 = (u / 48) * 32;
    } else {                             // W_lin [1536][512]
        int u = t - 7680;
        in = W_lin; out = WT + 7864320; N = 512; ldo = 1536;
        n0 = (u & 15) * 32; k0 = (u >> 4) * 32;
    }
    __shared__ float tt[32][33];
    int tx = threadIdx.x & 31, ty = threadIdx.x >> 5;
    #pragma unroll
    for (int i = 0; i < 4; i++) tt[ty + i * 8][tx] = in[(long)(k0 + ty + i * 8) * N + n0 + tx];
    __syncthreads();
    #pragma unroll
    for (int i = 0; i < 4; i++) out[(long)(n0 + ty + i * 8) * ldo + k0 + tx] = f2b(tt[tx][ty + i * 8]);
}

// ---------------- stable partition of each chunk's nodes by speaker ----------------
__global__ __launch_bounds__(256) void partition_kernel(const int* __restrict__ spk,
        int* __restrict__ idx, int* __restrict__ cnts)
{
    int c = blockIdx.x;
    int tid = threadIdx.x;
    int base = c * CH;
    __shared__ int zs[256];
    int zcount = 0;
    for (int i = 0; i < CH / 256; i++) {
        int n = base + tid * (CH / 256) + i;
        if (spk[(n & 255) * 64 + (n >> 8)] == 0) zcount++;
    }
    zs[tid] = zcount; __syncthreads();
    for (int off = 1; off < 256; off <<= 1) {
        int v = (tid >= off) ? zs[tid - off] : 0;
        __syncthreads();
        zs[tid] += v;
        __syncthreads();
    }
    int Z = zs[255];
    int zpos = zs[tid] - zcount;                 // exclusive zeros before my range
    int opos = tid * (CH / 256) - zpos;          // ones before my range
    for (int i = 0; i < CH / 256; i++) {
        int nl = tid * (CH / 256) + i;
        int n = base + nl;
        if (spk[(n & 255) * 64 + (n >> 8)] == 0) idx[base + (zpos++)] = nl;
        else                                     idx[base + Z + (opos++)] = nl;
    }
    if (tid == 0) cnts[c] = Z;
}

// ---------------- em[:, 0:1024) = bf16(features) in node order ----------------
__global__ __launch_bounds__(256) void build_em_x(const float* __restrict__ feats,
                                                  unsigned short* __restrict__ em)
{
    int n = blockIdx.x;
    int tid = threadIdx.x;
    const float* f = feats + remap_row(n) * Dc;
    float4 v = ((const float4*)f)[tid];
    unsigned short* e = em + (long)n * DHc + tid * 4;
    e[0] = f2b(v.x); e[1] = f2b(v.y); e[2] = f2b(v.z); e[3] = f2b(v.w);
}

// ---------------- MFMA GEMM, async staging, fragment-ordered LDS (round-7 engine) ----------------
template<bool CBF, bool CT, bool BIAS, bool RELU>
__global__ __launch_bounds__(256) void gemm_as(
    const unsigned short* __restrict__ A, const unsigned short* __restrict__ B,
    void* __restrict__ Cv, const float* __restrict__ bias,
    int K, int lda, int ldb, int ldc, long sA, long sB, long sC)
{
    __shared__ __align__(16) unsigned short As[4096];
    __shared__ __align__(16) unsigned short Bs[4096];
    const int tid = threadIdx.x;
    const int z = blockIdx.z;
    const int m0 = blockIdx.y * 128, n0 = blockIdx.x * 128;
    const int lane = tid & 63, wave = tid >> 6;
    const int q = lane >> 4, mr = lane & 15;
    const int wrow = (wave >> 1) * 64, wcol = (wave & 1) * 64;

    const unsigned short* Ag0 = A + z * sA + (long)(m0 + wave * 32 + mr) * lda + q * 8;
    const unsigned short* Ag1 = Ag0 + (long)16 * lda;
    const unsigned short* Bg0 = B + z * sB + (long)(n0 + wave * 32 + mr) * ldb + q * 8;
    const unsigned short* Bg1 = Bg0 + (long)16 * ldb;
    unsigned short* Al0 = As + wave * 1024;
    unsigned short* Bl0 = Bs + wave * 1024;

    floatx4 acc[4][4];
    #pragma unroll
    for (int mt = 0; mt < 4; mt++)
        #pragma unroll
        for (int nt = 0; nt < 4; nt++) acc[mt][nt] = (floatx4){0.f, 0.f, 0.f, 0.f};

    const int ga = (wave >> 1) * 2048;
    const int gb = (wave & 1) * 2048;

    for (int k0 = 0; k0 < K; k0 += 32) {
        glds16(Ag0 + k0, Al0);
        glds16(Ag1 + k0, Al0 + 512);
        glds16(Bg0 + k0, Bl0);
        glds16(Bg1 + k0, Bl0 + 512);
        __syncthreads();
        short8 af[4], bfr[4];
        #pragma unroll
        for (int t = 0; t < 4; t++) {
            af[t]  = *(const short8*)&As[ga + t * 512 + lane * 8];
            bfr[t] = *(const short8*)&Bs[gb + t * 512 + lane * 8];
        }
        #pragma unroll
        for (int mt = 0; mt < 4; mt++)
            #pragma unroll
            for (int nt = 0; nt < 4; nt++)
                acc[mt][nt] = __builtin_amdgcn_mfma_f32_16x16x32_bf16(af[mt], bfr[nt], acc[mt][nt], 0, 0, 0);
        __syncthreads();
    }

    float* Cf = (float*)Cv;
    unsigned short* Cb = (unsigned short*)Cv;
    #pragma unroll
    for (int mt = 0; mt < 4; mt++) {
        #pragma unroll
        for (int nt = 0; nt < 4; nt++) {
            int col = n0 + wcol + nt * 16 + mr;
            float bv = BIAS ? bias[col] : 0.f;
            #pragma unroll
            for (int rg = 0; rg < 4; rg++) {
                int row = m0 + wrow + mt * 16 + q * 4 + rg;
                float v = acc[mt][nt][rg] + bv;
                if (RELU) v = fmaxf(v, 0.f);
                if (CT) {
                    Cb[(long)(row >> 8) * 131072 + (long)col * 256 + (row & 255)] = f2b(v);
                } else {
                    long ci = z * sC + (long)row * ldc + col;
                    if (CBF) Cb[ci] = f2b(v);
                    else     Cf[ci] = v;
                }
            }
        }
    }
}

// ---------------- row-indexed GEMM for speaker-partitioned RGCN (C scatter, ldc 2560) ----------------
// A = em chunk base; rows gathered via idx[off + m]; early-exit on device count.
template<bool SP1>
__global__ __launch_bounds__(256) void gemm_idx(
    const unsigned short* __restrict__ A, const unsigned short* __restrict__ B,
    unsigned short* __restrict__ C, const int* __restrict__ idx,
    const int* __restrict__ cntp)
{
    const int cnt0 = *cntp;
    const int off  = SP1 ? cnt0 : 0;
    const int M    = SP1 ? (CH - cnt0) : cnt0;
    const int m0 = blockIdx.y * 128;
    if (m0 >= M) return;
    const int n0 = blockIdx.x * 128;
    const int tid = threadIdx.x;
    const int lane = tid & 63, wave = tid >> 6;
    const int q = lane >> 4, mr = lane & 15;
    const int wrow = (wave >> 1) * 64, wcol = (wave & 1) * 64;

    int r0 = m0 + wave * 32 + mr;
    int ar0 = idx[off + min(r0, M - 1)];
    int ar1 = idx[off + min(r0 + 16, M - 1)];
    const unsigned short* Ag0 = A + (long)ar0 * DHc + q * 8;
    const unsigned short* Ag1 = A + (long)ar1 * DHc + q * 8;
    const unsigned short* Bg0 = B + (long)(n0 + wave * 32 + mr) * 1024 + q * 8;
    const unsigned short* Bg1 = Bg0 + 16 * 1024;

    __shared__ __align__(16) unsigned short As[4096];
    __shared__ __align__(16) unsigned short Bs[4096];
    unsigned short* Al0 = As + wave * 1024;
    unsigned short* Bl0 = Bs + wave * 1024;

    floatx4 acc[4][4];
    #pragma unroll
    for (int mt = 0; mt < 4; mt++)
        #pragma unroll
        for (int nt = 0; nt < 4; nt++) acc[mt][nt] = (floatx4){0.f, 0.f, 0.f, 0.f};

    const int ga = (wave >> 1) * 2048;
    const int gb = (wave & 1) * 2048;

    for (int k0 = 0; k0 < 1024; k0 += 32) {
        glds16(Ag0 + k0, Al0);
        glds16(Ag1 + k0, Al0 + 512);
        glds16(Bg0 + k0, Bl0);
        glds16(Bg1 + k0, Bl0 + 512);
        __syncthreads();
        short8 af[4], bfr[4];
        #pragma unroll
        for (int t = 0; t < 4; t++) {
            af[t]  = *(const short8*)&As[ga + t * 512 + lane * 8];
            bfr[t] = *(const short8*)&Bs[gb + t * 512 + lane * 8];
        }
        #pragma unroll
        for (int mt = 0; mt < 4; mt++)
            #pragma unroll
            for (int nt = 0; nt < 4; nt++)
                acc[mt][nt] = __builtin_amdgcn_mfma_f32_16x16x32_bf16(af[mt], bfr[nt], acc[mt][nt], 0, 0, 0);
        __syncthreads();
    }

    #pragma unroll
    for (int mt = 0; mt < 4; mt++) {
        #pragma unroll
        for (int nt = 0; nt < 4; nt++) {
            int col = n0 + wcol + nt * 16 + mr;
            #pragma unroll
            for (int rg = 0; rg < 4; rg++) {
                int row = m0 + wrow + mt * 16 + q * 4 + rg;
                int crow = idx[off + min(row, M - 1)];
                C[(long)crow * 2560 + col] = f2b(acc[mt][nt][rg]);
            }
        }
    }
}

// ---------------- edge_norm: windowed softmax over k (scale node-ordered) ----------------
__global__ __launch_bounds__(256) void edge_norm_kernel(const float* __restrict__ scale,
                                                        float* __restrict__ enorm)
{
    int g = blockIdx.x * 256 + threadIdx.x;   // b*L + j
    int b = g >> 8, j = g & 255;
    int klo = max(0, j - WINc), khi = min(Lc - 1, j + WINc);
    float vals[NWc];
    float m = -1e30f;
    for (int k = klo; k <= khi; k++) {
        float v = scale[(long)((b << 8) + k) * Lc + j];
        vals[k - klo] = v;
        m = fmaxf(m, v);
    }
    float s = 0.f;
    for (int k = klo; k <= khi; k++) {
        float e = expf(vals[k - klo] - m);
        vals[k - klo] = e;
        s += e;
    }
    float inv = 1.f / s;
    for (int k = klo; k <= khi; k++)
        enorm[(long)g * NWc + (k - j + WINc)] = vals[k - klo] * inv;
}

// ---------------- RGCN aggregation (hall4 bf16 [CH][2560]: 4 dst-sel blocks + root) ----------------
__global__ __launch_bounds__(256) void rgcn_gather4(const unsigned short* __restrict__ hall4,
        const float* __restrict__ enorm, const int* __restrict__ spk,
        const float* __restrict__ b_rgcn, float* __restrict__ h1, int chunk_base)
{
    int nloc = blockIdx.x;
    int n = chunk_base + nloc;
    int b = n >> 8, k = n & 255;
    int tid = threadIdx.x;
    int spkk = spk[k * 64 + b];
    int jlo = max(0, k - WINc), jhi = min(Lc - 1, k + WINc);
    unsigned int ru = *(const unsigned int*)(hall4 + (long)nloc * 2560 + 2048 + 2 * tid);
    float a0 = bf2f((unsigned short)(ru & 0xffff)) + b_rgcn[2 * tid];
    float a1 = bf2f((unsigned short)(ru >> 16)) + b_rgcn[2 * tid + 1];
    int cb = spkk * 2;
    for (int j = jlo; j <= jhi; j++) {
        int c = cb + ((j < k) ? 0 : 1);
        float w = enorm[((long)((b << 8) + j)) * NWc + (k - j + WINc)];
        unsigned int u = *(const unsigned int*)(hall4 + ((long)(nloc - k + j)) * 2560 + c * 512 + 2 * tid);
        a0 += w * bf2f((unsigned short)(u & 0xffff));
        a1 += w * bf2f((unsigned short)(u >> 16));
    }
    *(float2*)&h1[(long)n * Hc + 2 * tid] = make_float2(a0, a1);
}

// ---------------- anh1 = bf16[ concat(window-sum(h1), h1) ]  [N][1024] ----------------
__global__ __launch_bounds__(256) void build_anh1(const float* __restrict__ h1,
                                                  unsigned short* __restrict__ anh1)
{
    int n = blockIdx.x;
    int b = n >> 8, k = n & 255;
    int tid = threadIdx.x;
    int jlo = max(0, k - WINc), jhi = min(Lc - 1, k + WINc);
    float a0 = 0.f, a1 = 0.f;
    for (int j = jlo; j <= jhi; j++) {
        const float* src = h1 + ((long)((b << 8) + j)) * Hc;
        a0 += src[tid];
        a1 += src[tid + 256];
    }
    unsigned short* dst = anh1 + (long)n * 1024;
    const float* self = h1 + (long)n * Hc;
    dst[tid]       = f2b(a0);
    dst[tid + 256] = f2b(a1);
    dst[tid + 512] = f2b(self[tid]);
    dst[tid + 768] = f2b(self[tid + 256]);
}

// ---------------- tanh + row softmax -> bf16 attention weights ----------------
__global__ __launch_bounds__(256) void tanh_softmax_rows(const float* __restrict__ S,
                                                         unsigned short* __restrict__ a)
{
    int row = blockIdx.x;
    int tid = threadIdx.x;
    __shared__ float red[256];
    float v = tanhf(S[(long)row * Lc + tid]);
    red[tid] = v; __syncthreads();
    for (int s = 128; s > 0; s >>= 1) { if (tid < s) red[tid] = fmaxf(red[tid], red[tid + s]); __syncthreads(); }
    float m = red[0]; __syncthreads();
    float e = expf(v - m);
    red[tid] = e; __syncthreads();
    for (int s = 128; s > 0; s >>= 1) { if (tid < s) red[tid] += red[tid + s]; __syncthreads(); }
    float sum = red[0];
    a[(long)row * Lc + tid] = f2b(e / sum);
}

// ---------------- final classifier + log_softmax (fp32 out) ----------------
__global__ __launch_bounds__(256) void out_kernel(const unsigned short* __restrict__ hidden,
        const float* __restrict__ Wfc, const float* __restrict__ bfc, float* __restrict__ out)
{
    int tid = threadIdx.x;
    int lane = tid & 63;
    int row = blockIdx.x * 4 + (tid >> 6);
    float acc[Cc] = {};
    const unsigned short* h = hidden + (long)row * Hc;
    for (int k = lane; k < Hc; k += 64) {
        float hv = bf2f(h[k]);
        #pragma unroll
        for (int c = 0; c < Cc; c++) acc[c] += hv * Wfc[k * Cc + c];
    }
    #pragma unroll
    for (int c = 0; c < Cc; c++)
        for (int off = 32; off > 0; off >>= 1) acc[c] += __shfl_down(acc[c], off, 64);
    if (lane == 0) {
        float m = -1e30f;
        #pragma unroll
        for (int c = 0; c < Cc; c++) { acc[c] += bfc[c]; m = fmaxf(m, acc[c]); }
        float s = 0.f;
        #pragma unroll
        for (int c = 0; c < Cc; c++) s += expf(acc[c] - m);
        float lse = logf(s);
        #pragma unroll
        for (int c = 0; c < Cc; c++) out[(long)row * Cc + c] = acc[c] - m - lse;
    }
}

extern "C" void kernel_launch(void* const* d_in, const int* in_sizes, int n_in,
                              void* d_out, int out_size, void* d_ws, size_t ws_size,
                              hipStream_t stream)
{
    const float* feats   = (const float*)d_in[0];
    const float* Wscalar = (const float*)d_in[1];
    const float* W_rel   = (const float*)d_in[2];
    const float* W_root  = (const float*)d_in[3];
    const float* b_rgcn  = (const float*)d_in[4];
    const float* W_nbr   = (const float*)d_in[5];
    const float* W_self  = (const float*)d_in[6];
    const float* b_gc    = (const float*)d_in[7];
    const float* W_match = (const float*)d_in[8];
    const float* b_match = (const float*)d_in[9];
    const float* W_lin   = (const float*)d_in[10];
    const float* b_lin   = (const float*)d_in[11];
    const float* W_fc    = (const float*)d_in[12];
    const float* b_fc    = (const float*)d_in[13];
    const int*   spk     = (const int*)d_in[14];

    char* wsb = (char*)d_ws;
    // Layout (peak 152.9 MB, <= round-7's working 153.0):
    unsigned short* em    = (unsigned short*)wsb;               // [0,48M) persistent
    char* RB = wsb + 50331648;                                  // time-multiplexed region (48M)
    float*          scale = (float*)RB;                         // 16M  (steps 1-2)
    unsigned short* hall4 = (unsigned short*)RB;                // 41.9M (RGCN loop)
    unsigned short* anh1  = (unsigned short*)RB;                // 32M  (anh1 -> h2)
    unsigned short* xt    = (unsigned short*)RB;                // 48M  (xt -> S)
    unsigned short* emWT  = (unsigned short*)RB;                // 16M  (after S)
    unsigned short* hidden= (unsigned short*)(RB + 16777216);   // 16M  (after S)
    char* HB = wsb + 100663296;                                 // second region (32M)
    float*          h1    = (float*)HB;                         // 32M (RGCN -> build_anh1)
    float*          S     = (float*)HB;                         // 16M (after h1 dead)
    unsigned short* ac    = (unsigned short*)(HB + 16777216);   // 8M  (softmax -> hidden)
    int* idx              = (int*)(HB + 16777216);              // 64K (early; clobbered later - ok)
    int* cnts             = (int*)(HB + 16777216 + 65536);      // 8B  (early)
    unsigned short* WT    = (unsigned short*)(wsb + 134217728); // 17.3M persistent
    unsigned short* WscalarT = WT;
    unsigned short* WrelT    = WT + 262144;      // 4608x1024: rels 0..7 then root
    unsigned short* WgcT     = WT + 4980736;     // 512x1024 (nbr k0..512 | self k512..1024)
    unsigned short* WmatchT  = WT + 5505024;     // 1536x1536
    unsigned short* WlinT    = WT + 7864320;     // 512x1536
    float*          enorm = (float*)(wsb + 151519232);          // 1.31M

    // ---- 0a. all weight transposes (1 launch)
    transpose_all<<<dim3(8448), 256, 0, stream>>>(Wscalar, W_rel, W_root, W_nbr, W_self,
                                                  W_match, W_lin, WT);
    // ---- 0b. speaker partition per chunk
    partition_kernel<<<dim3(2), 256, 0, stream>>>(spk, idx, cnts);
    // ---- 0c. em[:, 0:1024) = bf16 features, node order
    build_em_x<<<dim3(Nc), 256, 0, stream>>>(feats, em);

    // ---- 1. scale = x @ Wscalar  [16384 x 256]
    gemm_as<false, false, false, false><<<dim3(2, 128, 1), 256, 0, stream>>>(
        em, WscalarT, scale, nullptr, 1024, DHc, 1024, 256, 0, 0, 0);

    // ---- 2. windowed softmax
    edge_norm_kernel<<<dim3(64), 256, 0, stream>>>(scale, enorm);

    // ---- 3. RGCN per 8192-node chunk: speaker-split 4-transform GEMMs + root, then gather
    for (int c = 0; c < 2; c++) {
        const unsigned short* emc = em + (long)c * CH * DHc;
        gemm_idx<false><<<dim3(16, 64, 1), 256, 0, stream>>>(
            emc, WrelT, hall4, idx + c * CH, cnts + c);
        gemm_idx<true><<<dim3(16, 64, 1), 256, 0, stream>>>(
            emc, WrelT + 2048 * 1024, hall4, idx + c * CH, cnts + c);
        gemm_as<true, false, false, false><<<dim3(4, 64, 1), 256, 0, stream>>>(
            emc, WrelT + 4096 * 1024, hall4 + 2048, nullptr, 1024, DHc, 1024, 2560, 0, 0, 0);
        rgcn_gather4<<<dim3(CH), 256, 0, stream>>>(hall4, enorm, spk, b_rgcn, h1, c * CH);
    }

    // ---- 4. anh1 = concat(window-sum(h1), h1); h2 -> em[:, 1024:1536)
    build_anh1<<<dim3(Nc), 256, 0, stream>>>(h1, anh1);
    gemm_as<true, false, true, false><<<dim3(4, 128, 1), 256, 0, stream>>>(
        anh1, WgcT, em + 1024, b_gc, 1024, 1024, 1024, DHc, 0, 0, 0);

    // ---- 5. xt = em @ W_match + b_match
    gemm_as<true, false, true, false><<<dim3(12, 128, 1), 256, 0, stream>>>(
        em, WmatchT, xt, b_match, DHc, DHc, DHc, DHc, 0, 0, 0);

    // ---- 6. S_b = xt_b @ em_b^T  (z = 64 convs)
    gemm_as<false, false, false, false><<<dim3(2, 2, 64), 256, 0, stream>>>(
        xt, em, S, nullptr, DHc, DHc, DHc, 256, 393216, 393216, 65536);

    // ---- 7. a = softmax(tanh(S))
    tanh_softmax_rows<<<dim3(Nc), 256, 0, stream>>>(S, ac);

    // ---- 8. emWT[conv][h][t] = (em @ W_lin + b_lin)^T per conv   (xt dead -> RB free)
    gemm_as<true, true, true, false><<<dim3(4, 128, 1), 256, 0, stream>>>(
        em, WlinT, emWT, b_lin, DHc, DHc, DHc, 256, 0, 0, 0);

    // ---- 9. hidden = relu(a @ emW)  (z = 64 convs, bf16 out)
    gemm_as<true, false, false, true><<<dim3(4, 2, 64), 256, 0, stream>>>(
        ac, emWT, hidden, nullptr, 256, 256, 256, 512, 65536, 131072, 131072);

    // ---- 10. logits + log_softmax
    out_kernel<<<dim3(Nc / 4), 256, 0, stream>>>(hidden, W_fc, b_fc, (float*)d_out);
}

// Round 2
// 863.034 us; speedup vs baseline: 1.0753x; 1.0753x over previous
//
#include <hip/hip_runtime.h>
#include <hip/hip_bf16.h>

// Problem constants
#define Lc 256
#define Bc 64
#define Dc 1024
#define Hc 512
#define Rc 8
#define Cc 6
#define WINc 10
#define NWc 21
#define Nc (Bc*Lc)        // 16384
#define DHc (Dc+Hc)       // 1536
#define CH 8192           // RGCN chunk (32 conversations)

typedef __attribute__((ext_vector_type(8))) short short8;
typedef __attribute__((ext_vector_type(4))) float floatx4;

__device__ inline unsigned short f2b(float x) {
    __hip_bfloat16 h = __float2bfloat16(x);
    return *reinterpret_cast<unsigned short*>(&h);
}
__device__ inline float bf2f(unsigned short u) {
    __hip_bfloat16 h;
    *reinterpret_cast<unsigned short*>(&h) = u;
    return __bfloat162float(h);
}

// node id n = b*256+s  ->  feats row s*64+b
__device__ inline long remap_row(int node) { return (long)(((node & 255) << 6) + (node >> 8)); }

typedef __attribute__((address_space(3))) unsigned int lds_u32;
typedef __attribute__((address_space(1))) unsigned int glb_u32;
__device__ inline void glds16(const unsigned short* g, unsigned short* l) {
    __builtin_amdgcn_global_load_lds((const glb_u32*)g, (lds_u32*)l, 16, 0, 0);
}

#define SB0 __builtin_amdgcn_sched_barrier(0)
#define BAR __builtin_amdgcn_s_barrier()

// ---------------- all weight transposes in ONE launch (fp32 [K][N] -> bf16 [N][K]) ----------------
__global__ __launch_bounds__(256) void transpose_all(
    const float* __restrict__ Wscalar, const float* __restrict__ W_rel,
    const float* __restrict__ W_root, const float* __restrict__ W_nbr,
    const float* __restrict__ W_self, const float* __restrict__ W_match,
    const float* __restrict__ W_lin, unsigned short* __restrict__ WT)
{
    int t = blockIdx.x;
    const float* in; unsigned short* out; int N, ldo, n0, k0;
    if (t < 256) {                       // Wscalar [1024][256] -> [256][1024]
        in = Wscalar; out = WT; N = 256; ldo = 1024;
        n0 = (t & 7) * 32; k0 = (t >> 3) * 32;
    } else if (t < 4352) {               // W_rel 8x[1024][512] -> rows r*512..
        int u = t - 256; int r = u >> 9; u &= 511;
        in = W_rel + (long)r * 524288; out = WT + 262144 + (long)r * 524288; N = 512; ldo = 1024;
        n0 = (u & 15) * 32; k0 = (u >> 4) * 32;
    } else if (t < 4864) {               // W_root -> WrelT rows 4096..4608
        int u = t - 4352;
        in = W_root; out = WT + 262144 + 4096 * 1024; N = 512; ldo = 1024;
        n0 = (u & 15) * 32; k0 = (u >> 4) * 32;
    } else if (t < 5120) {               // W_nbr -> WgcT k 0..512
        int u = t - 4864;
        in = W_nbr; out = WT + 4980736; N = 512; ldo = 1024;
        n0 = (u & 15) * 32; k0 = (u >> 4) * 32;
    } else if (t < 5376) {               // W_self -> WgcT k 512..1024
        int u = t - 5120;
        in = W_self; out = WT + 4980736 + 512; N = 512; ldo = 1024;
        n0 = (u & 15) * 32; k0 = (u >> 4) * 32;
    } else if (t < 7680) {               // W_match [1536][1536]
        int u = t - 5376;
        in = W_match; out = WT + 5505024; N = 1536; ldo = 1536;
        n0 = (u % 48) * 32; k0 = (u / 48) * 32;
    } else {                             // W_lin [1536][512]
        int u = t - 7680;
        in = W_lin; out = WT + 7864320; N = 512; ldo = 1536;
        n0 = (u & 15) * 32; k0 = (u >> 4) * 32;
    }
    __shared__ float tt[32][33];
    int tx = threadIdx.x & 31, ty = threadIdx.x >> 5;
    #pragma unroll
    for (int i = 0; i < 4; i++) tt[ty + i * 8][tx] = in[(long)(k0 + ty + i * 8) * N + n0 + tx];
    __syncthreads();
    #pragma unroll
    for (int i = 0; i < 4; i++) out[(long)(n0 + ty + i * 8) * ldo + k0 + tx] = f2b(tt[tx][ty + i * 8]);
}

// ---------------- stable partition of each chunk's nodes by speaker ----------------
__global__ __launch_bounds__(256) void partition_kernel(const int* __restrict__ spk,
        int* __restrict__ idx, int* __restrict__ cnts)
{
    int c = blockIdx.x;
    int tid = threadIdx.x;
    int base = c * CH;
    __shared__ int zs[256];
    int zcount = 0;
    for (int i = 0; i < CH / 256; i++) {
        int n = base + tid * (CH / 256) + i;
        if (spk[(n & 255) * 64 + (n >> 8)] == 0) zcount++;
    }
    zs[tid] = zcount; __syncthreads();
    for (int off = 1; off < 256; off <<= 1) {
        int v = (tid >= off) ? zs[tid - off] : 0;
        __syncthreads();
        zs[tid] += v;
        __syncthreads();
    }
    int Z = zs[255];
    int zpos = zs[tid] - zcount;                 // exclusive zeros before my range
    int opos = tid * (CH / 256) - zpos;          // ones before my range
    for (int i = 0; i < CH / 256; i++) {
        int nl = tid * (CH / 256) + i;
        int n = base + nl;
        if (spk[(n & 255) * 64 + (n >> 8)] == 0) idx[base + (zpos++)] = nl;
        else                                     idx[base + Z + (opos++)] = nl;
    }
    if (tid == 0) cnts[c] = Z;
}

// ---------------- em[:, 0:1024) = bf16(features) in node order ----------------
__global__ __launch_bounds__(256) void build_em_x(const float* __restrict__ feats,
                                                  unsigned short* __restrict__ em)
{
    int n = blockIdx.x;
    int tid = threadIdx.x;
    const float* f = feats + remap_row(n) * Dc;
    float4 v = ((const float4*)f)[tid];
    unsigned short* e = em + (long)n * DHc + tid * 4;
    e[0] = f2b(v.x); e[1] = f2b(v.y); e[2] = f2b(v.z); e[3] = f2b(v.w);
}

// ---------------- 128^2 MFMA GEMM, async staging (round-7 engine; small/batched shapes) ----------------
template<bool CBF, bool CT, bool BIAS, bool RELU>
__global__ __launch_bounds__(256) void gemm_as(
    const unsigned short* __restrict__ A, const unsigned short* __restrict__ B,
    void* __restrict__ Cv, const float* __restrict__ bias,
    int K, int lda, int ldb, int ldc, long sA, long sB, long sC)
{
    __shared__ __align__(16) unsigned short As[4096];
    __shared__ __align__(16) unsigned short Bs[4096];
    const int tid = threadIdx.x;
    const int z = blockIdx.z;
    const int m0 = blockIdx.y * 128, n0 = blockIdx.x * 128;
    const int lane = tid & 63, wave = tid >> 6;
    const int q = lane >> 4, mr = lane & 15;
    const int wrow = (wave >> 1) * 64, wcol = (wave & 1) * 64;

    const unsigned short* Ag0 = A + z * sA + (long)(m0 + wave * 32 + mr) * lda + q * 8;
    const unsigned short* Ag1 = Ag0 + (long)16 * lda;
    const unsigned short* Bg0 = B + z * sB + (long)(n0 + wave * 32 + mr) * ldb + q * 8;
    const unsigned short* Bg1 = Bg0 + (long)16 * ldb;
    unsigned short* Al0 = As + wave * 1024;
    unsigned short* Bl0 = Bs + wave * 1024;

    floatx4 acc[4][4];
    #pragma unroll
    for (int mt = 0; mt < 4; mt++)
        #pragma unroll
        for (int nt = 0; nt < 4; nt++) acc[mt][nt] = (floatx4){0.f, 0.f, 0.f, 0.f};

    const int ga = (wave >> 1) * 2048;
    const int gb = (wave & 1) * 2048;

    for (int k0 = 0; k0 < K; k0 += 32) {
        glds16(Ag0 + k0, Al0);
        glds16(Ag1 + k0, Al0 + 512);
        glds16(Bg0 + k0, Bl0);
        glds16(Bg1 + k0, Bl0 + 512);
        __syncthreads();
        short8 af[4], bfr[4];
        #pragma unroll
        for (int t = 0; t < 4; t++) {
            af[t]  = *(const short8*)&As[ga + t * 512 + lane * 8];
            bfr[t] = *(const short8*)&Bs[gb + t * 512 + lane * 8];
        }
        #pragma unroll
        for (int mt = 0; mt < 4; mt++)
            #pragma unroll
            for (int nt = 0; nt < 4; nt++)
                acc[mt][nt] = __builtin_amdgcn_mfma_f32_16x16x32_bf16(af[mt], bfr[nt], acc[mt][nt], 0, 0, 0);
        __syncthreads();
    }

    float* Cf = (float*)Cv;
    unsigned short* Cb = (unsigned short*)Cv;
    #pragma unroll
    for (int mt = 0; mt < 4; mt++) {
        #pragma unroll
        for (int nt = 0; nt < 4; nt++) {
            int col = n0 + wcol + nt * 16 + mr;
            float bv = BIAS ? bias[col] : 0.f;
            #pragma unroll
            for (int rg = 0; rg < 4; rg++) {
                int row = m0 + wrow + mt * 16 + q * 4 + rg;
                float v = acc[mt][nt][rg] + bv;
                if (RELU) v = fmaxf(v, 0.f);
                if (CT) {
                    Cb[(long)(row >> 8) * 131072 + (long)col * 256 + (row & 255)] = f2b(v);
                } else {
                    long ci = z * sC + (long)row * ldc + col;
                    if (CBF) Cb[ci] = f2b(v);
                    else     Cf[ci] = v;
                }
            }
        }
    }
}

// ---------------- 256^2 8-wave deep-pipelined GEMM (T2 swizzle + T3/T4 counted vmcnt + T5) ----------
// BM=BN=256, BK=64 (2 K-halves of 32). LDS: A[2buf][2kh][256][32] + B same = 128 KiB.
// Per K-tile: 4 phases {dsread quad, stage 1 half-slot, (vmcnt@j3), bar, lgkm, 16 MFMA, bar}.
// Stage ledger (slot sigma=4t+j staged at phase sigma-6): every region is written >=1 barrier
// after its last reader; every reader is >=1 counted-vmcnt+barrier after its staging.
// vmcnt(4) at j=3 leaves exactly tile t+2's (A-k0,B-k0) 4 loads in flight; never 0 mid-loop.
// LDS swizzle: elem col-group g stored at g ^ ((row>>1)&3); staged via pre-swizzled GLOBAL
// source (global_load_lds dest must be linear - rule #21); read with same XOR -> 2-way banks.
template<bool CBF, bool CT, bool BIAS, bool RELU>
__global__ __launch_bounds__(512, 2) void gemm256(
    const unsigned short* __restrict__ A, const unsigned short* __restrict__ B,
    void* __restrict__ Cv, const float* __restrict__ bias,
    int K, int lda, int ldb, int ldc)
{
    __shared__ __align__(16) unsigned short LDS[65536];   // 128 KiB
    unsigned short* lp = &LDS[0];
    const int tid  = threadIdx.x;
    const int lane = tid & 63, wave = tid >> 6;
    const int wm = wave >> 2, wn = wave & 3;              // 2x4 wave grid
    const int m0 = blockIdx.y * 256, n0 = blockIdx.x * 256;
    const int NT = K >> 6;                                 // K-tiles of 64
    const int q = lane >> 4, mr = lane & 15;

    // ---- staging invariants: load i covers rows i*128 + wave*16 + (lane>>2), 4 lanes/row
    const int r0 = wave * 16 + (lane >> 2);
    const int r1 = r0 + 128;
    const int c0 = ((lane & 3) ^ ((r0 >> 1) & 3)) * 8;    // pre-swizzled source col (elems)
    const int c1 = ((lane & 3) ^ ((r1 >> 1) & 3)) * 8;
    const unsigned short* Ag0 = A + (long)(m0 + r0) * lda + c0;
    const unsigned short* Ag1 = A + (long)(m0 + r1) * lda + c1;
    const unsigned short* Bg0 = B + (long)(n0 + r0) * ldb + c0;
    const unsigned short* Bg1 = B + (long)(n0 + r1) * ldb + c1;
    const int wofs = wave * 512;                           // wave's linear LDS piece (elems)

    // ---- ds_read fragment offsets (elems, within one (buf,kh) 8192-elem region)
    int offA[8], offB[4];
    #pragma unroll
    for (int mt = 0; mt < 8; mt++) {
        int row = wm * 128 + mt * 16 + mr;
        offA[mt] = row * 32 + ((q ^ ((row >> 1) & 3)) * 8);
    }
    #pragma unroll
    for (int nt = 0; nt < 4; nt++) {
        int row = wn * 64 + nt * 16 + mr;
        offB[nt] = row * 32 + ((q ^ ((row >> 1) & 3)) * 8);
    }

    floatx4 acc[8][4];
    #pragma unroll
    for (int mt = 0; mt < 8; mt++)
        #pragma unroll
        for (int nt = 0; nt < 4; nt++) acc[mt][nt] = (floatx4){0.f, 0.f, 0.f, 0.f};

    // ---- prologue: stage slots 0..5 = t0{A0,B0,A1,B1}, t1{A0,B0}
    glds16(Ag0,      lp + wofs);                 glds16(Ag1,      lp + 4096 + wofs);
    glds16(Bg0,      lp + 32768 + wofs);         glds16(Bg1,      lp + 32768 + 4096 + wofs);
    glds16(Ag0 + 32, lp + 8192 + wofs);          glds16(Ag1 + 32, lp + 8192 + 4096 + wofs);
    glds16(Bg0 + 32, lp + 32768 + 8192 + wofs);  glds16(Bg1 + 32, lp + 32768 + 8192 + 4096 + wofs);
    glds16(Ag0 + 64, lp + 16384 + wofs);         glds16(Ag1 + 64, lp + 16384 + 4096 + wofs);
    glds16(Bg0 + 64, lp + 32768 + 16384 + wofs); glds16(Bg1 + 64, lp + 32768 + 16384 + 4096 + wofs);
    asm volatile("s_waitcnt vmcnt(4)" ::: "memory");   // t0 fully staged; t1 k0 pair in flight
    SB0; BAR; SB0;

    for (int t = 0; t < NT; t++) {
        const int buf = t & 1;
        const int ab  = buf * 16384;        // A (buf,kh0) base; +8192 for kh1; +32768 for B
        short8 aF[4], bF[4];

        // ===== phase j=0: quad mt0-3 x ks0 ; stage (t+1, A, kh1) -> buf^1
        #pragma unroll
        for (int i = 0; i < 4; i++) aF[i] = *(const short8*)(lp + ab + offA[i]);
        #pragma unroll
        for (int i = 0; i < 4; i++) bF[i] = *(const short8*)(lp + 32768 + ab + offB[i]);
        if (t + 1 < NT) {
            const int kc = (t + 1) * 64 + 32;
            unsigned short* d = lp + (buf ^ 1) * 16384 + 8192 + wofs;
            glds16(Ag0 + kc, d); glds16(Ag1 + kc, d + 4096);
        }
        SB0; BAR; SB0;
        asm volatile("s_waitcnt lgkmcnt(0)" ::: "memory"); SB0;
        __builtin_amdgcn_s_setprio(1);
        #pragma unroll
        for (int mt = 0; mt < 4; mt++)
            #pragma unroll
            for (int nt = 0; nt < 4; nt++)
                acc[mt][nt] = __builtin_amdgcn_mfma_f32_16x16x32_bf16(aF[mt], bF[nt], acc[mt][nt], 0, 0, 0);
        __builtin_amdgcn_s_setprio(0);
        SB0; BAR; SB0;

        // ===== phase j=1: quad mt4-7 x ks0 (bF reused) ; stage (t+1, B, kh1) -> buf^1
        #pragma unroll
        for (int i = 0; i < 4; i++) aF[i] = *(const short8*)(lp + ab + offA[4 + i]);
        if (t + 1 < NT) {
            const int kc = (t + 1) * 64 + 32;
            unsigned short* d = lp + 32768 + (buf ^ 1) * 16384 + 8192 + wofs;
            glds16(Bg0 + kc, d); glds16(Bg1 + kc, d + 4096);
        }
        SB0; BAR; SB0;
        asm volatile("s_waitcnt lgkmcnt(0)" ::: "memory"); SB0;
        __builtin_amdgcn_s_setprio(1);
        #pragma unroll
        for (int mt = 0; mt < 4; mt++)
            #pragma unroll
            for (int nt = 0; nt < 4; nt++)
                acc[4 + mt][nt] = __builtin_amdgcn_mfma_f32_16x16x32_bf16(aF[mt], bF[nt], acc[4 + mt][nt], 0, 0, 0);
        __builtin_amdgcn_s_setprio(0);
        SB0; BAR; SB0;

        // ===== phase j=2: quad mt0-3 x ks1 ; stage (t+2, A, kh0) -> buf (kh0 dead after j=1)
        #pragma unroll
        for (int i = 0; i < 4; i++) aF[i] = *(const short8*)(lp + ab + 8192 + offA[i]);
        #pragma unroll
        for (int i = 0; i < 4; i++) bF[i] = *(const short8*)(lp + 32768 + ab + 8192 + offB[i]);
        if (t + 2 < NT) {
            const int kc = (t + 2) * 64;
            unsigned short* d = lp + buf * 16384 + wofs;
            glds16(Ag0 + kc, d); glds16(Ag1 + kc, d + 4096);
        }
        SB0; BAR; SB0;
        asm volatile("s_waitcnt lgkmcnt(0)" ::: "memory"); SB0;
        __builtin_amdgcn_s_setprio(1);
        #pragma unroll
        for (int mt = 0; mt < 4; mt++)
            #pragma unroll
            for (int nt = 0; nt < 4; nt++)
                acc[mt][nt] = __builtin_amdgcn_mfma_f32_16x16x32_bf16(aF[mt], bF[nt], acc[mt][nt], 0, 0, 0);
        __builtin_amdgcn_s_setprio(0);
        SB0; BAR; SB0;

        // ===== phase j=3: quad mt4-7 x ks1 (bF reused) ; stage (t+2, B, kh0) -> buf ; counted wait
        #pragma unroll
        for (int i = 0; i < 4; i++) aF[i] = *(const short8*)(lp + ab + 8192 + offA[4 + i]);
        if (t + 2 < NT) {
            const int kc = (t + 2) * 64;
            unsigned short* d = lp + 32768 + buf * 16384 + wofs;
            glds16(Bg0 + kc, d); glds16(Bg1 + kc, d + 4096);
        }
        if (t < NT - 2)       { asm volatile("s_waitcnt vmcnt(4)" ::: "memory"); }
        else if (t == NT - 2) { asm volatile("s_waitcnt vmcnt(0)" ::: "memory"); }
        SB0; BAR; SB0;
        asm volatile("s_waitcnt lgkmcnt(0)" ::: "memory"); SB0;
        __builtin_amdgcn_s_setprio(1);
        #pragma unroll
        for (int mt = 0; mt < 4; mt++)
            #pragma unroll
            for (int nt = 0; nt < 4; nt++)
                acc[4 + mt][nt] = __builtin_amdgcn_mfma_f32_16x16x32_bf16(aF[mt], bF[nt], acc[4 + mt][nt], 0, 0, 0);
        __builtin_amdgcn_s_setprio(0);
        SB0; BAR; SB0;
    }

    // ---- epilogue
    float* Cf = (float*)Cv;
    unsigned short* Cb = (unsigned short*)Cv;
    #pragma unroll
    for (int mt = 0; mt < 8; mt++) {
        #pragma unroll
        for (int nt = 0; nt < 4; nt++) {
            int col = n0 + wn * 64 + nt * 16 + mr;
            float bv = BIAS ? bias[col] : 0.f;
            #pragma unroll
            for (int rg = 0; rg < 4; rg++) {
                int row = m0 + wm * 128 + mt * 16 + q * 4 + rg;
                float v = acc[mt][nt][rg] + bv;
                if (RELU) v = fmaxf(v, 0.f);
                if (CT) {
                    Cb[(long)(row >> 8) * 131072 + (long)col * 256 + (row & 255)] = f2b(v);
                } else {
                    long ci = (long)row * ldc + col;
                    if (CBF) Cb[ci] = f2b(v);
                    else     Cf[ci] = v;
                }
            }
        }
    }
}

// ---------------- row-indexed GEMM for speaker-partitioned RGCN (C scatter, ldc 2560) ----------------
template<bool SP1>
__global__ __launch_bounds__(256) void gemm_idx(
    const unsigned short* __restrict__ A, const unsigned short* __restrict__ B,
    unsigned short* __restrict__ C, const int* __restrict__ idx,
    const int* __restrict__ cntp)
{
    const int cnt0 = *cntp;
    const int off  = SP1 ? cnt0 : 0;
    const int M    = SP1 ? (CH - cnt0) : cnt0;
    const int m0 = blockIdx.y * 128;
    if (m0 >= M) return;
    const int n0 = blockIdx.x * 128;
    const int tid = threadIdx.x;
    const int lane = tid & 63, wave = tid >> 6;
    const int q = lane >> 4, mr = lane & 15;
    const int wrow = (wave >> 1) * 64, wcol = (wave & 1) * 64;

    int r0 = m0 + wave * 32 + mr;
    int ar0 = idx[off + min(r0, M - 1)];
    int ar1 = idx[off + min(r0 + 16, M - 1)];
    const unsigned short* Ag0 = A + (long)ar0 * DHc + q * 8;
    const unsigned short* Ag1 = A + (long)ar1 * DHc + q * 8;
    const unsigned short* Bg0 = B + (long)(n0 + wave * 32 + mr) * 1024 + q * 8;
    const unsigned short* Bg1 = Bg0 + 16 * 1024;

    __shared__ __align__(16) unsigned short As[4096];
    __shared__ __align__(16) unsigned short Bs[4096];
    unsigned short* Al0 = As + wave * 1024;
    unsigned short* Bl0 = Bs + wave * 1024;

    floatx4 acc[4][4];
    #pragma unroll
    for (int mt = 0; mt < 4; mt++)
        #pragma unroll
        for (int nt = 0; nt < 4; nt++) acc[mt][nt] = (floatx4){0.f, 0.f, 0.f, 0.f};

    const int ga = (wave >> 1) * 2048;
    const int gb = (wave & 1) * 2048;

    for (int k0 = 0; k0 < 1024; k0 += 32) {
        glds16(Ag0 + k0, Al0);
        glds16(Ag1 + k0, Al0 + 512);
        glds16(Bg0 + k0, Bl0);
        glds16(Bg1 + k0, Bl0 + 512);
        __syncthreads();
        short8 af[4], bfr[4];
        #pragma unroll
        for (int t = 0; t < 4; t++) {
            af[t]  = *(const short8*)&As[ga + t * 512 + lane * 8];
            bfr[t] = *(const short8*)&Bs[gb + t * 512 + lane * 8];
        }
        #pragma unroll
        for (int mt = 0; mt < 4; mt++)
            #pragma unroll
            for (int nt = 0; nt < 4; nt++)
                acc[mt][nt] = __builtin_amdgcn_mfma_f32_16x16x32_bf16(af[mt], bfr[nt], acc[mt][nt], 0, 0, 0);
        __syncthreads();
    }

    #pragma unroll
    for (int mt = 0; mt < 4; mt++) {
        #pragma unroll
        for (int nt = 0; nt < 4; nt++) {
            int col = n0 + wcol + nt * 16 + mr;
            #pragma unroll
            for (int rg = 0; rg < 4; rg++) {
                int row = m0 + wrow + mt * 16 + q * 4 + rg;
                int crow = idx[off + min(row, M - 1)];
                C[(long)crow * 2560 + col] = f2b(acc[mt][nt][rg]);
            }
        }
    }
}

// ---------------- edge_norm: windowed softmax over k (scale node-ordered) ----------------
__global__ __launch_bounds__(256) void edge_norm_kernel(const float* __restrict__ scale,
                                                        float* __restrict__ enorm)
{
    int g = blockIdx.x * 256 + threadIdx.x;   // b*L + j
    int b = g >> 8, j = g & 255;
    int klo = max(0, j - WINc), khi = min(Lc - 1, j + WINc);
    float vals[NWc];
    float m = -1e30f;
    for (int k = klo; k <= khi; k++) {
        float v = scale[(long)((b << 8) + k) * Lc + j];
        vals[k - klo] = v;
        m = fmaxf(m, v);
    }
    float s = 0.f;
    for (int k = klo; k <= khi; k++) {
        float e = expf(vals[k - klo] - m);
        vals[k - klo] = e;
        s += e;
    }
    float inv = 1.f / s;
    for (int k = klo; k <= khi; k++)
        enorm[(long)g * NWc + (k - j + WINc)] = vals[k - klo] * inv;
}

// ---------------- RGCN aggregation (hall4 bf16 [CH][2560]: 4 dst-sel blocks + root) ----------------
__global__ __launch_bounds__(256) void rgcn_gather4(const unsigned short* __restrict__ hall4,
        const float* __restrict__ enorm, const int* __restrict__ spk,
        const float* __restrict__ b_rgcn, float* __restrict__ h1, int chunk_base)
{
    int nloc = blockIdx.x;
    int n = chunk_base + nloc;
    int b = n >> 8, k = n & 255;
    int tid = threadIdx.x;
    int spkk = spk[k * 64 + b];
    int jlo = max(0, k - WINc), jhi = min(Lc - 1, k + WINc);
    unsigned int ru = *(const unsigned int*)(hall4 + (long)nloc * 2560 + 2048 + 2 * tid);
    float a0 = bf2f((unsigned short)(ru & 0xffff)) + b_rgcn[2 * tid];
    float a1 = bf2f((unsigned short)(ru >> 16)) + b_rgcn[2 * tid + 1];
    int cb = spkk * 2;
    for (int j = jlo; j <= jhi; j++) {
        int c = cb + ((j < k) ? 0 : 1);
        float w = enorm[((long)((b << 8) + j)) * NWc + (k - j + WINc)];
        unsigned int u = *(const unsigned int*)(hall4 + ((long)(nloc - k + j)) * 2560 + c * 512 + 2 * tid);
        a0 += w * bf2f((unsigned short)(u & 0xffff));
        a1 += w * bf2f((unsigned short)(u >> 16));
    }
    *(float2*)&h1[(long)n * Hc + 2 * tid] = make_float2(a0, a1);
}

// ---------------- anh1 = bf16[ concat(window-sum(h1), h1) ]  [N][1024] ----------------
__global__ __launch_bounds__(256) void build_anh1(const float* __restrict__ h1,
                                                  unsigned short* __restrict__ anh1)
{
    int n = blockIdx.x;
    int b = n >> 8, k = n & 255;
    int tid = threadIdx.x;
    int jlo = max(0, k - WINc), jhi = min(Lc - 1, k + WINc);
    float a0 = 0.f, a1 = 0.f;
    for (int j = jlo; j <= jhi; j++) {
        const float* src = h1 + ((long)((b << 8) + j)) * Hc;
        a0 += src[tid];
        a1 += src[tid + 256];
    }
    unsigned short* dst = anh1 + (long)n * 1024;
    const float* self = h1 + (long)n * Hc;
    dst[tid]       = f2b(a0);
    dst[tid + 256] = f2b(a1);
    dst[tid + 512] = f2b(self[tid]);
    dst[tid + 768] = f2b(self[tid + 256]);
}

// ---------------- tanh + row softmax -> bf16 attention weights ----------------
__global__ __launch_bounds__(256) void tanh_softmax_rows(const float* __restrict__ S,
                                                         unsigned short* __restrict__ a)
{
    int row = blockIdx.x;
    int tid = threadIdx.x;
    __shared__ float red[256];
    float v = tanhf(S[(long)row * Lc + tid]);
    red[tid] = v; __syncthreads();
    for (int s = 128; s > 0; s >>= 1) { if (tid < s) red[tid] = fmaxf(red[tid], red[tid + s]); __syncthreads(); }
    float m = red[0]; __syncthreads();
    float e = expf(v - m);
    red[tid] = e; __syncthreads();
    for (int s = 128; s > 0; s >>= 1) { if (tid < s) red[tid] += red[tid + s]; __syncthreads(); }
    float sum = red[0];
    a[(long)row * Lc + tid] = f2b(e / sum);
}

// ---------------- final classifier + log_softmax (fp32 out) ----------------
__global__ __launch_bounds__(256) void out_kernel(const unsigned short* __restrict__ hidden,
        const float* __restrict__ Wfc, const float* __restrict__ bfc, float* __restrict__ out)
{
    int tid = threadIdx.x;
    int lane = tid & 63;
    int row = blockIdx.x * 4 + (tid >> 6);
    float acc[Cc] = {};
    const unsigned short* h = hidden + (long)row * Hc;
    for (int k = lane; k < Hc; k += 64) {
        float hv = bf2f(h[k]);
        #pragma unroll
        for (int c = 0; c < Cc; c++) acc[c] += hv * Wfc[k * Cc + c];
    }
    #pragma unroll
    for (int c = 0; c < Cc; c++)
        for (int off = 32; off > 0; off >>= 1) acc[c] += __shfl_down(acc[c], off, 64);
    if (lane == 0) {
        float m = -1e30f;
        #pragma unroll
        for (int c = 0; c < Cc; c++) { acc[c] += bfc[c]; m = fmaxf(m, acc[c]); }
        float s = 0.f;
        #pragma unroll
        for (int c = 0; c < Cc; c++) s += expf(acc[c] - m);
        float lse = logf(s);
        #pragma unroll
        for (int c = 0; c < Cc; c++) out[(long)row * Cc + c] = acc[c] - m - lse;
    }
}

extern "C" void kernel_launch(void* const* d_in, const int* in_sizes, int n_in,
                              void* d_out, int out_size, void* d_ws, size_t ws_size,
                              hipStream_t stream)
{
    const float* feats   = (const float*)d_in[0];
    const float* Wscalar = (const float*)d_in[1];
    const float* W_rel   = (const float*)d_in[2];
    const float* W_root  = (const float*)d_in[3];
    const float* b_rgcn  = (const float*)d_in[4];
    const float* W_nbr   = (const float*)d_in[5];
    const float* W_self  = (const float*)d_in[6];
    const float* b_gc    = (const float*)d_in[7];
    const float* W_match = (const float*)d_in[8];
    const float* b_match = (const float*)d_in[9];
    const float* W_lin   = (const float*)d_in[10];
    const float* b_lin   = (const float*)d_in[11];
    const float* W_fc    = (const float*)d_in[12];
    const float* b_fc    = (const float*)d_in[13];
    const int*   spk     = (const int*)d_in[14];

    char* wsb = (char*)d_ws;
    unsigned short* em    = (unsigned short*)wsb;               // [0,48M) persistent
    char* RB = wsb + 50331648;                                  // time-multiplexed region (48M)
    float*          scale = (float*)RB;                         // 16M  (steps 1-2)
    unsigned short* hall4 = (unsigned short*)RB;                // 41.9M (RGCN loop)
    unsigned short* anh1  = (unsigned short*)RB;                // 32M  (anh1 -> h2)
    unsigned short* xt    = (unsigned short*)RB;                // 48M  (xt -> S)
    unsigned short* emWT  = (unsigned short*)RB;                // 16M  (after S)
    unsigned short* hidden= (unsigned short*)(RB + 16777216);   // 16M  (after S)
    char* HB = wsb + 100663296;                                 // second region (32M)
    float*          h1    = (float*)HB;                         // 32M (RGCN -> build_anh1)
    float*          S     = (float*)HB;                         // 16M (after h1 dead)
    unsigned short* ac    = (unsigned short*)(HB + 16777216);   // 8M  (softmax -> hidden)
    int* idx              = (int*)(HB + 16777216);              // 64K (early; clobbered later - ok)
    int* cnts             = (int*)(HB + 16777216 + 65536);      // 8B  (early)
    unsigned short* WT    = (unsigned short*)(wsb + 134217728); // 17.3M persistent
    unsigned short* WscalarT = WT;
    unsigned short* WrelT    = WT + 262144;      // 4608x1024: rels 0..7 then root
    unsigned short* WgcT     = WT + 4980736;     // 512x1024 (nbr k0..512 | self k512..1024)
    unsigned short* WmatchT  = WT + 5505024;     // 1536x1536
    unsigned short* WlinT    = WT + 7864320;     // 512x1536
    float*          enorm = (float*)(wsb + 151519232);          // 1.31M

    // ---- 0a. all weight transposes (1 launch)
    transpose_all<<<dim3(8448), 256, 0, stream>>>(Wscalar, W_rel, W_root, W_nbr, W_self,
                                                  W_match, W_lin, WT);
    // ---- 0b. speaker partition per chunk
    partition_kernel<<<dim3(2), 256, 0, stream>>>(spk, idx, cnts);
    // ---- 0c. em[:, 0:1024) = bf16 features, node order
    build_em_x<<<dim3(Nc), 256, 0, stream>>>(feats, em);

    // ---- 1. scale = x @ Wscalar  [16384 x 256]
    gemm_as<false, false, false, false><<<dim3(2, 128, 1), 256, 0, stream>>>(
        em, WscalarT, scale, nullptr, 1024, DHc, 1024, 256, 0, 0, 0);

    // ---- 2. windowed softmax
    edge_norm_kernel<<<dim3(64), 256, 0, stream>>>(scale, enorm);

    // ---- 3. RGCN per 8192-node chunk: speaker-split 4-transform GEMMs + root, then gather
    for (int c = 0; c < 2; c++) {
        const unsigned short* emc = em + (long)c * CH * DHc;
        gemm_idx<false><<<dim3(16, 64, 1), 256, 0, stream>>>(
            emc, WrelT, hall4, idx + c * CH, cnts + c);
        gemm_idx<true><<<dim3(16, 64, 1), 256, 0, stream>>>(
            emc, WrelT + 2048 * 1024, hall4, idx + c * CH, cnts + c);
        gemm_as<true, false, false, false><<<dim3(4, 64, 1), 256, 0, stream>>>(
            emc, WrelT + 4096 * 1024, hall4 + 2048, nullptr, 1024, DHc, 1024, 2560, 0, 0, 0);
        rgcn_gather4<<<dim3(CH), 256, 0, stream>>>(hall4, enorm, spk, b_rgcn, h1, c * CH);
    }

    // ---- 4. anh1 = concat(window-sum(h1), h1); h2 -> em[:, 1024:1536)   [256^2 engine]
    build_anh1<<<dim3(Nc), 256, 0, stream>>>(h1, anh1);
    gemm256<true, false, true, false><<<dim3(2, 64, 1), 512, 0, stream>>>(
        anh1, WgcT, em + 1024, b_gc, 1024, 1024, 1024, DHc);

    // ---- 5. xt = em @ W_match + b_match   [256^2 engine]
    gemm256<true, false, true, false><<<dim3(6, 64, 1), 512, 0, stream>>>(
        em, WmatchT, xt, b_match, DHc, DHc, 1536, DHc);

    // ---- 6. S_b = xt_b @ em_b^T  (z = 64 convs)
    gemm_as<false, false, false, false><<<dim3(2, 2, 64), 256, 0, stream>>>(
        xt, em, S, nullptr, DHc, DHc, DHc, 256, 393216, 393216, 65536);

    // ---- 7. a = softmax(tanh(S))
    tanh_softmax_rows<<<dim3(Nc), 256, 0, stream>>>(S, ac);

    // ---- 8. emWT[conv][h][t] = (em @ W_lin + b_lin)^T per conv   [256^2 engine]
    gemm256<true, true, true, false><<<dim3(2, 64, 1), 512, 0, stream>>>(
        em, WlinT, emWT, b_lin, DHc, DHc, 1536, 256);

    // ---- 9. hidden = relu(a @ emW)  (z = 64 convs, bf16 out)
    gemm_as<true, false, false, true><<<dim3(4, 2, 64), 256, 0, stream>>>(
        ac, emWT, hidden, nullptr, 256, 256, 256, 512, 65536, 131072, 131072);

    // ---- 10. logits + log_softmax
    out_kernel<<<dim3(Nc / 4), 256, 0, stream>>>(hidden, W_fc, b_fc, (float*)d_out);
}

// Round 3
// 717.583 us; speedup vs baseline: 1.2933x; 1.2027x over previous
//
#include <hip/hip_runtime.h>
#include <hip/hip_bf16.h>

// Problem constants
#define Lc 256
#define Bc 64
#define Dc 1024
#define Hc 512
#define Rc 8
#define Cc 6
#define WINc 10
#define NWc 21
#define Nc (Bc*Lc)        // 16384
#define DHc (Dc+Hc)       // 1536
#define CH 8192           // RGCN chunk (32 conversations)

typedef __attribute__((ext_vector_type(8))) short short8;
typedef __attribute__((ext_vector_type(4))) float floatx4;

__device__ inline unsigned short f2b(float x) {
    __hip_bfloat16 h = __float2bfloat16(x);
    return *reinterpret_cast<unsigned short*>(&h);
}
__device__ inline float bf2f(unsigned short u) {
    __hip_bfloat16 h;
    *reinterpret_cast<unsigned short*>(&h) = u;
    return __bfloat162float(h);
}

// node id n = b*256+s  ->  feats row s*64+b
__device__ inline long remap_row(int node) { return (long)(((node & 255) << 6) + (node >> 8)); }

typedef __attribute__((address_space(3))) unsigned int lds_u32;
typedef __attribute__((address_space(1))) unsigned int glb_u32;
__device__ inline void glds16(const unsigned short* g, unsigned short* l) {
    __builtin_amdgcn_global_load_lds((const glb_u32*)g, (lds_u32*)l, 16, 0, 0);
}

#define SB0 __builtin_amdgcn_sched_barrier(0)
#define BAR __builtin_amdgcn_s_barrier()

// ---------------- all weight transposes in ONE launch (fp32 [K][N] -> bf16 [N][K]) ----------------
__global__ __launch_bounds__(256) void transpose_all(
    const float* __restrict__ Wscalar, const float* __restrict__ W_rel,
    const float* __restrict__ W_root, const float* __restrict__ W_nbr,
    const float* __restrict__ W_self, const float* __restrict__ W_match,
    const float* __restrict__ W_lin, unsigned short* __restrict__ WT)
{
    int t = blockIdx.x;
    const float* in; unsigned short* out; int N, ldo, n0, k0;
    if (t < 256) {                       // Wscalar [1024][256] -> [256][1024]
        in = Wscalar; out = WT; N = 256; ldo = 1024;
        n0 = (t & 7) * 32; k0 = (t >> 3) * 32;
    } else if (t < 4352) {               // W_rel 8x[1024][512] -> rows r*512..
        int u = t - 256; int r = u >> 9; u &= 511;
        in = W_rel + (long)r * 524288; out = WT + 262144 + (long)r * 524288; N = 512; ldo = 1024;
        n0 = (u & 15) * 32; k0 = (u >> 4) * 32;
    } else if (t < 4864) {               // W_root -> WrelT rows 4096..4608
        int u = t - 4352;
        in = W_root; out = WT + 262144 + 4096 * 1024; N = 512; ldo = 1024;
        n0 = (u & 15) * 32; k0 = (u >> 4) * 32;
    } else if (t < 5120) {               // W_nbr -> WgcT k 0..512
        int u = t - 4864;
        in = W_nbr; out = WT + 4980736; N = 512; ldo = 1024;
        n0 = (u & 15) * 32; k0 = (u >> 4) * 32;
    } else if (t < 5376) {               // W_self -> WgcT k 512..1024
        int u = t - 5120;
        in = W_self; out = WT + 4980736 + 512; N = 512; ldo = 1024;
        n0 = (u & 15) * 32; k0 = (u >> 4) * 32;
    } else if (t < 7680) {               // W_match [1536][1536]
        int u = t - 5376;
        in = W_match; out = WT + 5505024; N = 1536; ldo = 1536;
        n0 = (u % 48) * 32; k0 = (u / 48) * 32;
    } else {                             // W_lin [1536][512] (rows follow W_match: merged B)
        int u = t - 7680;
        in = W_lin; out = WT + 7864320; N = 512; ldo = 1536;
        n0 = (u & 15) * 32; k0 = (u >> 4) * 32;
    }
    __shared__ float tt[32][33];
    int tx = threadIdx.x & 31, ty = threadIdx.x >> 5;
    #pragma unroll
    for (int i = 0; i < 4; i++) tt[ty + i * 8][tx] = in[(long)(k0 + ty + i * 8) * N + n0 + tx];
    __syncthreads();
    #pragma unroll
    for (int i = 0; i < 4; i++) out[(long)(n0 + ty + i * 8) * ldo + k0 + tx] = f2b(tt[tx][ty + i * 8]);
}

// ---------------- stable partition of each chunk's nodes by speaker ----------------
__global__ __launch_bounds__(256) void partition_kernel(const int* __restrict__ spk,
        int* __restrict__ idx, int* __restrict__ cnts)
{
    int c = blockIdx.x;
    int tid = threadIdx.x;
    int base = c * CH;
    __shared__ int zs[256];
    int zcount = 0;
    for (int i = 0; i < CH / 256; i++) {
        int n = base + tid * (CH / 256) + i;
        if (spk[(n & 255) * 64 + (n >> 8)] == 0) zcount++;
    }
    zs[tid] = zcount; __syncthreads();
    for (int off = 1; off < 256; off <<= 1) {
        int v = (tid >= off) ? zs[tid - off] : 0;
        __syncthreads();
        zs[tid] += v;
        __syncthreads();
    }
    int Z = zs[255];
    int zpos = zs[tid] - zcount;                 // exclusive zeros before my range
    int opos = tid * (CH / 256) - zpos;          // ones before my range
    for (int i = 0; i < CH / 256; i++) {
        int nl = tid * (CH / 256) + i;
        int n = base + nl;
        if (spk[(n & 255) * 64 + (n >> 8)] == 0) idx[base + (zpos++)] = nl;
        else                                     idx[base + Z + (opos++)] = nl;
    }
    if (tid == 0) cnts[c] = Z;
}

// ---------------- em[:, 0:1024) = bf16(features) in node order ----------------
__global__ __launch_bounds__(256) void build_em_x(const float* __restrict__ feats,
                                                  unsigned short* __restrict__ em)
{
    int n = blockIdx.x;
    int tid = threadIdx.x;
    const float* f = feats + remap_row(n) * Dc;
    float4 v = ((const float4*)f)[tid];
    unsigned short* e = em + (long)n * DHc + tid * 4;
    e[0] = f2b(v.x); e[1] = f2b(v.y); e[2] = f2b(v.z); e[3] = f2b(v.w);
}

// ---------------- 128^2 MFMA GEMM, async staging (small/batched shapes) ----------------
template<bool CBF, bool CT, bool BIAS, bool RELU>
__global__ __launch_bounds__(256) void gemm_as(
    const unsigned short* __restrict__ A, const unsigned short* __restrict__ B,
    void* __restrict__ Cv, const float* __restrict__ bias,
    int K, int lda, int ldb, int ldc, long sA, long sB, long sC)
{
    __shared__ __align__(16) unsigned short As[4096];
    __shared__ __align__(16) unsigned short Bs[4096];
    const int tid = threadIdx.x;
    const int z = blockIdx.z;
    const int m0 = blockIdx.y * 128, n0 = blockIdx.x * 128;
    const int lane = tid & 63, wave = tid >> 6;
    const int q = lane >> 4, mr = lane & 15;
    const int wrow = (wave >> 1) * 64, wcol = (wave & 1) * 64;

    const unsigned short* Ag0 = A + z * sA + (long)(m0 + wave * 32 + mr) * lda + q * 8;
    const unsigned short* Ag1 = Ag0 + (long)16 * lda;
    const unsigned short* Bg0 = B + z * sB + (long)(n0 + wave * 32 + mr) * ldb + q * 8;
    const unsigned short* Bg1 = Bg0 + (long)16 * ldb;
    unsigned short* Al0 = As + wave * 1024;
    unsigned short* Bl0 = Bs + wave * 1024;

    floatx4 acc[4][4];
    #pragma unroll
    for (int mt = 0; mt < 4; mt++)
        #pragma unroll
        for (int nt = 0; nt < 4; nt++) acc[mt][nt] = (floatx4){0.f, 0.f, 0.f, 0.f};

    const int ga = (wave >> 1) * 2048;
    const int gb = (wave & 1) * 2048;

    for (int k0 = 0; k0 < K; k0 += 32) {
        glds16(Ag0 + k0, Al0);
        glds16(Ag1 + k0, Al0 + 512);
        glds16(Bg0 + k0, Bl0);
        glds16(Bg1 + k0, Bl0 + 512);
        __syncthreads();
        short8 af[4], bfr[4];
        #pragma unroll
        for (int t = 0; t < 4; t++) {
            af[t]  = *(const short8*)&As[ga + t * 512 + lane * 8];
            bfr[t] = *(const short8*)&Bs[gb + t * 512 + lane * 8];
        }
        #pragma unroll
        for (int mt = 0; mt < 4; mt++)
            #pragma unroll
            for (int nt = 0; nt < 4; nt++)
                acc[mt][nt] = __builtin_amdgcn_mfma_f32_16x16x32_bf16(af[mt], bfr[nt], acc[mt][nt], 0, 0, 0);
        __syncthreads();
    }

    float* Cf = (float*)Cv;
    unsigned short* Cb = (unsigned short*)Cv;
    #pragma unroll
    for (int mt = 0; mt < 4; mt++) {
        #pragma unroll
        for (int nt = 0; nt < 4; nt++) {
            int col = n0 + wcol + nt * 16 + mr;
            float bv = BIAS ? bias[col] : 0.f;
            #pragma unroll
            for (int rg = 0; rg < 4; rg++) {
                int row = m0 + wrow + mt * 16 + q * 4 + rg;
                float v = acc[mt][nt][rg] + bv;
                if (RELU) v = fmaxf(v, 0.f);
                if (CT) {
                    Cb[(long)(row >> 8) * 131072 + (long)col * 256 + (row & 255)] = f2b(v);
                } else {
                    long ci = z * sC + (long)row * ldc + col;
                    if (CBF) Cb[ci] = f2b(v);
                    else     Cf[ci] = v;
                }
            }
        }
    }
}

// ================= 256^2 8-wave deep-pipelined engine core ==================
// BM=BN=256, BK=64 (2 K-halves of 32). LDS: A[2buf][2kh][256][32] + B same = 128 KiB.
// Per K-tile: 4 phases {dsread quad, stage 1 half-slot, (vmcnt@j3), bar, lgkm, 16 MFMA, bar}.
// vmcnt(4) at j=3 leaves exactly tile t+2's (A-kh0,B-kh0) 4 loads in flight; never 0 mid-loop.
// LDS swizzle: col-group g stored at g ^ ((row>>1)&3); staged via pre-swizzled GLOBAL source
// (global_load_lds dest must be linear - rule #21); read with same XOR.
__device__ __forceinline__ void gemm256_loop(
    unsigned short* lp,
    const unsigned short* Ag0, const unsigned short* Ag1,
    const unsigned short* Bg0, const unsigned short* Bg1,
    int NT, int wofs, const int* offA, const int* offB, floatx4 (&acc)[8][4])
{
    // prologue: stage t0{A,B kh0+kh1}, t1{A,B kh0}
    glds16(Ag0,      lp + wofs);                 glds16(Ag1,      lp + 4096 + wofs);
    glds16(Bg0,      lp + 32768 + wofs);         glds16(Bg1,      lp + 32768 + 4096 + wofs);
    glds16(Ag0 + 32, lp + 8192 + wofs);          glds16(Ag1 + 32, lp + 8192 + 4096 + wofs);
    glds16(Bg0 + 32, lp + 32768 + 8192 + wofs);  glds16(Bg1 + 32, lp + 32768 + 8192 + 4096 + wofs);
    glds16(Ag0 + 64, lp + 16384 + wofs);         glds16(Ag1 + 64, lp + 16384 + 4096 + wofs);
    glds16(Bg0 + 64, lp + 32768 + 16384 + wofs); glds16(Bg1 + 64, lp + 32768 + 16384 + 4096 + wofs);
    asm volatile("s_waitcnt vmcnt(4)" ::: "memory");
    SB0; BAR; SB0;

    for (int t = 0; t < NT; t++) {
        const int buf = t & 1;
        const int ab  = buf * 16384;
        short8 aF[4], bF[4];

        // phase j=0: quad mt0-3 x kh0 ; stage (t+1, A, kh1) -> buf^1
        #pragma unroll
        for (int i = 0; i < 4; i++) aF[i] = *(const short8*)(lp + ab + offA[i]);
        #pragma unroll
        for (int i = 0; i < 4; i++) bF[i] = *(const short8*)(lp + 32768 + ab + offB[i]);
        if (t + 1 < NT) {
            const int kc = (t + 1) * 64 + 32;
            unsigned short* d = lp + (buf ^ 1) * 16384 + 8192 + wofs;
            glds16(Ag0 + kc, d); glds16(Ag1 + kc, d + 4096);
        }
        SB0; BAR; SB0;
        asm volatile("s_waitcnt lgkmcnt(0)" ::: "memory"); SB0;
        __builtin_amdgcn_s_setprio(1);
        #pragma unroll
        for (int mt = 0; mt < 4; mt++)
            #pragma unroll
            for (int nt = 0; nt < 4; nt++)
                acc[mt][nt] = __builtin_amdgcn_mfma_f32_16x16x32_bf16(aF[mt], bF[nt], acc[mt][nt], 0, 0, 0);
        __builtin_amdgcn_s_setprio(0);
        SB0; BAR; SB0;

        // phase j=1: quad mt4-7 x kh0 (bF reused) ; stage (t+1, B, kh1) -> buf^1
        #pragma unroll
        for (int i = 0; i < 4; i++) aF[i] = *(const short8*)(lp + ab + offA[4 + i]);
        if (t + 1 < NT) {
            const int kc = (t + 1) * 64 + 32;
            unsigned short* d = lp + 32768 + (buf ^ 1) * 16384 + 8192 + wofs;
            glds16(Bg0 + kc, d); glds16(Bg1 + kc, d + 4096);
        }
        SB0; BAR; SB0;
        asm volatile("s_waitcnt lgkmcnt(0)" ::: "memory"); SB0;
        __builtin_amdgcn_s_setprio(1);
        #pragma unroll
        for (int mt = 0; mt < 4; mt++)
            #pragma unroll
            for (int nt = 0; nt < 4; nt++)
                acc[4 + mt][nt] = __builtin_amdgcn_mfma_f32_16x16x32_bf16(aF[mt], bF[nt], acc[4 + mt][nt], 0, 0, 0);
        __builtin_amdgcn_s_setprio(0);
        SB0; BAR; SB0;

        // phase j=2: quad mt0-3 x kh1 ; stage (t+2, A, kh0) -> buf (kh0 dead after j=1)
        #pragma unroll
        for (int i = 0; i < 4; i++) aF[i] = *(const short8*)(lp + ab + 8192 + offA[i]);
        #pragma unroll
        for (int i = 0; i < 4; i++) bF[i] = *(const short8*)(lp + 32768 + ab + 8192 + offB[i]);
        if (t + 2 < NT) {
            const int kc = (t + 2) * 64;
            unsigned short* d = lp + buf * 16384 + wofs;
            glds16(Ag0 + kc, d); glds16(Ag1 + kc, d + 4096);
        }
        SB0; BAR; SB0;
        asm volatile("s_waitcnt lgkmcnt(0)" ::: "memory"); SB0;
        __builtin_amdgcn_s_setprio(1);
        #pragma unroll
        for (int mt = 0; mt < 4; mt++)
            #pragma unroll
            for (int nt = 0; nt < 4; nt++)
                acc[mt][nt] = __builtin_amdgcn_mfma_f32_16x16x32_bf16(aF[mt], bF[nt], acc[mt][nt], 0, 0, 0);
        __builtin_amdgcn_s_setprio(0);
        SB0; BAR; SB0;

        // phase j=3: quad mt4-7 x kh1 (bF reused) ; stage (t+2, B, kh0) -> buf ; counted wait
        #pragma unroll
        for (int i = 0; i < 4; i++) aF[i] = *(const short8*)(lp + ab + 8192 + offA[4 + i]);
        if (t + 2 < NT) {
            const int kc = (t + 2) * 64;
            unsigned short* d = lp + 32768 + buf * 16384 + wofs;
            glds16(Bg0 + kc, d); glds16(Bg1 + kc, d + 4096);
        }
        if (t < NT - 2)       { asm volatile("s_waitcnt vmcnt(4)" ::: "memory"); }
        else if (t == NT - 2) { asm volatile("s_waitcnt vmcnt(0)" ::: "memory"); }
        SB0; BAR; SB0;
        asm volatile("s_waitcnt lgkmcnt(0)" ::: "memory"); SB0;
        __builtin_amdgcn_s_setprio(1);
        #pragma unroll
        for (int mt = 0; mt < 4; mt++)
            #pragma unroll
            for (int nt = 0; nt < 4; nt++)
                acc[4 + mt][nt] = __builtin_amdgcn_mfma_f32_16x16x32_bf16(aF[mt], bF[nt], acc[4 + mt][nt], 0, 0, 0);
        __builtin_amdgcn_s_setprio(0);
        SB0; BAR; SB0;
    }
}

// helper: per-kernel fragment offsets
__device__ __forceinline__ void frag_offsets(int wm, int wn, int q, int mr, int* offA, int* offB)
{
    #pragma unroll
    for (int mt = 0; mt < 8; mt++) {
        int row = wm * 128 + mt * 16 + mr;
        offA[mt] = row * 32 + ((q ^ ((row >> 1) & 3)) * 8);
    }
    #pragma unroll
    for (int nt = 0; nt < 4; nt++) {
        int row = wn * 64 + nt * 16 + mr;
        offB[nt] = row * 32 + ((q ^ ((row >> 1) & 3)) * 8);
    }
}

// ---------------- generic 256^2 GEMM (used for h2) ----------------
template<bool CBF, bool CT, bool BIAS, bool RELU>
__global__ __launch_bounds__(512, 2) void gemm256(
    const unsigned short* __restrict__ A, const unsigned short* __restrict__ B,
    void* __restrict__ Cv, const float* __restrict__ bias,
    int K, int lda, int ldb, int ldc)
{
    __shared__ __align__(16) unsigned short LDS[65536];
    unsigned short* lp = &LDS[0];
    const int tid  = threadIdx.x;
    const int lane = tid & 63, wave = tid >> 6;
    const int wm = wave >> 2, wn = wave & 3;
    const int m0 = blockIdx.y * 256, n0 = blockIdx.x * 256;
    const int NT = K >> 6;
    const int q = lane >> 4, mr = lane & 15;

    const int r0 = wave * 16 + (lane >> 2);
    const int r1 = r0 + 128;
    const int c0 = ((lane & 3) ^ ((r0 >> 1) & 3)) * 8;
    const int c1 = ((lane & 3) ^ ((r1 >> 1) & 3)) * 8;
    const unsigned short* Ag0 = A + (long)(m0 + r0) * lda + c0;
    const unsigned short* Ag1 = A + (long)(m0 + r1) * lda + c1;
    const unsigned short* Bg0 = B + (long)(n0 + r0) * ldb + c0;
    const unsigned short* Bg1 = B + (long)(n0 + r1) * ldb + c1;
    const int wofs = wave * 512;

    int offA[8], offB[4];
    frag_offsets(wm, wn, q, mr, offA, offB);

    floatx4 acc[8][4];
    #pragma unroll
    for (int mt = 0; mt < 8; mt++)
        #pragma unroll
        for (int nt = 0; nt < 4; nt++) acc[mt][nt] = (floatx4){0.f, 0.f, 0.f, 0.f};

    gemm256_loop(lp, Ag0, Ag1, Bg0, Bg1, NT, wofs, offA, offB, acc);

    float* Cf = (float*)Cv;
    unsigned short* Cb = (unsigned short*)Cv;
    #pragma unroll
    for (int mt = 0; mt < 8; mt++) {
        #pragma unroll
        for (int nt = 0; nt < 4; nt++) {
            int col = n0 + wn * 64 + nt * 16 + mr;
            float bv = BIAS ? bias[col] : 0.f;
            #pragma unroll
            for (int rg = 0; rg < 4; rg++) {
                int row = m0 + wm * 128 + mt * 16 + q * 4 + rg;
                float v = acc[mt][nt][rg] + bv;
                if (RELU) v = fmaxf(v, 0.f);
                if (CT) {
                    Cb[(long)(row >> 8) * 131072 + (long)col * 256 + (row & 255)] = f2b(v);
                } else {
                    long ci = (long)row * ldc + col;
                    if (CBF) Cb[ci] = f2b(v);
                    else     Cf[ci] = v;
                }
            }
        }
    }
}

// ---------------- RGCN 256^2: both speaker segments + root in ONE dispatch per chunk -----------
// blockIdx.x = col-tile 0..9 (cols x*256 of hall4's 2560; x<8 -> speaker rel block, x>=8 -> root).
// blockIdx.y enumerates 256-row tiles across segment s=0 (rows idx[0..cnt0)) then s=1.
// A rows gathered per-lane via idx (global_load_lds source is per-lane; dest stays linear).
__global__ __launch_bounds__(512, 2) void rgcn256(
    const unsigned short* __restrict__ A, const unsigned short* __restrict__ B,
    unsigned short* __restrict__ C, const int* __restrict__ idx,
    const int* __restrict__ cntp)
{
    const int cnt0 = *cntp;
    const int t0 = (cnt0 + 255) >> 8;
    const int M1 = CH - cnt0;
    const int t1 = (M1 + 255) >> 8;
    const int ty = blockIdx.y;
    int sblk, m0, M, off;
    if (ty < t0)           { sblk = 0; m0 = ty << 8;        M = cnt0; off = 0; }
    else if (ty < t0 + t1) { sblk = 1; m0 = (ty - t0) << 8; M = M1;   off = cnt0; }
    else return;

    const int x = blockIdx.x;
    const int brow = ((x < 8) ? sblk * 2048 : 2048) + x * 256;   // B row base in WrelT (root at 4096+)

    __shared__ __align__(16) unsigned short LDS[65536];
    unsigned short* lp = &LDS[0];
    const int tid  = threadIdx.x;
    const int lane = tid & 63, wave = tid >> 6;
    const int wm = wave >> 2, wn = wave & 3;
    const int q = lane >> 4, mr = lane & 15;

    const int r0 = wave * 16 + (lane >> 2);
    const int r1 = r0 + 128;
    const int c0 = ((lane & 3) ^ ((r0 >> 1) & 3)) * 8;
    const int c1 = ((lane & 3) ^ ((r1 >> 1) & 3)) * 8;
    const int gr0 = idx[off + min(m0 + r0, M - 1)];
    const int gr1 = idx[off + min(m0 + r1, M - 1)];
    const unsigned short* Ag0 = A + (long)gr0 * DHc + c0;
    const unsigned short* Ag1 = A + (long)gr1 * DHc + c1;
    const unsigned short* Bg0 = B + (long)(brow + r0) * 1024 + c0;
    const unsigned short* Bg1 = B + (long)(brow + r1) * 1024 + c1;
    const int wofs = wave * 512;

    int offA[8], offB[4];
    frag_offsets(wm, wn, q, mr, offA, offB);

    floatx4 acc[8][4];
    #pragma unroll
    for (int mt = 0; mt < 8; mt++)
        #pragma unroll
        for (int nt = 0; nt < 4; nt++) acc[mt][nt] = (floatx4){0.f, 0.f, 0.f, 0.f};

    gemm256_loop(lp, Ag0, Ag1, Bg0, Bg1, 16 /*K=1024*/, wofs, offA, offB, acc);

    #pragma unroll
    for (int mt = 0; mt < 8; mt++) {
        int rowb = m0 + wm * 128 + mt * 16 + q * 4;
        int cr[4];
        #pragma unroll
        for (int rg = 0; rg < 4; rg++) cr[rg] = idx[off + min(rowb + rg, M - 1)];
        #pragma unroll
        for (int nt = 0; nt < 4; nt++) {
            int col = x * 256 + wn * 64 + nt * 16 + mr;
            #pragma unroll
            for (int rg = 0; rg < 4; rg++)
                C[(long)cr[rg] * 2560 + col] = f2b(acc[mt][nt][rg]);
        }
    }
}

// ---------------- merged xt + emW: B = [W_matchT | W_linT] (2048 x 1536 contiguous) -------------
// blocks x<6 -> xt[row][col] (row-major, +b_match); x>=6 -> emWT per-conv transposed (+b_lin).
__global__ __launch_bounds__(512, 2) void gemm256_mw(
    const unsigned short* __restrict__ A, const unsigned short* __restrict__ B,
    unsigned short* __restrict__ xt, unsigned short* __restrict__ emWT,
    const float* __restrict__ b_match, const float* __restrict__ b_lin)
{
    __shared__ __align__(16) unsigned short LDS[65536];
    unsigned short* lp = &LDS[0];
    const int tid  = threadIdx.x;
    const int lane = tid & 63, wave = tid >> 6;
    const int wm = wave >> 2, wn = wave & 3;
    const int m0 = blockIdx.y * 256, n0 = blockIdx.x * 256;
    const int q = lane >> 4, mr = lane & 15;

    const int r0 = wave * 16 + (lane >> 2);
    const int r1 = r0 + 128;
    const int c0 = ((lane & 3) ^ ((r0 >> 1) & 3)) * 8;
    const int c1 = ((lane & 3) ^ ((r1 >> 1) & 3)) * 8;
    const unsigned short* Ag0 = A + (long)(m0 + r0) * DHc + c0;
    const unsigned short* Ag1 = A + (long)(m0 + r1) * DHc + c1;
    const unsigned short* Bg0 = B + (long)(n0 + r0) * 1536 + c0;
    const unsigned short* Bg1 = B + (long)(n0 + r1) * 1536 + c1;
    const int wofs = wave * 512;

    int offA[8], offB[4];
    frag_offsets(wm, wn, q, mr, offA, offB);

    floatx4 acc[8][4];
    #pragma unroll
    for (int mt = 0; mt < 8; mt++)
        #pragma unroll
        for (int nt = 0; nt < 4; nt++) acc[mt][nt] = (floatx4){0.f, 0.f, 0.f, 0.f};

    gemm256_loop(lp, Ag0, Ag1, Bg0, Bg1, 24 /*K=1536*/, wofs, offA, offB, acc);

    if (n0 < 1536) {
        #pragma unroll
        for (int mt = 0; mt < 8; mt++) {
            #pragma unroll
            for (int nt = 0; nt < 4; nt++) {
                int col = n0 + wn * 64 + nt * 16 + mr;
                float bv = b_match[col];
                #pragma unroll
                for (int rg = 0; rg < 4; rg++) {
                    int row = m0 + wm * 128 + mt * 16 + q * 4 + rg;
                    xt[(long)row * DHc + col] = f2b(acc[mt][nt][rg] + bv);
                }
            }
        }
    } else {
        #pragma unroll
        for (int mt = 0; mt < 8; mt++) {
            #pragma unroll
            for (int nt = 0; nt < 4; nt++) {
                int col = (n0 - 1536) + wn * 64 + nt * 16 + mr;
                float bv = b_lin[col];
                #pragma unroll
                for (int rg = 0; rg < 4; rg++) {
                    int row = m0 + wm * 128 + mt * 16 + q * 4 + rg;
                    emWT[(long)(row >> 8) * 131072 + (long)col * 256 + (row & 255)] =
                        f2b(acc[mt][nt][rg] + bv);
                }
            }
        }
    }
}

// ---------------- edge_norm: windowed softmax over k (scale node-ordered) ----------------
__global__ __launch_bounds__(256) void edge_norm_kernel(const float* __restrict__ scale,
                                                        float* __restrict__ enorm)
{
    int g = blockIdx.x * 256 + threadIdx.x;   // b*L + j
    int b = g >> 8, j = g & 255;
    int klo = max(0, j - WINc), khi = min(Lc - 1, j + WINc);
    float vals[NWc];
    float m = -1e30f;
    for (int k = klo; k <= khi; k++) {
        float v = scale[(long)((b << 8) + k) * Lc + j];
        vals[k - klo] = v;
        m = fmaxf(m, v);
    }
    float s = 0.f;
    for (int k = klo; k <= khi; k++) {
        float e = expf(vals[k - klo] - m);
        vals[k - klo] = e;
        s += e;
    }
    float inv = 1.f / s;
    for (int k = klo; k <= khi; k++)
        enorm[(long)g * NWc + (k - j + WINc)] = vals[k - klo] * inv;
}

// ---------------- RGCN aggregation (hall4 bf16 [CH][2560]: 4 dst-sel blocks + root) ----------------
__global__ __launch_bounds__(256) void rgcn_gather4(const unsigned short* __restrict__ hall4,
        const float* __restrict__ enorm, const int* __restrict__ spk,
        const float* __restrict__ b_rgcn, float* __restrict__ h1, int chunk_base)
{
    int nloc = blockIdx.x;
    int n = chunk_base + nloc;
    int b = n >> 8, k = n & 255;
    int tid = threadIdx.x;
    int spkk = spk[k * 64 + b];
    int jlo = max(0, k - WINc), jhi = min(Lc - 1, k + WINc);
    unsigned int ru = *(const unsigned int*)(hall4 + (long)nloc * 2560 + 2048 + 2 * tid);
    float a0 = bf2f((unsigned short)(ru & 0xffff)) + b_rgcn[2 * tid];
    float a1 = bf2f((unsigned short)(ru >> 16)) + b_rgcn[2 * tid + 1];
    int cb = spkk * 2;
    for (int j = jlo; j <= jhi; j++) {
        int c = cb + ((j < k) ? 0 : 1);
        float w = enorm[((long)((b << 8) + j)) * NWc + (k - j + WINc)];
        unsigned int u = *(const unsigned int*)(hall4 + ((long)(nloc - k + j)) * 2560 + c * 512 + 2 * tid);
        a0 += w * bf2f((unsigned short)(u & 0xffff));
        a1 += w * bf2f((unsigned short)(u >> 16));
    }
    *(float2*)&h1[(long)n * Hc + 2 * tid] = make_float2(a0, a1);
}

// ---------------- anh1 = bf16[ concat(window-sum(h1), h1) ]  [N][1024] ----------------
__global__ __launch_bounds__(256) void build_anh1(const float* __restrict__ h1,
                                                  unsigned short* __restrict__ anh1)
{
    int n = blockIdx.x;
    int b = n >> 8, k = n & 255;
    int tid = threadIdx.x;
    int jlo = max(0, k - WINc), jhi = min(Lc - 1, k + WINc);
    float a0 = 0.f, a1 = 0.f;
    for (int j = jlo; j <= jhi; j++) {
        const float* src = h1 + ((long)((b << 8) + j)) * Hc;
        a0 += src[tid];
        a1 += src[tid + 256];
    }
    unsigned short* dst = anh1 + (long)n * 1024;
    const float* self = h1 + (long)n * Hc;
    dst[tid]       = f2b(a0);
    dst[tid + 256] = f2b(a1);
    dst[tid + 512] = f2b(self[tid]);
    dst[tid + 768] = f2b(self[tid + 256]);
}

// ---------------- tanh + row softmax -> bf16 attention weights ----------------
__global__ __launch_bounds__(256) void tanh_softmax_rows(const float* __restrict__ S,
                                                         unsigned short* __restrict__ a)
{
    int row = blockIdx.x;
    int tid = threadIdx.x;
    __shared__ float red[256];
    float v = tanhf(S[(long)row * Lc + tid]);
    red[tid] = v; __syncthreads();
    for (int s = 128; s > 0; s >>= 1) { if (tid < s) red[tid] = fmaxf(red[tid], red[tid + s]); __syncthreads(); }
    float m = red[0]; __syncthreads();
    float e = expf(v - m);
    red[tid] = e; __syncthreads();
    for (int s = 128; s > 0; s >>= 1) { if (tid < s) red[tid] += red[tid + s]; __syncthreads(); }
    float sum = red[0];
    a[(long)row * Lc + tid] = f2b(e / sum);
}

// ---------------- final classifier + log_softmax (fp32 out) ----------------
__global__ __launch_bounds__(256) void out_kernel(const unsigned short* __restrict__ hidden,
        const float* __restrict__ Wfc, const float* __restrict__ bfc, float* __restrict__ out)
{
    int tid = threadIdx.x;
    int lane = tid & 63;
    int row = blockIdx.x * 4 + (tid >> 6);
    float acc[Cc] = {};
    const unsigned short* h = hidden + (long)row * Hc;
    for (int k = lane; k < Hc; k += 64) {
        float hv = bf2f(h[k]);
        #pragma unroll
        for (int c = 0; c < Cc; c++) acc[c] += hv * Wfc[k * Cc + c];
    }
    #pragma unroll
    for (int c = 0; c < Cc; c++)
        for (int off = 32; off > 0; off >>= 1) acc[c] += __shfl_down(acc[c], off, 64);
    if (lane == 0) {
        float m = -1e30f;
        #pragma unroll
        for (int c = 0; c < Cc; c++) { acc[c] += bfc[c]; m = fmaxf(m, acc[c]); }
        float s = 0.f;
        #pragma unroll
        for (int c = 0; c < Cc; c++) s += expf(acc[c] - m);
        float lse = logf(s);
        #pragma unroll
        for (int c = 0; c < Cc; c++) out[(long)row * Cc + c] = acc[c] - m - lse;
    }
}

extern "C" void kernel_launch(void* const* d_in, const int* in_sizes, int n_in,
                              void* d_out, int out_size, void* d_ws, size_t ws_size,
                              hipStream_t stream)
{
    const float* feats   = (const float*)d_in[0];
    const float* Wscalar = (const float*)d_in[1];
    const float* W_rel   = (const float*)d_in[2];
    const float* W_root  = (const float*)d_in[3];
    const float* b_rgcn  = (const float*)d_in[4];
    const float* W_nbr   = (const float*)d_in[5];
    const float* W_self  = (const float*)d_in[6];
    const float* b_gc    = (const float*)d_in[7];
    const float* W_match = (const float*)d_in[8];
    const float* b_match = (const float*)d_in[9];
    const float* W_lin   = (const float*)d_in[10];
    const float* b_lin   = (const float*)d_in[11];
    const float* W_fc    = (const float*)d_in[12];
    const float* b_fc    = (const float*)d_in[13];
    const int*   spk     = (const int*)d_in[14];

    char* wsb = (char*)d_ws;
    unsigned short* em    = (unsigned short*)wsb;               // [0,48M) persistent
    char* RB = wsb + 50331648;                                  // time-multiplexed region (48M)
    float*          scale = (float*)RB;                         // 16M  (steps 1-2)
    unsigned short* hall4 = (unsigned short*)RB;                // 41.9M (RGCN loop)
    unsigned short* anh1  = (unsigned short*)RB;                // 32M  (anh1 -> h2)
    unsigned short* xt    = (unsigned short*)RB;                // 48M  (xt -> S)
    unsigned short* hidden= (unsigned short*)(RB + 16777216);   // 16M  (after S; xt dead)
    char* HB = wsb + 100663296;                                 // second region (32M)
    float*          h1    = (float*)HB;                         // 32M (RGCN -> build_anh1; then dead)
    float*          S     = (float*)HB;                         // 16M (step 6 -> 7; h1 dead)
    unsigned short* emWT  = (unsigned short*)(wsb + 117440512); // 16M HB[16,32M) (step 5 -> 9)
    int* idx              = (int*)(HB + 16777216);              // 64K (read before gather(c1) clobbers)
    int* cnts             = (int*)(HB + 16777216 + 65536);      // 8B  (same)
    unsigned short* WT    = (unsigned short*)(wsb + 134217728); // 17.3M persistent (dead after step 5)
    unsigned short* WscalarT = WT;
    unsigned short* WrelT    = WT + 262144;      // 4608x1024: rels 0..7 then root at 4096..4608
    unsigned short* WgcT     = WT + 4980736;     // 512x1024 (nbr k0..512 | self k512..1024)
    unsigned short* WmatchT  = WT + 5505024;     // 1536x1536, then W_lin 512x1536 contiguous
    unsigned short* ac    = (unsigned short*)(wsb + 134217728); // 8M over dead WT head (step 7 -> 9)
    float*          enorm = (float*)(wsb + 151519232);          // 1.31M

    // ---- 0a. all weight transposes (1 launch)
    transpose_all<<<dim3(8448), 256, 0, stream>>>(Wscalar, W_rel, W_root, W_nbr, W_self,
                                                  W_match, W_lin, WT);
    // ---- 0b. speaker partition per chunk
    partition_kernel<<<dim3(2), 256, 0, stream>>>(spk, idx, cnts);
    // ---- 0c. em[:, 0:1024) = bf16 features, node order
    build_em_x<<<dim3(Nc), 256, 0, stream>>>(feats, em);

    // ---- 1. scale = x @ Wscalar  [16384 x 256]
    gemm_as<false, false, false, false><<<dim3(2, 128, 1), 256, 0, stream>>>(
        em, WscalarT, scale, nullptr, 1024, DHc, 1024, 256, 0, 0, 0);

    // ---- 2. windowed softmax
    edge_norm_kernel<<<dim3(64), 256, 0, stream>>>(scale, enorm);

    // ---- 3. RGCN per chunk: ONE 256^2 dispatch (both speakers + root), then gather
    for (int c = 0; c < 2; c++) {
        const unsigned short* emc = em + (long)c * CH * DHc;
        rgcn256<<<dim3(10, 33, 1), 512, 0, stream>>>(
            emc, WrelT, hall4, idx + c * CH, cnts + c);
        rgcn_gather4<<<dim3(CH), 256, 0, stream>>>(hall4, enorm, spk, b_rgcn, h1, c * CH);
    }

    // ---- 4. anh1 = concat(window-sum(h1), h1); h2 -> em[:, 1024:1536)   [256^2 engine]
    build_anh1<<<dim3(Nc), 256, 0, stream>>>(h1, anh1);
    gemm256<true, false, true, false><<<dim3(2, 64, 1), 512, 0, stream>>>(
        anh1, WgcT, em + 1024, b_gc, 1024, 1024, 1024, DHc);

    // ---- 5. merged: xt = em @ W_match + b_match  AND  emWT = (em @ W_lin + b_lin)^T per conv
    gemm256_mw<<<dim3(8, 64, 1), 512, 0, stream>>>(
        em, WmatchT, xt, emWT, b_match, b_lin);

    // ---- 6. S_b = xt_b @ em_b^T  (z = 64 convs)
    gemm_as<false, false, false, false><<<dim3(2, 2, 64), 256, 0, stream>>>(
        xt, em, S, nullptr, DHc, DHc, DHc, 256, 393216, 393216, 65536);

    // ---- 7. a = softmax(tanh(S))
    tanh_softmax_rows<<<dim3(Nc), 256, 0, stream>>>(S, ac);

    // ---- 9. hidden = relu(a @ emW)  (z = 64 convs, bf16 out)
    gemm_as<true, false, false, true><<<dim3(4, 2, 64), 256, 0, stream>>>(
        ac, emWT, hidden, nullptr, 256, 256, 256, 512, 65536, 131072, 131072);

    // ---- 10. logits + log_softmax
    out_kernel<<<dim3(Nc / 4), 256, 0, stream>>>(hidden, W_fc, b_fc, (float*)d_out);
}

// Round 4
// 707.774 us; speedup vs baseline: 1.3112x; 1.0139x over previous
//
#include <hip/hip_runtime.h>
#include <hip/hip_bf16.h>

// Problem constants
#define Lc 256
#define Bc 64
#define Dc 1024
#define Hc 512
#define Rc 8
#define Cc 6
#define WINc 10
#define NWc 21
#define Nc (Bc*Lc)        // 16384
#define DHc (Dc+Hc)       // 1536
#define CH 8192           // RGCN chunk (32 conversations)

typedef __attribute__((ext_vector_type(8))) short short8;
typedef __attribute__((ext_vector_type(4))) float floatx4;

__device__ inline unsigned short f2b(float x) {
    __hip_bfloat16 h = __float2bfloat16(x);
    return *reinterpret_cast<unsigned short*>(&h);
}
__device__ inline float bf2f(unsigned short u) {
    __hip_bfloat16 h;
    *reinterpret_cast<unsigned short*>(&h) = u;
    return __bfloat162float(h);
}

// node id n = b*256+s  ->  feats row s*64+b
__device__ inline long remap_row(int node) { return (long)(((node & 255) << 6) + (node >> 8)); }

typedef __attribute__((address_space(3))) unsigned int lds_u32;
typedef __attribute__((address_space(1))) unsigned int glb_u32;
__device__ inline void glds16(const unsigned short* g, unsigned short* l) {
    __builtin_amdgcn_global_load_lds((const glb_u32*)g, (lds_u32*)l, 16, 0, 0);
}

#define SB0 __builtin_amdgcn_sched_barrier(0)
#define BAR __builtin_amdgcn_s_barrier()

// bijective XCD-aware remap (m204): hw-bid b -> XCD b&7 (HW heuristic); give each XCD a
// contiguous logical range; decompose x-inner so one XCD sweeps all col-tiles of its rows
// (A-panel stays hot in that XCD's L2 -> kills the 4x A re-fetch seen in round 3).
__device__ __forceinline__ void xcd_remap(int gridX, int& x, int& y)
{
    int nwg = gridDim.x * gridDim.y;
    int bid = blockIdx.y * gridDim.x + blockIdx.x;
    int q = nwg >> 3, r = nwg & 7;
    int xcd = bid & 7, pos = bid >> 3;
    int logical = xcd * q + min(xcd, r) + pos;
    x = logical % gridX;
    y = logical / gridX;
}

// ---------------- all weight transposes in ONE launch (fp32 [K][N] -> bf16 [N][K]) ----------------
__global__ __launch_bounds__(256) void transpose_all(
    const float* __restrict__ Wscalar, const float* __restrict__ W_rel,
    const float* __restrict__ W_root, const float* __restrict__ W_nbr,
    const float* __restrict__ W_self, const float* __restrict__ W_match,
    const float* __restrict__ W_lin, unsigned short* __restrict__ WT)
{
    int t = blockIdx.x;
    const float* in; unsigned short* out; int N, ldo, n0, k0;
    if (t < 256) {                       // Wscalar [1024][256] -> [256][1024]
        in = Wscalar; out = WT; N = 256; ldo = 1024;
        n0 = (t & 7) * 32; k0 = (t >> 3) * 32;
    } else if (t < 4352) {               // W_rel 8x[1024][512] -> rows r*512..
        int u = t - 256; int r = u >> 9; u &= 511;
        in = W_rel + (long)r * 524288; out = WT + 262144 + (long)r * 524288; N = 512; ldo = 1024;
        n0 = (u & 15) * 32; k0 = (u >> 4) * 32;
    } else if (t < 4864) {               // W_root -> WrelT rows 4096..4608
        int u = t - 4352;
        in = W_root; out = WT + 262144 + 4096 * 1024; N = 512; ldo = 1024;
        n0 = (u & 15) * 32; k0 = (u >> 4) * 32;
    } else if (t < 5120) {               // W_nbr -> WgcT k 0..512
        int u = t - 4864;
        in = W_nbr; out = WT + 4980736; N = 512; ldo = 1024;
        n0 = (u & 15) * 32; k0 = (u >> 4) * 32;
    } else if (t < 5376) {               // W_self -> WgcT k 512..1024
        int u = t - 5120;
        in = W_self; out = WT + 4980736 + 512; N = 512; ldo = 1024;
        n0 = (u & 15) * 32; k0 = (u >> 4) * 32;
    } else if (t < 7680) {               // W_match [1536][1536]
        int u = t - 5376;
        in = W_match; out = WT + 5505024; N = 1536; ldo = 1536;
        n0 = (u % 48) * 32; k0 = (u / 48) * 32;
    } else {                             // W_lin [1536][512] (rows follow W_match: merged B)
        int u = t - 7680;
        in = W_lin; out = WT + 7864320; N = 512; ldo = 1536;
        n0 = (u & 15) * 32; k0 = (u >> 4) * 32;
    }
    __shared__ float tt[32][33];
    int tx = threadIdx.x & 31, ty = threadIdx.x >> 5;
    #pragma unroll
    for (int i = 0; i < 4; i++) tt[ty + i * 8][tx] = in[(long)(k0 + ty + i * 8) * N + n0 + tx];
    __syncthreads();
    #pragma unroll
    for (int i = 0; i < 4; i++) out[(long)(n0 + ty + i * 8) * ldo + k0 + tx] = f2b(tt[tx][ty + i * 8]);
}

// ---------------- stable partition of each chunk's nodes by speaker ----------------
__global__ __launch_bounds__(256) void partition_kernel(const int* __restrict__ spk,
        int* __restrict__ idx, int* __restrict__ cnts)
{
    int c = blockIdx.x;
    int tid = threadIdx.x;
    int base = c * CH;
    __shared__ int zs[256];
    int zcount = 0;
    for (int i = 0; i < CH / 256; i++) {
        int n = base + tid * (CH / 256) + i;
        if (spk[(n & 255) * 64 + (n >> 8)] == 0) zcount++;
    }
    zs[tid] = zcount; __syncthreads();
    for (int off = 1; off < 256; off <<= 1) {
        int v = (tid >= off) ? zs[tid - off] : 0;
        __syncthreads();
        zs[tid] += v;
        __syncthreads();
    }
    int Z = zs[255];
    int zpos = zs[tid] - zcount;                 // exclusive zeros before my range
    int opos = tid * (CH / 256) - zpos;          // ones before my range
    for (int i = 0; i < CH / 256; i++) {
        int nl = tid * (CH / 256) + i;
        int n = base + nl;
        if (spk[(n & 255) * 64 + (n >> 8)] == 0) idx[base + (zpos++)] = nl;
        else                                     idx[base + Z + (opos++)] = nl;
    }
    if (tid == 0) cnts[c] = Z;
}

// ---------------- em[:, 0:1024) = bf16(features) in node order ----------------
__global__ __launch_bounds__(256) void build_em_x(const float* __restrict__ feats,
                                                  unsigned short* __restrict__ em)
{
    int n = blockIdx.x;
    int tid = threadIdx.x;
    const float* f = feats + remap_row(n) * Dc;
    float4 v = ((const float4*)f)[tid];
    unsigned short* e = em + (long)n * DHc + tid * 4;
    e[0] = f2b(v.x); e[1] = f2b(v.y); e[2] = f2b(v.z); e[3] = f2b(v.w);
}

// ---------------- 128^2 MFMA GEMM, async staging (small/batched shapes) ----------------
template<bool CBF, bool CT, bool BIAS, bool RELU>
__global__ __launch_bounds__(256) void gemm_as(
    const unsigned short* __restrict__ A, const unsigned short* __restrict__ B,
    void* __restrict__ Cv, const float* __restrict__ bias,
    int K, int lda, int ldb, int ldc, long sA, long sB, long sC)
{
    __shared__ __align__(16) unsigned short As[4096];
    __shared__ __align__(16) unsigned short Bs[4096];
    const int tid = threadIdx.x;
    const int z = blockIdx.z;
    const int m0 = blockIdx.y * 128, n0 = blockIdx.x * 128;
    const int lane = tid & 63, wave = tid >> 6;
    const int q = lane >> 4, mr = lane & 15;
    const int wrow = (wave >> 1) * 64, wcol = (wave & 1) * 64;

    const unsigned short* Ag0 = A + z * sA + (long)(m0 + wave * 32 + mr) * lda + q * 8;
    const unsigned short* Ag1 = Ag0 + (long)16 * lda;
    const unsigned short* Bg0 = B + z * sB + (long)(n0 + wave * 32 + mr) * ldb + q * 8;
    const unsigned short* Bg1 = Bg0 + (long)16 * ldb;
    unsigned short* Al0 = As + wave * 1024;
    unsigned short* Bl0 = Bs + wave * 1024;

    floatx4 acc[4][4];
    #pragma unroll
    for (int mt = 0; mt < 4; mt++)
        #pragma unroll
        for (int nt = 0; nt < 4; nt++) acc[mt][nt] = (floatx4){0.f, 0.f, 0.f, 0.f};

    const int ga = (wave >> 1) * 2048;
    const int gb = (wave & 1) * 2048;

    for (int k0 = 0; k0 < K; k0 += 32) {
        glds16(Ag0 + k0, Al0);
        glds16(Ag1 + k0, Al0 + 512);
        glds16(Bg0 + k0, Bl0);
        glds16(Bg1 + k0, Bl0 + 512);
        __syncthreads();
        short8 af[4], bfr[4];
        #pragma unroll
        for (int t = 0; t < 4; t++) {
            af[t]  = *(const short8*)&As[ga + t * 512 + lane * 8];
            bfr[t] = *(const short8*)&Bs[gb + t * 512 + lane * 8];
        }
        #pragma unroll
        for (int mt = 0; mt < 4; mt++)
            #pragma unroll
            for (int nt = 0; nt < 4; nt++)
                acc[mt][nt] = __builtin_amdgcn_mfma_f32_16x16x32_bf16(af[mt], bfr[nt], acc[mt][nt], 0, 0, 0);
        __syncthreads();
    }

    float* Cf = (float*)Cv;
    unsigned short* Cb = (unsigned short*)Cv;
    #pragma unroll
    for (int mt = 0; mt < 4; mt++) {
        #pragma unroll
        for (int nt = 0; nt < 4; nt++) {
            int col = n0 + wcol + nt * 16 + mr;
            float bv = BIAS ? bias[col] : 0.f;
            #pragma unroll
            for (int rg = 0; rg < 4; rg++) {
                int row = m0 + wrow + mt * 16 + q * 4 + rg;
                float v = acc[mt][nt][rg] + bv;
                if (RELU) v = fmaxf(v, 0.f);
                if (CT) {
                    Cb[(long)(row >> 8) * 131072 + (long)col * 256 + (row & 255)] = f2b(v);
                } else {
                    long ci = z * sC + (long)row * ldc + col;
                    if (CBF) Cb[ci] = f2b(v);
                    else     Cf[ci] = v;
                }
            }
        }
    }
}

// ================= 256^2 8-wave deep-pipelined engine core ==================
// BM=BN=256, BK=64 (2 K-halves of 32). LDS: A[2buf][2kh][256][32] + B same = 128 KiB.
// Round-4 change: ds_reads are software-pipelined ONE PHASE AHEAD. Each phase issues the
// NEXT quad's fragment reads before its barrier; the MFMA consumes the quad issued one
// phase earlier. Compiler-inserted counted lgkmcnt leaves the new reads in flight, so
// LDS service overlaps MFMA + barrier instead of serializing (round-3: 39% MfmaUtil from
// exposed LDS time). Validity: all of tile t is staged+vmcnt'd by (t-1,j3)+BAR; the
// cross-tile quad Q0(t+1) is issued only after (t,j3)'s vmcnt+BAR. WAR on LDS regions:
// readers complete >=2 barriers before their region is re-staged (ledger per round 2).
// vmcnt(4) at j3 leaves exactly tile t+2's kh0 4 loads in flight; never 0 mid-loop.
#define MFMA16(ACCBASE, AFR, BFR) \
    { _Pragma("unroll") \
      for (int mt = 0; mt < 4; mt++) \
        _Pragma("unroll") \
        for (int nt = 0; nt < 4; nt++) \
            acc[ACCBASE + mt][nt] = __builtin_amdgcn_mfma_f32_16x16x32_bf16(AFR[mt], BFR[nt], acc[ACCBASE + mt][nt], 0, 0, 0); }

__device__ __forceinline__ void gemm256_loop(
    unsigned short* lp,
    const unsigned short* Ag0, const unsigned short* Ag1,
    const unsigned short* Bg0, const unsigned short* Bg1,
    int NT, int wofs, const int* offA, const int* offB, floatx4 (&acc)[8][4])
{
    // prologue: stage t0{A,B kh0+kh1}, t1{A,B kh0}
    glds16(Ag0,      lp + wofs);                 glds16(Ag1,      lp + 4096 + wofs);
    glds16(Bg0,      lp + 32768 + wofs);         glds16(Bg1,      lp + 32768 + 4096 + wofs);
    glds16(Ag0 + 32, lp + 8192 + wofs);          glds16(Ag1 + 32, lp + 8192 + 4096 + wofs);
    glds16(Bg0 + 32, lp + 32768 + 8192 + wofs);  glds16(Bg1 + 32, lp + 32768 + 8192 + 4096 + wofs);
    glds16(Ag0 + 64, lp + 16384 + wofs);         glds16(Ag1 + 64, lp + 16384 + 4096 + wofs);
    glds16(Bg0 + 64, lp + 32768 + 16384 + wofs); glds16(Bg1 + 64, lp + 32768 + 16384 + 4096 + wofs);
    asm volatile("s_waitcnt vmcnt(4)" ::: "memory");
    SB0; BAR; SB0;

    short8 aQ[4], a2Q[4], bQ[4], b2Q[4];
    // preload Q0(t=0): kh0 A mt0-3 + kh0 B
    #pragma unroll
    for (int i = 0; i < 4; i++) aQ[i] = *(const short8*)(lp + offA[i]);
    #pragma unroll
    for (int i = 0; i < 4; i++) bQ[i] = *(const short8*)(lp + 32768 + offB[i]);

    for (int t = 0; t < NT; t++) {
        const int buf = t & 1;
        const int ab  = buf * 16384;

        // ===== j0: stage A(t+1,kh1)->buf^1 ; issue Q1 (kh0 A mt4-7) ; MFMA Q0
        if (t + 1 < NT) {
            const int kc = (t + 1) * 64 + 32;
            unsigned short* d = lp + (buf ^ 1) * 16384 + 8192 + wofs;
            glds16(Ag0 + kc, d); glds16(Ag1 + kc, d + 4096);
        }
        #pragma unroll
        for (int i = 0; i < 4; i++) a2Q[i] = *(const short8*)(lp + ab + offA[4 + i]);
        SB0; BAR; SB0;
        __builtin_amdgcn_s_setprio(1);
        MFMA16(0, aQ, bQ)
        __builtin_amdgcn_s_setprio(0);
        SB0; BAR; SB0;

        // ===== j1: stage B(t+1,kh1)->buf^1 ; issue Q2 (kh1 A mt0-3 + kh1 B) ; MFMA Q1
        if (t + 1 < NT) {
            const int kc = (t + 1) * 64 + 32;
            unsigned short* d = lp + 32768 + (buf ^ 1) * 16384 + 8192 + wofs;
            glds16(Bg0 + kc, d); glds16(Bg1 + kc, d + 4096);
        }
        #pragma unroll
        for (int i = 0; i < 4; i++) aQ[i]  = *(const short8*)(lp + ab + 8192 + offA[i]);
        #pragma unroll
        for (int i = 0; i < 4; i++) b2Q[i] = *(const short8*)(lp + 32768 + ab + 8192 + offB[i]);
        SB0; BAR; SB0;
        __builtin_amdgcn_s_setprio(1);
        MFMA16(4, a2Q, bQ)
        __builtin_amdgcn_s_setprio(0);
        SB0; BAR; SB0;

        // ===== j2: stage A(t+2,kh0)->buf ; issue Q3 (kh1 A mt4-7) ; MFMA Q2
        if (t + 2 < NT) {
            const int kc = (t + 2) * 64;
            unsigned short* d = lp + buf * 16384 + wofs;
            glds16(Ag0 + kc, d); glds16(Ag1 + kc, d + 4096);
        }
        #pragma unroll
        for (int i = 0; i < 4; i++) a2Q[i] = *(const short8*)(lp + ab + 8192 + offA[4 + i]);
        SB0; BAR; SB0;
        __builtin_amdgcn_s_setprio(1);
        MFMA16(0, aQ, b2Q)
        __builtin_amdgcn_s_setprio(0);
        SB0; BAR; SB0;

        // ===== j3: stage B(t+2,kh0)->buf ; counted vmcnt ; BAR ; issue Q0(t+1) ; MFMA Q3
        if (t + 2 < NT) {
            const int kc = (t + 2) * 64;
            unsigned short* d = lp + 32768 + buf * 16384 + wofs;
            glds16(Bg0 + kc, d); glds16(Bg1 + kc, d + 4096);
        }
        if (t < NT - 2)       { asm volatile("s_waitcnt vmcnt(4)" ::: "memory"); }
        else if (t == NT - 2) { asm volatile("s_waitcnt vmcnt(0)" ::: "memory"); }
        SB0; BAR; SB0;
        if (t + 1 < NT) {
            const int ab2 = (buf ^ 1) * 16384;
            #pragma unroll
            for (int i = 0; i < 4; i++) aQ[i] = *(const short8*)(lp + ab2 + offA[i]);
            #pragma unroll
            for (int i = 0; i < 4; i++) bQ[i] = *(const short8*)(lp + 32768 + ab2 + offB[i]);
        }
        SB0;
        __builtin_amdgcn_s_setprio(1);
        MFMA16(4, a2Q, b2Q)
        __builtin_amdgcn_s_setprio(0);
        SB0; BAR; SB0;
    }
}

// helper: per-kernel fragment offsets
__device__ __forceinline__ void frag_offsets(int wm, int wn, int q, int mr, int* offA, int* offB)
{
    #pragma unroll
    for (int mt = 0; mt < 8; mt++) {
        int row = wm * 128 + mt * 16 + mr;
        offA[mt] = row * 32 + ((q ^ ((row >> 1) & 3)) * 8);
    }
    #pragma unroll
    for (int nt = 0; nt < 4; nt++) {
        int row = wn * 64 + nt * 16 + mr;
        offB[nt] = row * 32 + ((q ^ ((row >> 1) & 3)) * 8);
    }
}

// ---------------- generic 256^2 GEMM (used for h2) ----------------
template<bool CBF, bool CT, bool BIAS, bool RELU>
__global__ __launch_bounds__(512, 2) void gemm256(
    const unsigned short* __restrict__ A, const unsigned short* __restrict__ B,
    void* __restrict__ Cv, const float* __restrict__ bias,
    int K, int lda, int ldb, int ldc)
{
    __shared__ __align__(16) unsigned short LDS[65536];
    unsigned short* lp = &LDS[0];
    const int tid  = threadIdx.x;
    const int lane = tid & 63, wave = tid >> 6;
    const int wm = wave >> 2, wn = wave & 3;
    int bx, by;
    xcd_remap(gridDim.x, bx, by);
    const int m0 = by * 256, n0 = bx * 256;
    const int NT = K >> 6;
    const int q = lane >> 4, mr = lane & 15;

    const int r0 = wave * 16 + (lane >> 2);
    const int r1 = r0 + 128;
    const int c0 = ((lane & 3) ^ ((r0 >> 1) & 3)) * 8;
    const int c1 = ((lane & 3) ^ ((r1 >> 1) & 3)) * 8;
    const unsigned short* Ag0 = A + (long)(m0 + r0) * lda + c0;
    const unsigned short* Ag1 = A + (long)(m0 + r1) * lda + c1;
    const unsigned short* Bg0 = B + (long)(n0 + r0) * ldb + c0;
    const unsigned short* Bg1 = B + (long)(n0 + r1) * ldb + c1;
    const int wofs = wave * 512;

    int offA[8], offB[4];
    frag_offsets(wm, wn, q, mr, offA, offB);

    floatx4 acc[8][4];
    #pragma unroll
    for (int mt = 0; mt < 8; mt++)
        #pragma unroll
        for (int nt = 0; nt < 4; nt++) acc[mt][nt] = (floatx4){0.f, 0.f, 0.f, 0.f};

    gemm256_loop(lp, Ag0, Ag1, Bg0, Bg1, NT, wofs, offA, offB, acc);

    float* Cf = (float*)Cv;
    unsigned short* Cb = (unsigned short*)Cv;
    #pragma unroll
    for (int mt = 0; mt < 8; mt++) {
        #pragma unroll
        for (int nt = 0; nt < 4; nt++) {
            int col = n0 + wn * 64 + nt * 16 + mr;
            float bv = BIAS ? bias[col] : 0.f;
            #pragma unroll
            for (int rg = 0; rg < 4; rg++) {
                int row = m0 + wm * 128 + mt * 16 + q * 4 + rg;
                float v = acc[mt][nt][rg] + bv;
                if (RELU) v = fmaxf(v, 0.f);
                if (CT) {
                    Cb[(long)(row >> 8) * 131072 + (long)col * 256 + (row & 255)] = f2b(v);
                } else {
                    long ci = (long)row * ldc + col;
                    if (CBF) Cb[ci] = f2b(v);
                    else     Cf[ci] = v;
                }
            }
        }
    }
}

// ---------------- RGCN 256^2: both speaker segments + root in ONE dispatch per chunk -----------
// col-tile x 0..9 (cols x*256 of hall4's 2560; x<8 -> speaker rel block, x>=8 -> root).
// y enumerates 256-row tiles across segment s=0 (rows idx[0..cnt0)) then s=1.
// A rows gathered per-lane via idx (global_load_lds source is per-lane; dest stays linear).
__global__ __launch_bounds__(512, 2) void rgcn256(
    const unsigned short* __restrict__ A, const unsigned short* __restrict__ B,
    unsigned short* __restrict__ C, const int* __restrict__ idx,
    const int* __restrict__ cntp)
{
    const int cnt0 = *cntp;
    const int t0 = (cnt0 + 255) >> 8;
    const int M1 = CH - cnt0;
    const int t1 = (M1 + 255) >> 8;
    int x, ty;
    xcd_remap(gridDim.x, x, ty);
    int sblk, m0, M, off;
    if (ty < t0)           { sblk = 0; m0 = ty << 8;        M = cnt0; off = 0; }
    else if (ty < t0 + t1) { sblk = 1; m0 = (ty - t0) << 8; M = M1;   off = cnt0; }
    else return;

    const int brow = ((x < 8) ? sblk * 2048 : 2048) + x * 256;   // B row base in WrelT (root at 4096+)

    __shared__ __align__(16) unsigned short LDS[65536];
    unsigned short* lp = &LDS[0];
    const int tid  = threadIdx.x;
    const int lane = tid & 63, wave = tid >> 6;
    const int wm = wave >> 2, wn = wave & 3;
    const int q = lane >> 4, mr = lane & 15;

    const int r0 = wave * 16 + (lane >> 2);
    const int r1 = r0 + 128;
    const int c0 = ((lane & 3) ^ ((r0 >> 1) & 3)) * 8;
    const int c1 = ((lane & 3) ^ ((r1 >> 1) & 3)) * 8;
    const int gr0 = idx[off + min(m0 + r0, M - 1)];
    const int gr1 = idx[off + min(m0 + r1, M - 1)];
    const unsigned short* Ag0 = A + (long)gr0 * DHc + c0;
    const unsigned short* Ag1 = A + (long)gr1 * DHc + c1;
    const unsigned short* Bg0 = B + (long)(brow + r0) * 1024 + c0;
    const unsigned short* Bg1 = B + (long)(brow + r1) * 1024 + c1;
    const int wofs = wave * 512;

    int offA[8], offB[4];
    frag_offsets(wm, wn, q, mr, offA, offB);

    floatx4 acc[8][4];
    #pragma unroll
    for (int mt = 0; mt < 8; mt++)
        #pragma unroll
        for (int nt = 0; nt < 4; nt++) acc[mt][nt] = (floatx4){0.f, 0.f, 0.f, 0.f};

    gemm256_loop(lp, Ag0, Ag1, Bg0, Bg1, 16 /*K=1024*/, wofs, offA, offB, acc);

    #pragma unroll
    for (int mt = 0; mt < 8; mt++) {
        int rowb = m0 + wm * 128 + mt * 16 + q * 4;
        int cr[4];
        #pragma unroll
        for (int rg = 0; rg < 4; rg++) cr[rg] = idx[off + min(rowb + rg, M - 1)];
        #pragma unroll
        for (int nt = 0; nt < 4; nt++) {
            int col = x * 256 + wn * 64 + nt * 16 + mr;
            #pragma unroll
            for (int rg = 0; rg < 4; rg++)
                C[(long)cr[rg] * 2560 + col] = f2b(acc[mt][nt][rg]);
        }
    }
}

// ---------------- merged xt + emW: B = [W_matchT | W_linT] (2048 x 1536 contiguous) -------------
// col-tiles x<6 -> xt[row][col] (row-major, +b_match); x>=6 -> emWT per-conv transposed (+b_lin).
__global__ __launch_bounds__(512, 2) void gemm256_mw(
    const unsigned short* __restrict__ A, const unsigned short* __restrict__ B,
    unsigned short* __restrict__ xt, unsigned short* __restrict__ emWT,
    const float* __restrict__ b_match, const float* __restrict__ b_lin)
{
    __shared__ __align__(16) unsigned short LDS[65536];
    unsigned short* lp = &LDS[0];
    const int tid  = threadIdx.x;
    const int lane = tid & 63, wave = tid >> 6;
    const int wm = wave >> 2, wn = wave & 3;
    int bx, by;
    xcd_remap(gridDim.x, bx, by);
    const int m0 = by * 256, n0 = bx * 256;
    const int q = lane >> 4, mr = lane & 15;

    const int r0 = wave * 16 + (lane >> 2);
    const int r1 = r0 + 128;
    const int c0 = ((lane & 3) ^ ((r0 >> 1) & 3)) * 8;
    const int c1 = ((lane & 3) ^ ((r1 >> 1) & 3)) * 8;
    const unsigned short* Ag0 = A + (long)(m0 + r0) * DHc + c0;
    const unsigned short* Ag1 = A + (long)(m0 + r1) * DHc + c1;
    const unsigned short* Bg0 = B + (long)(n0 + r0) * 1536 + c0;
    const unsigned short* Bg1 = B + (long)(n0 + r1) * 1536 + c1;
    const int wofs = wave * 512;

    int offA[8], offB[4];
    frag_offsets(wm, wn, q, mr, offA, offB);

    floatx4 acc[8][4];
    #pragma unroll
    for (int mt = 0; mt < 8; mt++)
        #pragma unroll
        for (int nt = 0; nt < 4; nt++) acc[mt][nt] = (floatx4){0.f, 0.f, 0.f, 0.f};

    gemm256_loop(lp, Ag0, Ag1, Bg0, Bg1, 24 /*K=1536*/, wofs, offA, offB, acc);

    if (n0 < 1536) {
        #pragma unroll
        for (int mt = 0; mt < 8; mt++) {
            #pragma unroll
            for (int nt = 0; nt < 4; nt++) {
                int col = n0 + wn * 64 + nt * 16 + mr;
                float bv = b_match[col];
                #pragma unroll
                for (int rg = 0; rg < 4; rg++) {
                    int row = m0 + wm * 128 + mt * 16 + q * 4 + rg;
                    xt[(long)row * DHc + col] = f2b(acc[mt][nt][rg] + bv);
                }
            }
        }
    } else {
        #pragma unroll
        for (int mt = 0; mt < 8; mt++) {
            #pragma unroll
            for (int nt = 0; nt < 4; nt++) {
                int col = (n0 - 1536) + wn * 64 + nt * 16 + mr;
                float bv = b_lin[col];
                #pragma unroll
                for (int rg = 0; rg < 4; rg++) {
                    int row = m0 + wm * 128 + mt * 16 + q * 4 + rg;
                    emWT[(long)(row >> 8) * 131072 + (long)col * 256 + (row & 255)] =
                        f2b(acc[mt][nt][rg] + bv);
                }
            }
        }
    }
}

// ---------------- edge_norm: windowed softmax over k (scale node-ordered) ----------------
__global__ __launch_bounds__(256) void edge_norm_kernel(const float* __restrict__ scale,
                                                        float* __restrict__ enorm)
{
    int g = blockIdx.x * 256 + threadIdx.x;   // b*L + j
    int b = g >> 8, j = g & 255;
    int klo = max(0, j - WINc), khi = min(Lc - 1, j + WINc);
    float vals[NWc];
    float m = -1e30f;
    for (int k = klo; k <= khi; k++) {
        float v = scale[(long)((b << 8) + k) * Lc + j];
        vals[k - klo] = v;
        m = fmaxf(m, v);
    }
    float s = 0.f;
    for (int k = klo; k <= khi; k++) {
        float e = expf(vals[k - klo] - m);
        vals[k - klo] = e;
        s += e;
    }
    float inv = 1.f / s;
    for (int k = klo; k <= khi; k++)
        enorm[(long)g * NWc + (k - j + WINc)] = vals[k - klo] * inv;
}

// ---------------- RGCN aggregation (hall4 bf16 [CH][2560]: 4 dst-sel blocks + root) ----------------
__global__ __launch_bounds__(256) void rgcn_gather4(const unsigned short* __restrict__ hall4,
        const float* __restrict__ enorm, const int* __restrict__ spk,
        const float* __restrict__ b_rgcn, float* __restrict__ h1, int chunk_base)
{
    int nloc = blockIdx.x;
    int n = chunk_base + nloc;
    int b = n >> 8, k = n & 255;
    int tid = threadIdx.x;
    int spkk = spk[k * 64 + b];
    int jlo = max(0, k - WINc), jhi = min(Lc - 1, k + WINc);
    unsigned int ru = *(const unsigned int*)(hall4 + (long)nloc * 2560 + 2048 + 2 * tid);
    float a0 = bf2f((unsigned short)(ru & 0xffff)) + b_rgcn[2 * tid];
    float a1 = bf2f((unsigned short)(ru >> 16)) + b_rgcn[2 * tid + 1];
    int cb = spkk * 2;
    for (int j = jlo; j <= jhi; j++) {
        int c = cb + ((j < k) ? 0 : 1);
        float w = enorm[((long)((b << 8) + j)) * NWc + (k - j + WINc)];
        unsigned int u = *(const unsigned int*)(hall4 + ((long)(nloc - k + j)) * 2560 + c * 512 + 2 * tid);
        a0 += w * bf2f((unsigned short)(u & 0xffff));
        a1 += w * bf2f((unsigned short)(u >> 16));
    }
    *(float2*)&h1[(long)n * Hc + 2 * tid] = make_float2(a0, a1);
}

// ---------------- anh1 = bf16[ concat(window-sum(h1), h1) ]  [N][1024] ----------------
__global__ __launch_bounds__(256) void build_anh1(const float* __restrict__ h1,
                                                  unsigned short* __restrict__ anh1)
{
    int n = blockIdx.x;
    int b = n >> 8, k = n & 255;
    int tid = threadIdx.x;
    int jlo = max(0, k - WINc), jhi = min(Lc - 1, k + WINc);
    float a0 = 0.f, a1 = 0.f;
    for (int j = jlo; j <= jhi; j++) {
        const float* src = h1 + ((long)((b << 8) + j)) * Hc;
        a0 += src[tid];
        a1 += src[tid + 256];
    }
    unsigned short* dst = anh1 + (long)n * 1024;
    const float* self = h1 + (long)n * Hc;
    dst[tid]       = f2b(a0);
    dst[tid + 256] = f2b(a1);
    dst[tid + 512] = f2b(self[tid]);
    dst[tid + 768] = f2b(self[tid + 256]);
}

// ---------------- tanh + row softmax -> bf16 attention weights ----------------
__global__ __launch_bounds__(256) void tanh_softmax_rows(const float* __restrict__ S,
                                                         unsigned short* __restrict__ a)
{
    int row = blockIdx.x;
    int tid = threadIdx.x;
    __shared__ float red[256];
    float v = tanhf(S[(long)row * Lc + tid]);
    red[tid] = v; __syncthreads();
    for (int s = 128; s > 0; s >>= 1) { if (tid < s) red[tid] = fmaxf(red[tid], red[tid + s]); __syncthreads(); }
    float m = red[0]; __syncthreads();
    float e = expf(v - m);
    red[tid] = e; __syncthreads();
    for (int s = 128; s > 0; s >>= 1) { if (tid < s) red[tid] += red[tid + s]; __syncthreads(); }
    float sum = red[0];
    a[(long)row * Lc + tid] = f2b(e / sum);
}

// ---------------- final classifier + log_softmax (fp32 out) ----------------
__global__ __launch_bounds__(256) void out_kernel(const unsigned short* __restrict__ hidden,
        const float* __restrict__ Wfc, const float* __restrict__ bfc, float* __restrict__ out)
{
    int tid = threadIdx.x;
    int lane = tid & 63;
    int row = blockIdx.x * 4 + (tid >> 6);
    float acc[Cc] = {};
    const unsigned short* h = hidden + (long)row * Hc;
    for (int k = lane; k < Hc; k += 64) {
        float hv = bf2f(h[k]);
        #pragma unroll
        for (int c = 0; c < Cc; c++) acc[c] += hv * Wfc[k * Cc + c];
    }
    #pragma unroll
    for (int c = 0; c < Cc; c++)
        for (int off = 32; off > 0; off >>= 1) acc[c] += __shfl_down(acc[c], off, 64);
    if (lane == 0) {
        float m = -1e30f;
        #pragma unroll
        for (int c = 0; c < Cc; c++) { acc[c] += bfc[c]; m = fmaxf(m, acc[c]); }
        float s = 0.f;
        #pragma unroll
        for (int c = 0; c < Cc; c++) s += expf(acc[c] - m);
        float lse = logf(s);
        #pragma unroll
        for (int c = 0; c < Cc; c++) out[(long)row * Cc + c] = acc[c] - m - lse;
    }
}

extern "C" void kernel_launch(void* const* d_in, const int* in_sizes, int n_in,
                              void* d_out, int out_size, void* d_ws, size_t ws_size,
                              hipStream_t stream)
{
    const float* feats   = (const float*)d_in[0];
    const float* Wscalar = (const float*)d_in[1];
    const float* W_rel   = (const float*)d_in[2];
    const float* W_root  = (const float*)d_in[3];
    const float* b_rgcn  = (const float*)d_in[4];
    const float* W_nbr   = (const float*)d_in[5];
    const float* W_self  = (const float*)d_in[6];
    const float* b_gc    = (const float*)d_in[7];
    const float* W_match = (const float*)d_in[8];
    const float* b_match = (const float*)d_in[9];
    const float* W_lin   = (const float*)d_in[10];
    const float* b_lin   = (const float*)d_in[11];
    const float* W_fc    = (const float*)d_in[12];
    const float* b_fc    = (const float*)d_in[13];
    const int*   spk     = (const int*)d_in[14];

    char* wsb = (char*)d_ws;
    unsigned short* em    = (unsigned short*)wsb;               // [0,48M) persistent
    char* RB = wsb + 50331648;                                  // time-multiplexed region (48M)
    float*          scale = (float*)RB;                         // 16M  (steps 1-2)
    unsigned short* hall4 = (unsigned short*)RB;                // 41.9M (RGCN loop)
    unsigned short* anh1  = (unsigned short*)RB;                // 32M  (anh1 -> h2)
    unsigned short* xt    = (unsigned short*)RB;                // 48M  (xt -> S)
    unsigned short* hidden= (unsigned short*)(RB + 16777216);   // 16M  (after S; xt dead)
    char* HB = wsb + 100663296;                                 // second region (32M)
    float*          h1    = (float*)HB;                         // 32M (RGCN -> build_anh1; then dead)
    float*          S     = (float*)HB;                         // 16M (step 6 -> 7; h1 dead)
    unsigned short* emWT  = (unsigned short*)(wsb + 117440512); // 16M HB[16,32M) (step 5 -> 9)
    int* idx              = (int*)(HB + 16777216);              // 64K (read before gather(c1) clobbers)
    int* cnts             = (int*)(HB + 16777216 + 65536);      // 8B  (same)
    unsigned short* WT    = (unsigned short*)(wsb + 134217728); // 17.3M persistent (dead after step 5)
    unsigned short* WscalarT = WT;
    unsigned short* WrelT    = WT + 262144;      // 4608x1024: rels 0..7 then root at 4096..4608
    unsigned short* WgcT     = WT + 4980736;     // 512x1024 (nbr k0..512 | self k512..1024)
    unsigned short* WmatchT  = WT + 5505024;     // 1536x1536, then W_lin 512x1536 contiguous
    unsigned short* ac    = (unsigned short*)(wsb + 134217728); // 8M over dead WT head (step 7 -> 9)
    float*          enorm = (float*)(wsb + 151519232);          // 1.31M

    // ---- 0a. all weight transposes (1 launch)
    transpose_all<<<dim3(8448), 256, 0, stream>>>(Wscalar, W_rel, W_root, W_nbr, W_self,
                                                  W_match, W_lin, WT);
    // ---- 0b. speaker partition per chunk
    partition_kernel<<<dim3(2), 256, 0, stream>>>(spk, idx, cnts);
    // ---- 0c. em[:, 0:1024) = bf16 features, node order
    build_em_x<<<dim3(Nc), 256, 0, stream>>>(feats, em);

    // ---- 1. scale = x @ Wscalar  [16384 x 256]
    gemm_as<false, false, false, false><<<dim3(2, 128, 1), 256, 0, stream>>>(
        em, WscalarT, scale, nullptr, 1024, DHc, 1024, 256, 0, 0, 0);

    // ---- 2. windowed softmax
    edge_norm_kernel<<<dim3(64), 256, 0, stream>>>(scale, enorm);

    // ---- 3. RGCN per chunk: ONE 256^2 dispatch (both speakers + root), then gather
    for (int c = 0; c < 2; c++) {
        const unsigned short* emc = em + (long)c * CH * DHc;
        rgcn256<<<dim3(10, 33, 1), 512, 0, stream>>>(
            emc, WrelT, hall4, idx + c * CH, cnts + c);
        rgcn_gather4<<<dim3(CH), 256, 0, stream>>>(hall4, enorm, spk, b_rgcn, h1, c * CH);
    }

    // ---- 4. anh1 = concat(window-sum(h1), h1); h2 -> em[:, 1024:1536)   [256^2 engine]
    build_anh1<<<dim3(Nc), 256, 0, stream>>>(h1, anh1);
    gemm256<true, false, true, false><<<dim3(2, 64, 1), 512, 0, stream>>>(
        anh1, WgcT, em + 1024, b_gc, 1024, 1024, 1024, DHc);

    // ---- 5. merged: xt = em @ W_match + b_match  AND  emWT = (em @ W_lin + b_lin)^T per conv
    gemm256_mw<<<dim3(8, 64, 1), 512, 0, stream>>>(
        em, WmatchT, xt, emWT, b_match, b_lin);

    // ---- 6. S_b = xt_b @ em_b^T  (z = 64 convs)
    gemm_as<false, false, false, false><<<dim3(2, 2, 64), 256, 0, stream>>>(
        xt, em, S, nullptr, DHc, DHc, DHc, 256, 393216, 393216, 65536);

    // ---- 7. a = softmax(tanh(S))
    tanh_softmax_rows<<<dim3(Nc), 256, 0, stream>>>(S, ac);

    // ---- 9. hidden = relu(a @ emW)  (z = 64 convs, bf16 out)
    gemm_as<true, false, false, true><<<dim3(4, 2, 64), 256, 0, stream>>>(
        ac, emWT, hidden, nullptr, 256, 256, 256, 512, 65536, 131072, 131072);

    // ---- 10. logits + log_softmax
    out_kernel<<<dim3(Nc / 4), 256, 0, stream>>>(hidden, W_fc, b_fc, (float*)d_out);
}

// Round 5
// 704.191 us; speedup vs baseline: 1.3179x; 1.0051x over previous
//
#include <hip/hip_runtime.h>
#include <hip/hip_bf16.h>

// Problem constants
#define Lc 256
#define Bc 64
#define Dc 1024
#define Hc 512
#define Rc 8
#define Cc 6
#define WINc 10
#define NWc 21
#define Nc (Bc*Lc)        // 16384
#define DHc (Dc+Hc)       // 1536
#define CH 8192           // RGCN chunk (32 conversations)

typedef __attribute__((ext_vector_type(8))) short short8;
typedef __attribute__((ext_vector_type(4))) float floatx4;

__device__ inline unsigned short f2b(float x) {
    __hip_bfloat16 h = __float2bfloat16(x);
    return *reinterpret_cast<unsigned short*>(&h);
}
__device__ inline float bf2f(unsigned short u) {
    __hip_bfloat16 h;
    *reinterpret_cast<unsigned short*>(&h) = u;
    return __bfloat162float(h);
}

// node id n = b*256+s  ->  feats row s*64+b
__device__ inline long remap_row(int node) { return (long)(((node & 255) << 6) + (node >> 8)); }

typedef __attribute__((address_space(3))) unsigned int lds_u32;
typedef __attribute__((address_space(1))) unsigned int glb_u32;
__device__ inline void glds16(const unsigned short* g, unsigned short* l) {
    __builtin_amdgcn_global_load_lds((const glb_u32*)g, (lds_u32*)l, 16, 0, 0);
}

#define SB0 __builtin_amdgcn_sched_barrier(0)
#define BAR __builtin_amdgcn_s_barrier()

// bijective XCD-aware remap (m204): x-inner so one XCD sweeps all col-tiles of its rows
// (A-panel stays hot in its L2; verified round 4: FETCH 204->75 MB).
__device__ __forceinline__ void xcd_remap(int gridX, int& x, int& y)
{
    int nwg = gridDim.x * gridDim.y;
    int bid = blockIdx.y * gridDim.x + blockIdx.x;
    int q = nwg >> 3, r = nwg & 7;
    int xcd = bid & 7, pos = bid >> 3;
    int logical = xcd * q + min(xcd, r) + pos;
    x = logical % gridX;
    y = logical / gridX;
}

// ---------------- merged prep: weight transposes + em_x + speaker partition (1 launch) ----------
__global__ __launch_bounds__(256) void prep_all(
    const float* __restrict__ Wscalar, const float* __restrict__ W_rel,
    const float* __restrict__ W_root, const float* __restrict__ W_nbr,
    const float* __restrict__ W_self, const float* __restrict__ W_match,
    const float* __restrict__ W_lin, unsigned short* __restrict__ WT,
    const int* __restrict__ spk, int* __restrict__ idx, int* __restrict__ cnts,
    const float* __restrict__ feats, unsigned short* __restrict__ em)
{
    int t = blockIdx.x;
    if (t >= 8448 + 16384) {                     // ---- partition (2 blocks)
        int c = t - (8448 + 16384);
        int tid = threadIdx.x;
        int base = c * CH;
        __shared__ int zs[256];
        int zcount = 0;
        for (int i = 0; i < CH / 256; i++) {
            int n = base + tid * (CH / 256) + i;
            if (spk[(n & 255) * 64 + (n >> 8)] == 0) zcount++;
        }
        zs[tid] = zcount; __syncthreads();
        for (int off = 1; off < 256; off <<= 1) {
            int v = (tid >= off) ? zs[tid - off] : 0;
            __syncthreads();
            zs[tid] += v;
            __syncthreads();
        }
        int Z = zs[255];
        int zpos = zs[tid] - zcount;
        int opos = tid * (CH / 256) - zpos;
        for (int i = 0; i < CH / 256; i++) {
            int nl = tid * (CH / 256) + i;
            int n = base + nl;
            if (spk[(n & 255) * 64 + (n >> 8)] == 0) idx[base + (zpos++)] = nl;
            else                                     idx[base + Z + (opos++)] = nl;
        }
        if (tid == 0) cnts[c] = Z;
        return;
    }
    if (t >= 8448) {                             // ---- em[:,0:1024) = bf16 feats (16384 blocks)
        int n = t - 8448;
        int tid = threadIdx.x;
        const float* f = feats + remap_row(n) * Dc;
        float4 v = ((const float4*)f)[tid];
        unsigned short* e = em + (long)n * DHc + tid * 4;
        e[0] = f2b(v.x); e[1] = f2b(v.y); e[2] = f2b(v.z); e[3] = f2b(v.w);
        return;
    }
    // ---- weight transposes (8448 blocks), fp32 [K][N] -> bf16 [N][K]
    const float* in; unsigned short* out; int N, ldo, n0, k0;
    if (t < 256) {                       // Wscalar [1024][256] -> [256][1024]
        in = Wscalar; out = WT; N = 256; ldo = 1024;
        n0 = (t & 7) * 32; k0 = (t >> 3) * 32;
    } else if (t < 4352) {               // W_rel 8x[1024][512] -> rows r*512..
        int u = t - 256; int r = u >> 9; u &= 511;
        in = W_rel + (long)r * 524288; out = WT + 262144 + (long)r * 524288; N = 512; ldo = 1024;
        n0 = (u & 15) * 32; k0 = (u >> 4) * 32;
    } else if (t < 4864) {               // W_root -> WrelT rows 4096..4608
        int u = t - 4352;
        in = W_root; out = WT + 262144 + 4096 * 1024; N = 512; ldo = 1024;
        n0 = (u & 15) * 32; k0 = (u >> 4) * 32;
    } else if (t < 5120) {               // W_nbr -> WgcT k 0..512
        int u = t - 4864;
        in = W_nbr; out = WT + 4980736; N = 512; ldo = 1024;
        n0 = (u & 15) * 32; k0 = (u >> 4) * 32;
    } else if (t < 5376) {               // W_self -> WgcT k 512..1024
        int u = t - 5120;
        in = W_self; out = WT + 4980736 + 512; N = 512; ldo = 1024;
        n0 = (u & 15) * 32; k0 = (u >> 4) * 32;
    } else if (t < 7680) {               // W_match [1536][1536]
        int u = t - 5376;
        in = W_match; out = WT + 5505024; N = 1536; ldo = 1536;
        n0 = (u % 48) * 32; k0 = (u / 48) * 32;
    } else {                             // W_lin [1536][512] (rows follow W_match: merged B)
        int u = t - 7680;
        in = W_lin; out = WT + 7864320; N = 512; ldo = 1536;
        n0 = (u & 15) * 32; k0 = (u >> 4) * 32;
    }
    __shared__ float tt[32][33];
    int tx = threadIdx.x & 31, ty = threadIdx.x >> 5;
    #pragma unroll
    for (int i = 0; i < 4; i++) tt[ty + i * 8][tx] = in[(long)(k0 + ty + i * 8) * N + n0 + tx];
    __syncthreads();
    #pragma unroll
    for (int i = 0; i < 4; i++) out[(long)(n0 + ty + i * 8) * ldo + k0 + tx] = f2b(tt[tx][ty + i * 8]);
}

// ---------------- 128^2 MFMA GEMM, async staging (small/batched shapes) ----------------
template<bool CBF, bool CT, bool BIAS, bool RELU>
__global__ __launch_bounds__(256) void gemm_as(
    const unsigned short* __restrict__ A, const unsigned short* __restrict__ B,
    void* __restrict__ Cv, const float* __restrict__ bias,
    int K, int lda, int ldb, int ldc, long sA, long sB, long sC)
{
    __shared__ __align__(16) unsigned short As[4096];
    __shared__ __align__(16) unsigned short Bs[4096];
    const int tid = threadIdx.x;
    const int z = blockIdx.z;
    const int m0 = blockIdx.y * 128, n0 = blockIdx.x * 128;
    const int lane = tid & 63, wave = tid >> 6;
    const int q = lane >> 4, mr = lane & 15;
    const int wrow = (wave >> 1) * 64, wcol = (wave & 1) * 64;

    const unsigned short* Ag0 = A + z * sA + (long)(m0 + wave * 32 + mr) * lda + q * 8;
    const unsigned short* Ag1 = Ag0 + (long)16 * lda;
    const unsigned short* Bg0 = B + z * sB + (long)(n0 + wave * 32 + mr) * ldb + q * 8;
    const unsigned short* Bg1 = Bg0 + (long)16 * ldb;
    unsigned short* Al0 = As + wave * 1024;
    unsigned short* Bl0 = Bs + wave * 1024;

    floatx4 acc[4][4];
    #pragma unroll
    for (int mt = 0; mt < 4; mt++)
        #pragma unroll
        for (int nt = 0; nt < 4; nt++) acc[mt][nt] = (floatx4){0.f, 0.f, 0.f, 0.f};

    const int ga = (wave >> 1) * 2048;
    const int gb = (wave & 1) * 2048;

    for (int k0 = 0; k0 < K; k0 += 32) {
        glds16(Ag0 + k0, Al0);
        glds16(Ag1 + k0, Al0 + 512);
        glds16(Bg0 + k0, Bl0);
        glds16(Bg1 + k0, Bl0 + 512);
        __syncthreads();
        short8 af[4], bfr[4];
        #pragma unroll
        for (int t = 0; t < 4; t++) {
            af[t]  = *(const short8*)&As[ga + t * 512 + lane * 8];
            bfr[t] = *(const short8*)&Bs[gb + t * 512 + lane * 8];
        }
        #pragma unroll
        for (int mt = 0; mt < 4; mt++)
            #pragma unroll
            for (int nt = 0; nt < 4; nt++)
                acc[mt][nt] = __builtin_amdgcn_mfma_f32_16x16x32_bf16(af[mt], bfr[nt], acc[mt][nt], 0, 0, 0);
        __syncthreads();
    }

    float* Cf = (float*)Cv;
    unsigned short* Cb = (unsigned short*)Cv;
    #pragma unroll
    for (int mt = 0; mt < 4; mt++) {
        #pragma unroll
        for (int nt = 0; nt < 4; nt++) {
            int col = n0 + wcol + nt * 16 + mr;
            float bv = BIAS ? bias[col] : 0.f;
            #pragma unroll
            for (int rg = 0; rg < 4; rg++) {
                int row = m0 + wrow + mt * 16 + q * 4 + rg;
                float v = acc[mt][nt][rg] + bv;
                if (RELU) v = fmaxf(v, 0.f);
                if (CT) {
                    Cb[(long)(row >> 8) * 131072 + (long)col * 256 + (row & 255)] = f2b(v);
                } else {
                    long ci = z * sC + (long)row * ldc + col;
                    if (CBF) Cb[ci] = f2b(v);
                    else     Cf[ci] = v;
                }
            }
        }
    }
}

// ================= 256^2 8-wave engine core — m201-faithful skeleton ==================
// BM=BN=256, BK=64 (2 kh of 32). LDS: A[2buf][2kh][256][32] + B same = 128 KiB.
// Per K-tile t, 4 phases; each = {JIT ds_reads, stage ONE 16KB half-slot, BAR, lgkm(0),
// setprio(1), 16 MFMA, setprio(0), BAR}. B (bQ kh0 + b2Q kh1) held in regs the whole tile.
// Staging stream (1 slot/phase): P0: Akh1(t+1); P1: Bkh0(t+2); P2: Bkh1(t+2); P3: Akh0(t+2).
// vmcnt(6) ONLY at P3: drains exactly all 4 slots of tile t+1 (issued 3-6 phases earlier),
// leaves t+2's 6 loads in flight (m201's counted-wait discipline; never 0 mid-loop).
// WAR ledger: each slot staged >=1 barrier pair after its old data's last ds_read
// (Akh1: read P3(t-1); Bkh0: P0(t); Bkh1: P1(t); Akh0: P1(t)).
#define MFMA16(ACCBASE, AFR, BFR) \
    { _Pragma("unroll") \
      for (int mt = 0; mt < 4; mt++) \
        _Pragma("unroll") \
        for (int nt = 0; nt < 4; nt++) \
            acc[ACCBASE + mt][nt] = __builtin_amdgcn_mfma_f32_16x16x32_bf16(AFR[mt], BFR[nt], acc[ACCBASE + mt][nt], 0, 0, 0); }

__device__ __forceinline__ void gemm256_loop(
    unsigned short* lp,
    const unsigned short* Ag0, const unsigned short* Ag1,
    const unsigned short* Bg0, const unsigned short* Bg1,
    int NT, int wofs, const int* offA, const int* offB, floatx4 (&acc)[8][4])
{
    unsigned short* Bl = lp + 32768;
    // prologue: t0 all 4 slots; t1 {Bkh0, Bkh1, Akh0}  (t1.Akh1 staged at (0,P0))
    glds16(Ag0,      lp + wofs);                glds16(Ag1,      lp + wofs + 4096);
    glds16(Ag0 + 32, lp + 8192 + wofs);         glds16(Ag1 + 32, lp + 8192 + wofs + 4096);
    glds16(Bg0,      Bl + wofs);                glds16(Bg1,      Bl + wofs + 4096);
    glds16(Bg0 + 32, Bl + 8192 + wofs);         glds16(Bg1 + 32, Bl + 8192 + wofs + 4096);
    glds16(Bg0 + 64, Bl + 16384 + wofs);        glds16(Bg1 + 64, Bl + 16384 + wofs + 4096);
    glds16(Bg0 + 96, Bl + 16384 + 8192 + wofs); glds16(Bg1 + 96, Bl + 16384 + 8192 + wofs + 4096);
    glds16(Ag0 + 64, lp + 16384 + wofs);        glds16(Ag1 + 64, lp + 16384 + wofs + 4096);
    asm volatile("s_waitcnt vmcnt(6)" ::: "memory");   // t0 complete; t1's 6 in flight
    SB0; BAR; SB0;

    short8 aF[4], bQ[4], b2Q[4];
    for (int t = 0; t < NT; t++) {
        const int buf = t & 1;
        const int ab  = buf * 16384;
        const int abx = (buf ^ 1) * 16384;

        // ===== P0: reads aF(kh0 mt0-3) + bQ(kh0, held full tile); stage Akh1(t+1)
        #pragma unroll
        for (int i = 0; i < 4; i++) aF[i] = *(const short8*)(lp + ab + offA[i]);
        #pragma unroll
        for (int i = 0; i < 4; i++) bQ[i] = *(const short8*)(Bl + ab + offB[i]);
        if (t + 1 < NT) {
            const int kc = (t + 1) * 64 + 32;
            glds16(Ag0 + kc, lp + abx + 8192 + wofs);
            glds16(Ag1 + kc, lp + abx + 8192 + wofs + 4096);
        }
        SB0; BAR; SB0;
        asm volatile("s_waitcnt lgkmcnt(0)" ::: "memory"); SB0;
        __builtin_amdgcn_s_setprio(1);
        MFMA16(0, aF, bQ)
        __builtin_amdgcn_s_setprio(0);
        SB0; BAR; SB0;

        // ===== P1: reads aF(kh0 mt4-7) + b2Q(kh1, held); stage Bkh0(t+2)
        #pragma unroll
        for (int i = 0; i < 4; i++) aF[i]  = *(const short8*)(lp + ab + offA[4 + i]);
        #pragma unroll
        for (int i = 0; i < 4; i++) b2Q[i] = *(const short8*)(Bl + ab + 8192 + offB[i]);
        if (t + 2 < NT) {
            const int kc = (t + 2) * 64;
            glds16(Bg0 + kc, Bl + ab + wofs);
            glds16(Bg1 + kc, Bl + ab + wofs + 4096);
        }
        SB0; BAR; SB0;
        asm volatile("s_waitcnt lgkmcnt(0)" ::: "memory"); SB0;
        __builtin_amdgcn_s_setprio(1);
        MFMA16(4, aF, bQ)
        __builtin_amdgcn_s_setprio(0);
        SB0; BAR; SB0;

        // ===== P2: reads aF(kh1 mt0-3); stage Bkh1(t+2)
        #pragma unroll
        for (int i = 0; i < 4; i++) aF[i] = *(const short8*)(lp + ab + 8192 + offA[i]);
        if (t + 2 < NT) {
            const int kc = (t + 2) * 64 + 32;
            glds16(Bg0 + kc, Bl + ab + 8192 + wofs);
            glds16(Bg1 + kc, Bl + ab + 8192 + wofs + 4096);
        }
        SB0; BAR; SB0;
        asm volatile("s_waitcnt lgkmcnt(0)" ::: "memory"); SB0;
        __builtin_amdgcn_s_setprio(1);
        MFMA16(0, aF, b2Q)
        __builtin_amdgcn_s_setprio(0);
        SB0; BAR; SB0;

        // ===== P3: reads aF(kh1 mt4-7); stage Akh0(t+2); counted vmcnt(6)
        #pragma unroll
        for (int i = 0; i < 4; i++) aF[i] = *(const short8*)(lp + ab + 8192 + offA[4 + i]);
        if (t + 2 < NT) {
            const int kc = (t + 2) * 64;
            glds16(Ag0 + kc, lp + ab + wofs);
            glds16(Ag1 + kc, lp + ab + wofs + 4096);
        }
        if (t < NT - 2)       { asm volatile("s_waitcnt vmcnt(6)" ::: "memory"); }
        else if (t == NT - 2) { asm volatile("s_waitcnt vmcnt(0)" ::: "memory"); }
        SB0; BAR; SB0;
        asm volatile("s_waitcnt lgkmcnt(0)" ::: "memory"); SB0;
        __builtin_amdgcn_s_setprio(1);
        MFMA16(4, aF, b2Q)
        __builtin_amdgcn_s_setprio(0);
        SB0; BAR; SB0;
    }
}

// helper: per-kernel fragment offsets (XOR-swizzled, matches pre-swizzled global source)
__device__ __forceinline__ void frag_offsets(int wm, int wn, int q, int mr, int* offA, int* offB)
{
    #pragma unroll
    for (int mt = 0; mt < 8; mt++) {
        int row = wm * 128 + mt * 16 + mr;
        offA[mt] = row * 32 + ((q ^ ((row >> 1) & 3)) * 8);
    }
    #pragma unroll
    for (int nt = 0; nt < 4; nt++) {
        int row = wn * 64 + nt * 16 + mr;
        offB[nt] = row * 32 + ((q ^ ((row >> 1) & 3)) * 8);
    }
}

// ---------------- generic 256^2 GEMM (used for h2) ----------------
template<bool CBF, bool CT, bool BIAS, bool RELU>
__global__ __launch_bounds__(512, 2) void gemm256(
    const unsigned short* __restrict__ A, const unsigned short* __restrict__ B,
    void* __restrict__ Cv, const float* __restrict__ bias,
    int K, int lda, int ldb, int ldc)
{
    __shared__ __align__(16) unsigned short LDS[65536];
    unsigned short* lp = &LDS[0];
    const int tid  = threadIdx.x;
    const int lane = tid & 63, wave = tid >> 6;
    const int wm = wave >> 2, wn = wave & 3;
    int bx, by;
    xcd_remap(gridDim.x, bx, by);
    const int m0 = by * 256, n0 = bx * 256;
    const int NT = K >> 6;
    const int q = lane >> 4, mr = lane & 15;

    const int r0 = wave * 16 + (lane >> 2);
    const int r1 = r0 + 128;
    const int c0 = ((lane & 3) ^ ((r0 >> 1) & 3)) * 8;
    const int c1 = ((lane & 3) ^ ((r1 >> 1) & 3)) * 8;
    const unsigned short* Ag0 = A + (long)(m0 + r0) * lda + c0;
    const unsigned short* Ag1 = A + (long)(m0 + r1) * lda + c1;
    const unsigned short* Bg0 = B + (long)(n0 + r0) * ldb + c0;
    const unsigned short* Bg1 = B + (long)(n0 + r1) * ldb + c1;
    const int wofs = wave * 512;

    int offA[8], offB[4];
    frag_offsets(wm, wn, q, mr, offA, offB);

    floatx4 acc[8][4];
    #pragma unroll
    for (int mt = 0; mt < 8; mt++)
        #pragma unroll
        for (int nt = 0; nt < 4; nt++) acc[mt][nt] = (floatx4){0.f, 0.f, 0.f, 0.f};

    gemm256_loop(lp, Ag0, Ag1, Bg0, Bg1, NT, wofs, offA, offB, acc);

    float* Cf = (float*)Cv;
    unsigned short* Cb = (unsigned short*)Cv;
    #pragma unroll
    for (int mt = 0; mt < 8; mt++) {
        #pragma unroll
        for (int nt = 0; nt < 4; nt++) {
            int col = n0 + wn * 64 + nt * 16 + mr;
            float bv = BIAS ? bias[col] : 0.f;
            #pragma unroll
            for (int rg = 0; rg < 4; rg++) {
                int row = m0 + wm * 128 + mt * 16 + q * 4 + rg;
                float v = acc[mt][nt][rg] + bv;
                if (RELU) v = fmaxf(v, 0.f);
                if (CT) {
                    Cb[(long)(row >> 8) * 131072 + (long)col * 256 + (row & 255)] = f2b(v);
                } else {
                    long ci = (long)row * ldc + col;
                    if (CBF) Cb[ci] = f2b(v);
                    else     Cf[ci] = v;
                }
            }
        }
    }
}

// ---------------- RGCN 256^2: both speaker segments + root in ONE dispatch per chunk -----------
__global__ __launch_bounds__(512, 2) void rgcn256(
    const unsigned short* __restrict__ A, const unsigned short* __restrict__ B,
    unsigned short* __restrict__ C, const int* __restrict__ idx,
    const int* __restrict__ cntp)
{
    const int cnt0 = *cntp;
    const int t0 = (cnt0 + 255) >> 8;
    const int M1 = CH - cnt0;
    const int t1 = (M1 + 255) >> 8;
    int x, ty;
    xcd_remap(gridDim.x, x, ty);
    int sblk, m0, M, off;
    if (ty < t0)           { sblk = 0; m0 = ty << 8;        M = cnt0; off = 0; }
    else if (ty < t0 + t1) { sblk = 1; m0 = (ty - t0) << 8; M = M1;   off = cnt0; }
    else return;

    const int brow = ((x < 8) ? sblk * 2048 : 2048) + x * 256;   // B row base in WrelT (root at 4096+)

    __shared__ __align__(16) unsigned short LDS[65536];
    unsigned short* lp = &LDS[0];
    const int tid  = threadIdx.x;
    const int lane = tid & 63, wave = tid >> 6;
    const int wm = wave >> 2, wn = wave & 3;
    const int q = lane >> 4, mr = lane & 15;

    const int r0 = wave * 16 + (lane >> 2);
    const int r1 = r0 + 128;
    const int c0 = ((lane & 3) ^ ((r0 >> 1) & 3)) * 8;
    const int c1 = ((lane & 3) ^ ((r1 >> 1) & 3)) * 8;
    const int gr0 = idx[off + min(m0 + r0, M - 1)];
    const int gr1 = idx[off + min(m0 + r1, M - 1)];
    const unsigned short* Ag0 = A + (long)gr0 * DHc + c0;
    const unsigned short* Ag1 = A + (long)gr1 * DHc + c1;
    const unsigned short* Bg0 = B + (long)(brow + r0) * 1024 + c0;
    const unsigned short* Bg1 = B + (long)(brow + r1) * 1024 + c1;
    const int wofs = wave * 512;

    int offA[8], offB[4];
    frag_offsets(wm, wn, q, mr, offA, offB);

    floatx4 acc[8][4];
    #pragma unroll
    for (int mt = 0; mt < 8; mt++)
        #pragma unroll
        for (int nt = 0; nt < 4; nt++) acc[mt][nt] = (floatx4){0.f, 0.f, 0.f, 0.f};

    gemm256_loop(lp, Ag0, Ag1, Bg0, Bg1, 16 /*K=1024*/, wofs, offA, offB, acc);

    #pragma unroll
    for (int mt = 0; mt < 8; mt++) {
        int rowb = m0 + wm * 128 + mt * 16 + q * 4;
        int cr[4];
        #pragma unroll
        for (int rg = 0; rg < 4; rg++) cr[rg] = idx[off + min(rowb + rg, M - 1)];
        #pragma unroll
        for (int nt = 0; nt < 4; nt++) {
            int col = x * 256 + wn * 64 + nt * 16 + mr;
            #pragma unroll
            for (int rg = 0; rg < 4; rg++)
                C[(long)cr[rg] * 2560 + col] = f2b(acc[mt][nt][rg]);
        }
    }
}

// ---------------- merged xt + emW: B = [W_matchT | W_linT] (2048 x 1536 contiguous) -------------
__global__ __launch_bounds__(512, 2) void gemm256_mw(
    const unsigned short* __restrict__ A, const unsigned short* __restrict__ B,
    unsigned short* __restrict__ xt, unsigned short* __restrict__ emWT,
    const float* __restrict__ b_match, const float* __restrict__ b_lin)
{
    __shared__ __align__(16) unsigned short LDS[65536];
    unsigned short* lp = &LDS[0];
    const int tid  = threadIdx.x;
    const int lane = tid & 63, wave = tid >> 6;
    const int wm = wave >> 2, wn = wave & 3;
    int bx, by;
    xcd_remap(gridDim.x, bx, by);
    const int m0 = by * 256, n0 = bx * 256;
    const int q = lane >> 4, mr = lane & 15;

    const int r0 = wave * 16 + (lane >> 2);
    const int r1 = r0 + 128;
    const int c0 = ((lane & 3) ^ ((r0 >> 1) & 3)) * 8;
    const int c1 = ((lane & 3) ^ ((r1 >> 1) & 3)) * 8;
    const unsigned short* Ag0 = A + (long)(m0 + r0) * DHc + c0;
    const unsigned short* Ag1 = A + (long)(m0 + r1) * DHc + c1;
    const unsigned short* Bg0 = B + (long)(n0 + r0) * 1536 + c0;
    const unsigned short* Bg1 = B + (long)(n0 + r1) * 1536 + c1;
    const int wofs = wave * 512;

    int offA[8], offB[4];
    frag_offsets(wm, wn, q, mr, offA, offB);

    floatx4 acc[8][4];
    #pragma unroll
    for (int mt = 0; mt < 8; mt++)
        #pragma unroll
        for (int nt = 0; nt < 4; nt++) acc[mt][nt] = (floatx4){0.f, 0.f, 0.f, 0.f};

    gemm256_loop(lp, Ag0, Ag1, Bg0, Bg1, 24 /*K=1536*/, wofs, offA, offB, acc);

    if (n0 < 1536) {
        #pragma unroll
        for (int mt = 0; mt < 8; mt++) {
            #pragma unroll
            for (int nt = 0; nt < 4; nt++) {
                int col = n0 + wn * 64 + nt * 16 + mr;
                float bv = b_match[col];
                #pragma unroll
                for (int rg = 0; rg < 4; rg++) {
                    int row = m0 + wm * 128 + mt * 16 + q * 4 + rg;
                    xt[(long)row * DHc + col] = f2b(acc[mt][nt][rg] + bv);
                }
            }
        }
    } else {
        #pragma unroll
        for (int mt = 0; mt < 8; mt++) {
            #pragma unroll
            for (int nt = 0; nt < 4; nt++) {
                int col = (n0 - 1536) + wn * 64 + nt * 16 + mr;
                float bv = b_lin[col];
                #pragma unroll
                for (int rg = 0; rg < 4; rg++) {
                    int row = m0 + wm * 128 + mt * 16 + q * 4 + rg;
                    emWT[(long)(row >> 8) * 131072 + (long)col * 256 + (row & 255)] =
                        f2b(acc[mt][nt][rg] + bv);
                }
            }
        }
    }
}

// ---------------- edge_norm: windowed softmax over k (scale node-ordered) ----------------
__global__ __launch_bounds__(256) void edge_norm_kernel(const float* __restrict__ scale,
                                                        float* __restrict__ enorm)
{
    int g = blockIdx.x * 256 + threadIdx.x;   // b*L + j
    int b = g >> 8, j = g & 255;
    int klo = max(0, j - WINc), khi = min(Lc - 1, j + WINc);
    float vals[NWc];
    float m = -1e30f;
    for (int k = klo; k <= khi; k++) {
        float v = scale[(long)((b << 8) + k) * Lc + j];
        vals[k - klo] = v;
        m = fmaxf(m, v);
    }
    float s = 0.f;
    for (int k = klo; k <= khi; k++) {
        float e = expf(vals[k - klo] - m);
        vals[k - klo] = e;
        s += e;
    }
    float inv = 1.f / s;
    for (int k = klo; k <= khi; k++)
        enorm[(long)g * NWc + (k - j + WINc)] = vals[k - klo] * inv;
}

// ---------------- RGCN aggregation (hall4 bf16 [CH][2560]: 4 dst-sel blocks + root) ----------------
__global__ __launch_bounds__(256) void rgcn_gather4(const unsigned short* __restrict__ hall4,
        const float* __restrict__ enorm, const int* __restrict__ spk,
        const float* __restrict__ b_rgcn, float* __restrict__ h1, int chunk_base)
{
    int nloc = blockIdx.x;
    int n = chunk_base + nloc;
    int b = n >> 8, k = n & 255;
    int tid = threadIdx.x;
    int spkk = spk[k * 64 + b];
    int jlo = max(0, k - WINc), jhi = min(Lc - 1, k + WINc);
    unsigned int ru = *(const unsigned int*)(hall4 + (long)nloc * 2560 + 2048 + 2 * tid);
    float a0 = bf2f((unsigned short)(ru & 0xffff)) + b_rgcn[2 * tid];
    float a1 = bf2f((unsigned short)(ru >> 16)) + b_rgcn[2 * tid + 1];
    int cb = spkk * 2;
    for (int j = jlo; j <= jhi; j++) {
        int c = cb + ((j < k) ? 0 : 1);
        float w = enorm[((long)((b << 8) + j)) * NWc + (k - j + WINc)];
        unsigned int u = *(const unsigned int*)(hall4 + ((long)(nloc - k + j)) * 2560 + c * 512 + 2 * tid);
        a0 += w * bf2f((unsigned short)(u & 0xffff));
        a1 += w * bf2f((unsigned short)(u >> 16));
    }
    *(float2*)&h1[(long)n * Hc + 2 * tid] = make_float2(a0, a1);
}

// ---------------- anh1 = bf16[ concat(window-sum(h1), h1) ]  [N][1024] ----------------
__global__ __launch_bounds__(256) void build_anh1(const float* __restrict__ h1,
                                                  unsigned short* __restrict__ anh1)
{
    int n = blockIdx.x;
    int b = n >> 8, k = n & 255;
    int tid = threadIdx.x;
    int jlo = max(0, k - WINc), jhi = min(Lc - 1, k + WINc);
    float a0 = 0.f, a1 = 0.f;
    for (int j = jlo; j <= jhi; j++) {
        const float* src = h1 + ((long)((b << 8) + j)) * Hc;
        a0 += src[tid];
        a1 += src[tid + 256];
    }
    unsigned short* dst = anh1 + (long)n * 1024;
    const float* self = h1 + (long)n * Hc;
    dst[tid]       = f2b(a0);
    dst[tid + 256] = f2b(a1);
    dst[tid + 512] = f2b(self[tid]);
    dst[tid + 768] = f2b(self[tid + 256]);
}

// ---------------- tanh + row softmax -> bf16 attention weights ----------------
__global__ __launch_bounds__(256) void tanh_softmax_rows(const float* __restrict__ S,
                                                         unsigned short* __restrict__ a)
{
    int row = blockIdx.x;
    int tid = threadIdx.x;
    __shared__ float red[256];
    float v = tanhf(S[(long)row * Lc + tid]);
    red[tid] = v; __syncthreads();
    for (int s = 128; s > 0; s >>= 1) { if (tid < s) red[tid] = fmaxf(red[tid], red[tid + s]); __syncthreads(); }
    float m = red[0]; __syncthreads();
    float e = expf(v - m);
    red[tid] = e; __syncthreads();
    for (int s = 128; s > 0; s >>= 1) { if (tid < s) red[tid] += red[tid + s]; __syncthreads(); }
    float sum = red[0];
    a[(long)row * Lc + tid] = f2b(e / sum);
}

// ---------------- final classifier + log_softmax (fp32 out) ----------------
__global__ __launch_bounds__(256) void out_kernel(const unsigned short* __restrict__ hidden,
        const float* __restrict__ Wfc, const float* __restrict__ bfc, float* __restrict__ out)
{
    int tid = threadIdx.x;
    int lane = tid & 63;
    int row = blockIdx.x * 4 + (tid >> 6);
    float acc[Cc] = {};
    const unsigned short* h = hidden + (long)row * Hc;
    for (int k = lane; k < Hc; k += 64) {
        float hv = bf2f(h[k]);
        #pragma unroll
        for (int c = 0; c < Cc; c++) acc[c] += hv * Wfc[k * Cc + c];
    }
    #pragma unroll
    for (int c = 0; c < Cc; c++)
        for (int off = 32; off > 0; off >>= 1) acc[c] += __shfl_down(acc[c], off, 64);
    if (lane == 0) {
        float m = -1e30f;
        #pragma unroll
        for (int c = 0; c < Cc; c++) { acc[c] += bfc[c]; m = fmaxf(m, acc[c]); }
        float s = 0.f;
        #pragma unroll
        for (int c = 0; c < Cc; c++) s += expf(acc[c] - m);
        float lse = logf(s);
        #pragma unroll
        for (int c = 0; c < Cc; c++) out[(long)row * Cc + c] = acc[c] - m - lse;
    }
}

extern "C" void kernel_launch(void* const* d_in, const int* in_sizes, int n_in,
                              void* d_out, int out_size, void* d_ws, size_t ws_size,
                              hipStream_t stream)
{
    const float* feats   = (const float*)d_in[0];
    const float* Wscalar = (const float*)d_in[1];
    const float* W_rel   = (const float*)d_in[2];
    const float* W_root  = (const float*)d_in[3];
    const float* b_rgcn  = (const float*)d_in[4];
    const float* W_nbr   = (const float*)d_in[5];
    const float* W_self  = (const float*)d_in[6];
    const float* b_gc    = (const float*)d_in[7];
    const float* W_match = (const float*)d_in[8];
    const float* b_match = (const float*)d_in[9];
    const float* W_lin   = (const float*)d_in[10];
    const float* b_lin   = (const float*)d_in[11];
    const float* W_fc    = (const float*)d_in[12];
    const float* b_fc    = (const float*)d_in[13];
    const int*   spk     = (const int*)d_in[14];

    char* wsb = (char*)d_ws;
    unsigned short* em    = (unsigned short*)wsb;               // [0,48M) persistent
    char* RB = wsb + 50331648;                                  // time-multiplexed region (48M)
    float*          scale = (float*)RB;                         // 16M  (steps 1-2)
    unsigned short* hall4 = (unsigned short*)RB;                // 41.9M (RGCN loop)
    unsigned short* anh1  = (unsigned short*)RB;                // 32M  (anh1 -> h2)
    unsigned short* xt    = (unsigned short*)RB;                // 48M  (xt -> S)
    unsigned short* hidden= (unsigned short*)(RB + 16777216);   // 16M  (after S; xt dead)
    char* HB = wsb + 100663296;                                 // second region (32M)
    float*          h1    = (float*)HB;                         // 32M (RGCN -> build_anh1; then dead)
    float*          S     = (float*)HB;                         // 16M (step 6 -> 7; h1 dead)
    unsigned short* emWT  = (unsigned short*)(wsb + 117440512); // 16M HB[16,32M) (step 5 -> 9)
    int* idx              = (int*)(HB + 16777216);              // 64K (read before gather(c1) clobbers)
    int* cnts             = (int*)(HB + 16777216 + 65536);      // 8B  (same)
    unsigned short* WT    = (unsigned short*)(wsb + 134217728); // 17.3M persistent (dead after step 5)
    unsigned short* WscalarT = WT;
    unsigned short* WrelT    = WT + 262144;      // 4608x1024: rels 0..7 then root at 4096..4608
    unsigned short* WgcT     = WT + 4980736;     // 512x1024 (nbr k0..512 | self k512..1024)
    unsigned short* WmatchT  = WT + 5505024;     // 1536x1536, then W_lin 512x1536 contiguous
    unsigned short* ac    = (unsigned short*)(wsb + 134217728); // 8M over dead WT head (step 7 -> 9)
    float*          enorm = (float*)(wsb + 151519232);          // 1.31M

    // ---- 0. merged prep: transposes + em_x + partition (1 launch)
    prep_all<<<dim3(8448 + 16384 + 2), 256, 0, stream>>>(
        Wscalar, W_rel, W_root, W_nbr, W_self, W_match, W_lin, WT,
        spk, idx, cnts, feats, em);

    // ---- 1. scale = x @ Wscalar  [16384 x 256]
    gemm_as<false, false, false, false><<<dim3(2, 128, 1), 256, 0, stream>>>(
        em, WscalarT, scale, nullptr, 1024, DHc, 1024, 256, 0, 0, 0);

    // ---- 2. windowed softmax
    edge_norm_kernel<<<dim3(64), 256, 0, stream>>>(scale, enorm);

    // ---- 3. RGCN per chunk: ONE 256^2 dispatch (both speakers + root), then gather
    for (int c = 0; c < 2; c++) {
        const unsigned short* emc = em + (long)c * CH * DHc;
        rgcn256<<<dim3(10, 33, 1), 512, 0, stream>>>(
            emc, WrelT, hall4, idx + c * CH, cnts + c);
        rgcn_gather4<<<dim3(CH), 256, 0, stream>>>(hall4, enorm, spk, b_rgcn, h1, c * CH);
    }

    // ---- 4. anh1 = concat(window-sum(h1), h1); h2 -> em[:, 1024:1536)   [256^2 engine]
    build_anh1<<<dim3(Nc), 256, 0, stream>>>(h1, anh1);
    gemm256<true, false, true, false><<<dim3(2, 64, 1), 512, 0, stream>>>(
        anh1, WgcT, em + 1024, b_gc, 1024, 1024, 1024, DHc);

    // ---- 5. merged: xt = em @ W_match + b_match  AND  emWT = (em @ W_lin + b_lin)^T per conv
    gemm256_mw<<<dim3(8, 64, 1), 512, 0, stream>>>(
        em, WmatchT, xt, emWT, b_match, b_lin);

    // ---- 6. S_b = xt_b @ em_b^T  (z = 64 convs)
    gemm_as<false, false, false, false><<<dim3(2, 2, 64), 256, 0, stream>>>(
        xt, em, S, nullptr, DHc, DHc, DHc, 256, 393216, 393216, 65536);

    // ---- 7. a = softmax(tanh(S))
    tanh_softmax_rows<<<dim3(Nc), 256, 0, stream>>>(S, ac);

    // ---- 9. hidden = relu(a @ emW)  (z = 64 convs, bf16 out)
    gemm_as<true, false, false, true><<<dim3(4, 2, 64), 256, 0, stream>>>(
        ac, emWT, hidden, nullptr, 256, 256, 256, 512, 65536, 131072, 131072);

    // ---- 10. logits + log_softmax
    out_kernel<<<dim3(Nc / 4), 256, 0, stream>>>(hidden, W_fc, b_fc, (float*)d_out);
}

// Round 6
// 694.194 us; speedup vs baseline: 1.3369x; 1.0144x over previous
//
#include <hip/hip_runtime.h>
#include <hip/hip_bf16.h>

// Problem constants
#define Lc 256
#define Bc 64
#define Dc 1024
#define Hc 512
#define Rc 8
#define Cc 6
#define WINc 10
#define NWc 21
#define Nc (Bc*Lc)        // 16384
#define DHc (Dc+Hc)       // 1536
#define CH 8192           // RGCN chunk (32 conversations)

typedef __attribute__((ext_vector_type(8))) short short8;
typedef __attribute__((ext_vector_type(4))) float floatx4;

__device__ inline unsigned short f2b(float x) {
    __hip_bfloat16 h = __float2bfloat16(x);
    return *reinterpret_cast<unsigned short*>(&h);
}
__device__ inline float bf2f(unsigned short u) {
    __hip_bfloat16 h;
    *reinterpret_cast<unsigned short*>(&h) = u;
    return __bfloat162float(h);
}

// node id n = b*256+s  ->  feats row s*64+b
__device__ inline long remap_row(int node) { return (long)(((node & 255) << 6) + (node >> 8)); }

typedef __attribute__((address_space(3))) unsigned int lds_u32;
typedef __attribute__((address_space(1))) unsigned int glb_u32;
__device__ inline void glds16(const unsigned short* g, unsigned short* l) {
    __builtin_amdgcn_global_load_lds((const glb_u32*)g, (lds_u32*)l, 16, 0, 0);
}

#define SB0 __builtin_amdgcn_sched_barrier(0)
#define BAR __builtin_amdgcn_s_barrier()

// bijective XCD-aware remap (m204): x-inner so one XCD sweeps all col-tiles of its rows
// (A-panel stays hot in its L2; verified round 4: FETCH 204->75 MB).
__device__ __forceinline__ void xcd_remap(int gridX, int& x, int& y)
{
    int nwg = gridDim.x * gridDim.y;
    int bid = blockIdx.y * gridDim.x + blockIdx.x;
    int q = nwg >> 3, r = nwg & 7;
    int xcd = bid & 7, pos = bid >> 3;
    int logical = xcd * q + min(xcd, r) + pos;
    x = logical % gridX;
    y = logical / gridX;
}

// ---------------- merged prep: weight transposes + em_x + speaker partition (1 launch) ----------
__global__ __launch_bounds__(256) void prep_all(
    const float* __restrict__ Wscalar, const float* __restrict__ W_rel,
    const float* __restrict__ W_root, const float* __restrict__ W_nbr,
    const float* __restrict__ W_self, const float* __restrict__ W_match,
    const float* __restrict__ W_lin, unsigned short* __restrict__ WT,
    const int* __restrict__ spk, int* __restrict__ idx, int* __restrict__ cnts,
    const float* __restrict__ feats, unsigned short* __restrict__ em)
{
    int t = blockIdx.x;
    if (t >= 8448 + 16384) {                     // ---- partition (2 blocks)
        int c = t - (8448 + 16384);
        int tid = threadIdx.x;
        int base = c * CH;
        __shared__ int zs[256];
        int zcount = 0;
        for (int i = 0; i < CH / 256; i++) {
            int n = base + tid * (CH / 256) + i;
            if (spk[(n & 255) * 64 + (n >> 8)] == 0) zcount++;
        }
        zs[tid] = zcount; __syncthreads();
        for (int off = 1; off < 256; off <<= 1) {
            int v = (tid >= off) ? zs[tid - off] : 0;
            __syncthreads();
            zs[tid] += v;
            __syncthreads();
        }
        int Z = zs[255];
        int zpos = zs[tid] - zcount;
        int opos = tid * (CH / 256) - zpos;
        for (int i = 0; i < CH / 256; i++) {
            int nl = tid * (CH / 256) + i;
            int n = base + nl;
            if (spk[(n & 255) * 64 + (n >> 8)] == 0) idx[base + (zpos++)] = nl;
            else                                     idx[base + Z + (opos++)] = nl;
        }
        if (tid == 0) cnts[c] = Z;
        return;
    }
    if (t >= 8448) {                             // ---- em[:,0:1024) = bf16 feats (16384 blocks)
        int n = t - 8448;
        int tid = threadIdx.x;
        const float* f = feats + remap_row(n) * Dc;
        float4 v = ((const float4*)f)[tid];
        unsigned short* e = em + (long)n * DHc + tid * 4;
        e[0] = f2b(v.x); e[1] = f2b(v.y); e[2] = f2b(v.z); e[3] = f2b(v.w);
        return;
    }
    // ---- weight transposes (8448 blocks), fp32 [K][N] -> bf16 [N][K]
    const float* in; unsigned short* out; int N, ldo, n0, k0;
    if (t < 256) {                       // Wscalar [1024][256] -> [256][1024]
        in = Wscalar; out = WT; N = 256; ldo = 1024;
        n0 = (t & 7) * 32; k0 = (t >> 3) * 32;
    } else if (t < 4352) {               // W_rel 8x[1024][512] -> rows r*512..
        int u = t - 256; int r = u >> 9; u &= 511;
        in = W_rel + (long)r * 524288; out = WT + 262144 + (long)r * 524288; N = 512; ldo = 1024;
        n0 = (u & 15) * 32; k0 = (u >> 4) * 32;
    } else if (t < 4864) {               // W_root -> WrelT rows 4096..4608
        int u = t - 4352;
        in = W_root; out = WT + 262144 + 4096 * 1024; N = 512; ldo = 1024;
        n0 = (u & 15) * 32; k0 = (u >> 4) * 32;
    } else if (t < 5120) {               // W_nbr -> WgcT k 0..512
        int u = t - 4864;
        in = W_nbr; out = WT + 4980736; N = 512; ldo = 1024;
        n0 = (u & 15) * 32; k0 = (u >> 4) * 32;
    } else if (t < 5376) {               // W_self -> WgcT k 512..1024
        int u = t - 5120;
        in = W_self; out = WT + 4980736 + 512; N = 512; ldo = 1024;
        n0 = (u & 15) * 32; k0 = (u >> 4) * 32;
    } else if (t < 7680) {               // W_match [1536][1536]
        int u = t - 5376;
        in = W_match; out = WT + 5505024; N = 1536; ldo = 1536;
        n0 = (u % 48) * 32; k0 = (u / 48) * 32;
    } else {                             // W_lin [1536][512] (rows follow W_match: merged B)
        int u = t - 7680;
        in = W_lin; out = WT + 7864320; N = 512; ldo = 1536;
        n0 = (u & 15) * 32; k0 = (u >> 4) * 32;
    }
    __shared__ float tt[32][33];
    int tx = threadIdx.x & 31, ty = threadIdx.x >> 5;
    #pragma unroll
    for (int i = 0; i < 4; i++) tt[ty + i * 8][tx] = in[(long)(k0 + ty + i * 8) * N + n0 + tx];
    __syncthreads();
    #pragma unroll
    for (int i = 0; i < 4; i++) out[(long)(n0 + ty + i * 8) * ldo + k0 + tx] = f2b(tt[tx][ty + i * 8]);
}

// ---------------- 128^2 MFMA GEMM, async staging (small/batched shapes) ----------------
template<bool CBF, bool CT, bool BIAS, bool RELU>
__global__ __launch_bounds__(256) void gemm_as(
    const unsigned short* __restrict__ A, const unsigned short* __restrict__ B,
    void* __restrict__ Cv, const float* __restrict__ bias,
    int K, int lda, int ldb, int ldc, long sA, long sB, long sC)
{
    __shared__ __align__(16) unsigned short As[4096];
    __shared__ __align__(16) unsigned short Bs[4096];
    const int tid = threadIdx.x;
    const int z = blockIdx.z;
    const int m0 = blockIdx.y * 128, n0 = blockIdx.x * 128;
    const int lane = tid & 63, wave = tid >> 6;
    const int q = lane >> 4, mr = lane & 15;
    const int wrow = (wave >> 1) * 64, wcol = (wave & 1) * 64;

    const unsigned short* Ag0 = A + z * sA + (long)(m0 + wave * 32 + mr) * lda + q * 8;
    const unsigned short* Ag1 = Ag0 + (long)16 * lda;
    const unsigned short* Bg0 = B + z * sB + (long)(n0 + wave * 32 + mr) * ldb + q * 8;
    const unsigned short* Bg1 = Bg0 + (long)16 * ldb;
    unsigned short* Al0 = As + wave * 1024;
    unsigned short* Bl0 = Bs + wave * 1024;

    floatx4 acc[4][4];
    #pragma unroll
    for (int mt = 0; mt < 4; mt++)
        #pragma unroll
        for (int nt = 0; nt < 4; nt++) acc[mt][nt] = (floatx4){0.f, 0.f, 0.f, 0.f};

    const int ga = (wave >> 1) * 2048;
    const int gb = (wave & 1) * 2048;

    for (int k0 = 0; k0 < K; k0 += 32) {
        glds16(Ag0 + k0, Al0);
        glds16(Ag1 + k0, Al0 + 512);
        glds16(Bg0 + k0, Bl0);
        glds16(Bg1 + k0, Bl0 + 512);
        __syncthreads();
        short8 af[4], bfr[4];
        #pragma unroll
        for (int t = 0; t < 4; t++) {
            af[t]  = *(const short8*)&As[ga + t * 512 + lane * 8];
            bfr[t] = *(const short8*)&Bs[gb + t * 512 + lane * 8];
        }
        #pragma unroll
        for (int mt = 0; mt < 4; mt++)
            #pragma unroll
            for (int nt = 0; nt < 4; nt++)
                acc[mt][nt] = __builtin_amdgcn_mfma_f32_16x16x32_bf16(af[mt], bfr[nt], acc[mt][nt], 0, 0, 0);
        __syncthreads();
    }

    float* Cf = (float*)Cv;
    unsigned short* Cb = (unsigned short*)Cv;
    #pragma unroll
    for (int mt = 0; mt < 4; mt++) {
        #pragma unroll
        for (int nt = 0; nt < 4; nt++) {
            int col = n0 + wcol + nt * 16 + mr;
            float bv = BIAS ? bias[col] : 0.f;
            #pragma unroll
            for (int rg = 0; rg < 4; rg++) {
                int row = m0 + wrow + mt * 16 + q * 4 + rg;
                float v = acc[mt][nt][rg] + bv;
                if (RELU) v = fmaxf(v, 0.f);
                if (CT) {
                    Cb[(long)(row >> 8) * 131072 + (long)col * 256 + (row & 255)] = f2b(v);
                } else {
                    long ci = z * sC + (long)row * ldc + col;
                    if (CBF) Cb[ci] = f2b(v);
                    else     Cf[ci] = v;
                }
            }
        }
    }
}

// ================= 256^2 8-wave engine core — SINGLE barrier per phase ==================
// BM=BN=256, BK=64 (2 kh of 32). LDS: A[2buf][2kh][256][32] + B same = 128 KiB.
// Round-6 change: ONE barrier per phase, at phase START. Phase = {BAR; ds_reads(p);
// stage 1 half-slot; [vmcnt@P3]; lgkm(0); SB0; setprio MFMA}. No post-MFMA barrier, so
// LDS service of phase p+1 overlaps MFMA of phase p across waves (the overlap the old
// double-barrier structure forbade: rounds 3-5 all ~40% MfmaUtil with LDS+MFMA additive).
// WAR ledger (safe with single barrier): stage(p) issued after BAR(p); all waves reach
// BAR(p) only after MFMA(p-1) which follows lgkm(0) -> every earlier ds_read has RETURNED
// before any overwrite is issued. Staged slots' last LDS-read phases: Akh1@P0 overwrites
// data last read P3(t-1); Bkh0@P1 last read P0(t); Bkh1@P2 last read P1(t); Akh0@P3 last
// read P1(t) -- all strictly earlier. RAW: vmcnt(6) at P3(t) drains exactly tile t+1's 4
// slots (8 loads, issued 3-6 phases earlier), leaves t+2's 6 in flight; every wave's
// vmcnt precedes its BAR(P0,t+1). bQ/b2Q register lifetimes are SSA-tracked.
#define MFMA16(ACCBASE, AFR, BFR) \
    { _Pragma("unroll") \
      for (int mt = 0; mt < 4; mt++) \
        _Pragma("unroll") \
        for (int nt = 0; nt < 4; nt++) \
            acc[ACCBASE + mt][nt] = __builtin_amdgcn_mfma_f32_16x16x32_bf16(AFR[mt], BFR[nt], acc[ACCBASE + mt][nt], 0, 0, 0); }

__device__ __forceinline__ void gemm256_loop(
    unsigned short* lp,
    const unsigned short* Ag0, const unsigned short* Ag1,
    const unsigned short* Bg0, const unsigned short* Bg1,
    int NT, int wofs, const int* offA, const int* offB, floatx4 (&acc)[8][4])
{
    unsigned short* Bl = lp + 32768;
    // prologue: t0 all 4 slots; t1 {Bkh0, Bkh1, Akh0}  (t1.Akh1 staged at (0,P0))
    glds16(Ag0,      lp + wofs);                glds16(Ag1,      lp + wofs + 4096);
    glds16(Ag0 + 32, lp + 8192 + wofs);         glds16(Ag1 + 32, lp + 8192 + wofs + 4096);
    glds16(Bg0,      Bl + wofs);                glds16(Bg1,      Bl + wofs + 4096);
    glds16(Bg0 + 32, Bl + 8192 + wofs);         glds16(Bg1 + 32, Bl + 8192 + wofs + 4096);
    glds16(Bg0 + 64, Bl + 16384 + wofs);        glds16(Bg1 + 64, Bl + 16384 + wofs + 4096);
    glds16(Bg0 + 96, Bl + 16384 + 8192 + wofs); glds16(Bg1 + 96, Bl + 16384 + 8192 + wofs + 4096);
    glds16(Ag0 + 64, lp + 16384 + wofs);        glds16(Ag1 + 64, lp + 16384 + wofs + 4096);
    asm volatile("s_waitcnt vmcnt(6)" ::: "memory");   // t0 complete; t1's 6 in flight

    short8 aF[4], bQ[4], b2Q[4];
    for (int t = 0; t < NT; t++) {
        const int buf = t & 1;
        const int ab  = buf * 16384;
        const int abx = (buf ^ 1) * 16384;

        // ===== P0: reads aF(kh0 mt0-3) + bQ(kh0, held 2 phases); stage Akh1(t+1)
        SB0; BAR; SB0;
        #pragma unroll
        for (int i = 0; i < 4; i++) aF[i] = *(const short8*)(lp + ab + offA[i]);
        #pragma unroll
        for (int i = 0; i < 4; i++) bQ[i] = *(const short8*)(Bl + ab + offB[i]);
        if (t + 1 < NT) {
            const int kc = (t + 1) * 64 + 32;
            glds16(Ag0 + kc, lp + abx + 8192 + wofs);
            glds16(Ag1 + kc, lp + abx + 8192 + wofs + 4096);
        }
        asm volatile("s_waitcnt lgkmcnt(0)" ::: "memory"); SB0;
        __builtin_amdgcn_s_setprio(1);
        MFMA16(0, aF, bQ)
        __builtin_amdgcn_s_setprio(0);

        // ===== P1: reads aF(kh0 mt4-7) + b2Q(kh1, held 2 phases); stage Bkh0(t+2)
        SB0; BAR; SB0;
        #pragma unroll
        for (int i = 0; i < 4; i++) aF[i]  = *(const short8*)(lp + ab + offA[4 + i]);
        #pragma unroll
        for (int i = 0; i < 4; i++) b2Q[i] = *(const short8*)(Bl + ab + 8192 + offB[i]);
        if (t + 2 < NT) {
            const int kc = (t + 2) * 64;
            glds16(Bg0 + kc, Bl + ab + wofs);
            glds16(Bg1 + kc, Bl + ab + wofs + 4096);
        }
        asm volatile("s_waitcnt lgkmcnt(0)" ::: "memory"); SB0;
        __builtin_amdgcn_s_setprio(1);
        MFMA16(4, aF, bQ)
        __builtin_amdgcn_s_setprio(0);

        // ===== P2: reads aF(kh1 mt0-3); stage Bkh1(t+2)
        SB0; BAR; SB0;
        #pragma unroll
        for (int i = 0; i < 4; i++) aF[i] = *(const short8*)(lp + ab + 8192 + offA[i]);
        if (t + 2 < NT) {
            const int kc = (t + 2) * 64 + 32;
            glds16(Bg0 + kc, Bl + ab + 8192 + wofs);
            glds16(Bg1 + kc, Bl + ab + 8192 + wofs + 4096);
        }
        asm volatile("s_waitcnt lgkmcnt(0)" ::: "memory"); SB0;
        __builtin_amdgcn_s_setprio(1);
        MFMA16(0, aF, b2Q)
        __builtin_amdgcn_s_setprio(0);

        // ===== P3: reads aF(kh1 mt4-7); stage Akh0(t+2); counted vmcnt(6)
        SB0; BAR; SB0;
        #pragma unroll
        for (int i = 0; i < 4; i++) aF[i] = *(const short8*)(lp + ab + 8192 + offA[4 + i]);
        if (t + 2 < NT) {
            const int kc = (t + 2) * 64;
            glds16(Ag0 + kc, lp + ab + wofs);
            glds16(Ag1 + kc, lp + ab + wofs + 4096);
        }
        if (t < NT - 2)       { asm volatile("s_waitcnt vmcnt(6)" ::: "memory"); }
        else if (t == NT - 2) { asm volatile("s_waitcnt vmcnt(0)" ::: "memory"); }
        asm volatile("s_waitcnt lgkmcnt(0)" ::: "memory"); SB0;
        __builtin_amdgcn_s_setprio(1);
        MFMA16(4, aF, b2Q)
        __builtin_amdgcn_s_setprio(0);
    }
}

// helper: per-kernel fragment offsets (XOR-swizzled, matches pre-swizzled global source)
__device__ __forceinline__ void frag_offsets(int wm, int wn, int q, int mr, int* offA, int* offB)
{
    #pragma unroll
    for (int mt = 0; mt < 8; mt++) {
        int row = wm * 128 + mt * 16 + mr;
        offA[mt] = row * 32 + ((q ^ ((row >> 1) & 3)) * 8);
    }
    #pragma unroll
    for (int nt = 0; nt < 4; nt++) {
        int row = wn * 64 + nt * 16 + mr;
        offB[nt] = row * 32 + ((q ^ ((row >> 1) & 3)) * 8);
    }
}

// ---------------- generic 256^2 GEMM (used for h2) ----------------
template<bool CBF, bool CT, bool BIAS, bool RELU>
__global__ __launch_bounds__(512, 2) void gemm256(
    const unsigned short* __restrict__ A, const unsigned short* __restrict__ B,
    void* __restrict__ Cv, const float* __restrict__ bias,
    int K, int lda, int ldb, int ldc)
{
    __shared__ __align__(16) unsigned short LDS[65536];
    unsigned short* lp = &LDS[0];
    const int tid  = threadIdx.x;
    const int lane = tid & 63, wave = tid >> 6;
    const int wm = wave >> 2, wn = wave & 3;
    int bx, by;
    xcd_remap(gridDim.x, bx, by);
    const int m0 = by * 256, n0 = bx * 256;
    const int NT = K >> 6;
    const int q = lane >> 4, mr = lane & 15;

    const int r0 = wave * 16 + (lane >> 2);
    const int r1 = r0 + 128;
    const int c0 = ((lane & 3) ^ ((r0 >> 1) & 3)) * 8;
    const int c1 = ((lane & 3) ^ ((r1 >> 1) & 3)) * 8;
    const unsigned short* Ag0 = A + (long)(m0 + r0) * lda + c0;
    const unsigned short* Ag1 = A + (long)(m0 + r1) * lda + c1;
    const unsigned short* Bg0 = B + (long)(n0 + r0) * ldb + c0;
    const unsigned short* Bg1 = B + (long)(n0 + r1) * ldb + c1;
    const int wofs = wave * 512;

    int offA[8], offB[4];
    frag_offsets(wm, wn, q, mr, offA, offB);

    floatx4 acc[8][4];
    #pragma unroll
    for (int mt = 0; mt < 8; mt++)
        #pragma unroll
        for (int nt = 0; nt < 4; nt++) acc[mt][nt] = (floatx4){0.f, 0.f, 0.f, 0.f};

    gemm256_loop(lp, Ag0, Ag1, Bg0, Bg1, NT, wofs, offA, offB, acc);

    float* Cf = (float*)Cv;
    unsigned short* Cb = (unsigned short*)Cv;
    #pragma unroll
    for (int mt = 0; mt < 8; mt++) {
        #pragma unroll
        for (int nt = 0; nt < 4; nt++) {
            int col = n0 + wn * 64 + nt * 16 + mr;
            float bv = BIAS ? bias[col] : 0.f;
            #pragma unroll
            for (int rg = 0; rg < 4; rg++) {
                int row = m0 + wm * 128 + mt * 16 + q * 4 + rg;
                float v = acc[mt][nt][rg] + bv;
                if (RELU) v = fmaxf(v, 0.f);
                if (CT) {
                    Cb[(long)(row >> 8) * 131072 + (long)col * 256 + (row & 255)] = f2b(v);
                } else {
                    long ci = (long)row * ldc + col;
                    if (CBF) Cb[ci] = f2b(v);
                    else     Cf[ci] = v;
                }
            }
        }
    }
}

// ---------------- RGCN 256^2: both speaker segments + root in ONE dispatch per chunk -----------
__global__ __launch_bounds__(512, 2) void rgcn256(
    const unsigned short* __restrict__ A, const unsigned short* __restrict__ B,
    unsigned short* __restrict__ C, const int* __restrict__ idx,
    const int* __restrict__ cntp)
{
    const int cnt0 = *cntp;
    const int t0 = (cnt0 + 255) >> 8;
    const int M1 = CH - cnt0;
    const int t1 = (M1 + 255) >> 8;
    int x, ty;
    xcd_remap(gridDim.x, x, ty);
    int sblk, m0, M, off;
    if (ty < t0)           { sblk = 0; m0 = ty << 8;        M = cnt0; off = 0; }
    else if (ty < t0 + t1) { sblk = 1; m0 = (ty - t0) << 8; M = M1;   off = cnt0; }
    else return;

    const int brow = ((x < 8) ? sblk * 2048 : 2048) + x * 256;   // B row base in WrelT (root at 4096+)

    __shared__ __align__(16) unsigned short LDS[65536];
    unsigned short* lp = &LDS[0];
    const int tid  = threadIdx.x;
    const int lane = tid & 63, wave = tid >> 6;
    const int wm = wave >> 2, wn = wave & 3;
    const int q = lane >> 4, mr = lane & 15;

    const int r0 = wave * 16 + (lane >> 2);
    const int r1 = r0 + 128;
    const int c0 = ((lane & 3) ^ ((r0 >> 1) & 3)) * 8;
    const int c1 = ((lane & 3) ^ ((r1 >> 1) & 3)) * 8;
    const int gr0 = idx[off + min(m0 + r0, M - 1)];
    const int gr1 = idx[off + min(m0 + r1, M - 1)];
    const unsigned short* Ag0 = A + (long)gr0 * DHc + c0;
    const unsigned short* Ag1 = A + (long)gr1 * DHc + c1;
    const unsigned short* Bg0 = B + (long)(brow + r0) * 1024 + c0;
    const unsigned short* Bg1 = B + (long)(brow + r1) * 1024 + c1;
    const int wofs = wave * 512;

    int offA[8], offB[4];
    frag_offsets(wm, wn, q, mr, offA, offB);

    floatx4 acc[8][4];
    #pragma unroll
    for (int mt = 0; mt < 8; mt++)
        #pragma unroll
        for (int nt = 0; nt < 4; nt++) acc[mt][nt] = (floatx4){0.f, 0.f, 0.f, 0.f};

    gemm256_loop(lp, Ag0, Ag1, Bg0, Bg1, 16 /*K=1024*/, wofs, offA, offB, acc);

    #pragma unroll
    for (int mt = 0; mt < 8; mt++) {
        int rowb = m0 + wm * 128 + mt * 16 + q * 4;
        int cr[4];
        #pragma unroll
        for (int rg = 0; rg < 4; rg++) cr[rg] = idx[off + min(rowb + rg, M - 1)];
        #pragma unroll
        for (int nt = 0; nt < 4; nt++) {
            int col = x * 256 + wn * 64 + nt * 16 + mr;
            #pragma unroll
            for (int rg = 0; rg < 4; rg++)
                C[(long)cr[rg] * 2560 + col] = f2b(acc[mt][nt][rg]);
        }
    }
}

// ---------------- merged xt + emW: B = [W_matchT | W_linT] (2048 x 1536 contiguous) -------------
__global__ __launch_bounds__(512, 2) void gemm256_mw(
    const unsigned short* __restrict__ A, const unsigned short* __restrict__ B,
    unsigned short* __restrict__ xt, unsigned short* __restrict__ emWT,
    const float* __restrict__ b_match, const float* __restrict__ b_lin)
{
    __shared__ __align__(16) unsigned short LDS[65536];
    unsigned short* lp = &LDS[0];
    const int tid  = threadIdx.x;
    const int lane = tid & 63, wave = tid >> 6;
    const int wm = wave >> 2, wn = wave & 3;
    int bx, by;
    xcd_remap(gridDim.x, bx, by);
    const int m0 = by * 256, n0 = bx * 256;
    const int q = lane >> 4, mr = lane & 15;

    const int r0 = wave * 16 + (lane >> 2);
    const int r1 = r0 + 128;
    const int c0 = ((lane & 3) ^ ((r0 >> 1) & 3)) * 8;
    const int c1 = ((lane & 3) ^ ((r1 >> 1) & 3)) * 8;
    const unsigned short* Ag0 = A + (long)(m0 + r0) * DHc + c0;
    const unsigned short* Ag1 = A + (long)(m0 + r1) * DHc + c1;
    const unsigned short* Bg0 = B + (long)(n0 + r0) * 1536 + c0;
    const unsigned short* Bg1 = B + (long)(n0 + r1) * 1536 + c1;
    const int wofs = wave * 512;

    int offA[8], offB[4];
    frag_offsets(wm, wn, q, mr, offA, offB);

    floatx4 acc[8][4];
    #pragma unroll
    for (int mt = 0; mt < 8; mt++)
        #pragma unroll
        for (int nt = 0; nt < 4; nt++) acc[mt][nt] = (floatx4){0.f, 0.f, 0.f, 0.f};

    gemm256_loop(lp, Ag0, Ag1, Bg0, Bg1, 24 /*K=1536*/, wofs, offA, offB, acc);

    if (n0 < 1536) {
        #pragma unroll
        for (int mt = 0; mt < 8; mt++) {
            #pragma unroll
            for (int nt = 0; nt < 4; nt++) {
                int col = n0 + wn * 64 + nt * 16 + mr;
                float bv = b_match[col];
                #pragma unroll
                for (int rg = 0; rg < 4; rg++) {
                    int row = m0 + wm * 128 + mt * 16 + q * 4 + rg;
                    xt[(long)row * DHc + col] = f2b(acc[mt][nt][rg] + bv);
                }
            }
        }
    } else {
        #pragma unroll
        for (int mt = 0; mt < 8; mt++) {
            #pragma unroll
            for (int nt = 0; nt < 4; nt++) {
                int col = (n0 - 1536) + wn * 64 + nt * 16 + mr;
                float bv = b_lin[col];
                #pragma unroll
                for (int rg = 0; rg < 4; rg++) {
                    int row = m0 + wm * 128 + mt * 16 + q * 4 + rg;
                    emWT[(long)(row >> 8) * 131072 + (long)col * 256 + (row & 255)] =
                        f2b(acc[mt][nt][rg] + bv);
                }
            }
        }
    }
}

// ---------------- edge_norm: windowed softmax over k (scale node-ordered) ----------------
__global__ __launch_bounds__(256) void edge_norm_kernel(const float* __restrict__ scale,
                                                        float* __restrict__ enorm)
{
    int g = blockIdx.x * 256 + threadIdx.x;   // b*L + j
    int b = g >> 8, j = g & 255;
    int klo = max(0, j - WINc), khi = min(Lc - 1, j + WINc);
    float vals[NWc];
    float m = -1e30f;
    for (int k = klo; k <= khi; k++) {
        float v = scale[(long)((b << 8) + k) * Lc + j];
        vals[k - klo] = v;
        m = fmaxf(m, v);
    }
    float s = 0.f;
    for (int k = klo; k <= khi; k++) {
        float e = expf(vals[k - klo] - m);
        vals[k - klo] = e;
        s += e;
    }
    float inv = 1.f / s;
    for (int k = klo; k <= khi; k++)
        enorm[(long)g * NWc + (k - j + WINc)] = vals[k - klo] * inv;
}

// ---------------- RGCN aggregation (hall4 bf16 [CH][2560]: 4 dst-sel blocks + root) ----------------
__global__ __launch_bounds__(256) void rgcn_gather4(const unsigned short* __restrict__ hall4,
        const float* __restrict__ enorm, const int* __restrict__ spk,
        const float* __restrict__ b_rgcn, float* __restrict__ h1, int chunk_base)
{
    int nloc = blockIdx.x;
    int n = chunk_base + nloc;
    int b = n >> 8, k = n & 255;
    int tid = threadIdx.x;
    int spkk = spk[k * 64 + b];
    int jlo = max(0, k - WINc), jhi = min(Lc - 1, k + WINc);
    unsigned int ru = *(const unsigned int*)(hall4 + (long)nloc * 2560 + 2048 + 2 * tid);
    float a0 = bf2f((unsigned short)(ru & 0xffff)) + b_rgcn[2 * tid];
    float a1 = bf2f((unsigned short)(ru >> 16)) + b_rgcn[2 * tid + 1];
    int cb = spkk * 2;
    for (int j = jlo; j <= jhi; j++) {
        int c = cb + ((j < k) ? 0 : 1);
        float w = enorm[((long)((b << 8) + j)) * NWc + (k - j + WINc)];
        unsigned int u = *(const unsigned int*)(hall4 + ((long)(nloc - k + j)) * 2560 + c * 512 + 2 * tid);
        a0 += w * bf2f((unsigned short)(u & 0xffff));
        a1 += w * bf2f((unsigned short)(u >> 16));
    }
    *(float2*)&h1[(long)n * Hc + 2 * tid] = make_float2(a0, a1);
}

// ---------------- anh1 = bf16[ concat(window-sum(h1), h1) ]  [N][1024] ----------------
__global__ __launch_bounds__(256) void build_anh1(const float* __restrict__ h1,
                                                  unsigned short* __restrict__ anh1)
{
    int n = blockIdx.x;
    int b = n >> 8, k = n & 255;
    int tid = threadIdx.x;
    int jlo = max(0, k - WINc), jhi = min(Lc - 1, k + WINc);
    float a0 = 0.f, a1 = 0.f;
    for (int j = jlo; j <= jhi; j++) {
        const float* src = h1 + ((long)((b << 8) + j)) * Hc;
        a0 += src[tid];
        a1 += src[tid + 256];
    }
    unsigned short* dst = anh1 + (long)n * 1024;
    const float* self = h1 + (long)n * Hc;
    dst[tid]       = f2b(a0);
    dst[tid + 256] = f2b(a1);
    dst[tid + 512] = f2b(self[tid]);
    dst[tid + 768] = f2b(self[tid + 256]);
}

// ---------------- tanh + row softmax -> bf16 attention weights ----------------
__global__ __launch_bounds__(256) void tanh_softmax_rows(const float* __restrict__ S,
                                                         unsigned short* __restrict__ a)
{
    int row = blockIdx.x;
    int tid = threadIdx.x;
    __shared__ float red[256];
    float v = tanhf(S[(long)row * Lc + tid]);
    red[tid] = v; __syncthreads();
    for (int s = 128; s > 0; s >>= 1) { if (tid < s) red[tid] = fmaxf(red[tid], red[tid + s]); __syncthreads(); }
    float m = red[0]; __syncthreads();
    float e = expf(v - m);
    red[tid] = e; __syncthreads();
    for (int s = 128; s > 0; s >>= 1) { if (tid < s) red[tid] += red[tid + s]; __syncthreads(); }
    float sum = red[0];
    a[(long)row * Lc + tid] = f2b(e / sum);
}

// ---------------- final classifier + log_softmax (fp32 out) ----------------
__global__ __launch_bounds__(256) void out_kernel(const unsigned short* __restrict__ hidden,
        const float* __restrict__ Wfc, const float* __restrict__ bfc, float* __restrict__ out)
{
    int tid = threadIdx.x;
    int lane = tid & 63;
    int row = blockIdx.x * 4 + (tid >> 6);
    float acc[Cc] = {};
    const unsigned short* h = hidden + (long)row * Hc;
    for (int k = lane; k < Hc; k += 64) {
        float hv = bf2f(h[k]);
        #pragma unroll
        for (int c = 0; c < Cc; c++) acc[c] += hv * Wfc[k * Cc + c];
    }
    #pragma unroll
    for (int c = 0; c < Cc; c++)
        for (int off = 32; off > 0; off >>= 1) acc[c] += __shfl_down(acc[c], off, 64);
    if (lane == 0) {
        float m = -1e30f;
        #pragma unroll
        for (int c = 0; c < Cc; c++) { acc[c] += bfc[c]; m = fmaxf(m, acc[c]); }
        float s = 0.f;
        #pragma unroll
        for (int c = 0; c < Cc; c++) s += expf(acc[c] - m);
        float lse = logf(s);
        #pragma unroll
        for (int c = 0; c < Cc; c++) out[(long)row * Cc + c] = acc[c] - m - lse;
    }
}

extern "C" void kernel_launch(void* const* d_in, const int* in_sizes, int n_in,
                              void* d_out, int out_size, void* d_ws, size_t ws_size,
                              hipStream_t stream)
{
    const float* feats   = (const float*)d_in[0];
    const float* Wscalar = (const float*)d_in[1];
    const float* W_rel   = (const float*)d_in[2];
    const float* W_root  = (const float*)d_in[3];
    const float* b_rgcn  = (const float*)d_in[4];
    const float* W_nbr   = (const float*)d_in[5];
    const float* W_self  = (const float*)d_in[6];
    const float* b_gc    = (const float*)d_in[7];
    const float* W_match = (const float*)d_in[8];
    const float* b_match = (const float*)d_in[9];
    const float* W_lin   = (const float*)d_in[10];
    const float* b_lin   = (const float*)d_in[11];
    const float* W_fc    = (const float*)d_in[12];
    const float* b_fc    = (const float*)d_in[13];
    const int*   spk     = (const int*)d_in[14];

    char* wsb = (char*)d_ws;
    unsigned short* em    = (unsigned short*)wsb;               // [0,48M) persistent
    char* RB = wsb + 50331648;                                  // time-multiplexed region (48M)
    float*          scale = (float*)RB;                         // 16M  (steps 1-2)
    unsigned short* hall4 = (unsigned short*)RB;                // 41.9M (RGCN loop)
    unsigned short* anh1  = (unsigned short*)RB;                // 32M  (anh1 -> h2)
    unsigned short* xt    = (unsigned short*)RB;                // 48M  (xt -> S)
    unsigned short* hidden= (unsigned short*)(RB + 16777216);   // 16M  (after S; xt dead)
    char* HB = wsb + 100663296;                                 // second region (32M)
    float*          h1    = (float*)HB;                         // 32M (RGCN -> build_anh1; then dead)
    float*          S     = (float*)HB;                         // 16M (step 6 -> 7; h1 dead)
    unsigned short* emWT  = (unsigned short*)(wsb + 117440512); // 16M HB[16,32M) (step 5 -> 9)
    int* idx              = (int*)(HB + 16777216);              // 64K (read before gather(c1) clobbers)
    int* cnts             = (int*)(HB + 16777216 + 65536);      // 8B  (same)
    unsigned short* WT    = (unsigned short*)(wsb + 134217728); // 17.3M persistent (dead after step 5)
    unsigned short* WscalarT = WT;
    unsigned short* WrelT    = WT + 262144;      // 4608x1024: rels 0..7 then root at 4096..4608
    unsigned short* WgcT     = WT + 4980736;     // 512x1024 (nbr k0..512 | self k512..1024)
    unsigned short* WmatchT  = WT + 5505024;     // 1536x1536, then W_lin 512x1536 contiguous
    unsigned short* ac    = (unsigned short*)(wsb + 134217728); // 8M over dead WT head (step 7 -> 9)
    float*          enorm = (float*)(wsb + 151519232);          // 1.31M

    // ---- 0. merged prep: transposes + em_x + partition (1 launch)
    prep_all<<<dim3(8448 + 16384 + 2), 256, 0, stream>>>(
        Wscalar, W_rel, W_root, W_nbr, W_self, W_match, W_lin, WT,
        spk, idx, cnts, feats, em);

    // ---- 1. scale = x @ Wscalar  [16384 x 256]
    gemm_as<false, false, false, false><<<dim3(2, 128, 1), 256, 0, stream>>>(
        em, WscalarT, scale, nullptr, 1024, DHc, 1024, 256, 0, 0, 0);

    // ---- 2. windowed softmax
    edge_norm_kernel<<<dim3(64), 256, 0, stream>>>(scale, enorm);

    // ---- 3. RGCN per chunk: ONE 256^2 dispatch (both speakers + root), then gather
    for (int c = 0; c < 2; c++) {
        const unsigned short* emc = em + (long)c * CH * DHc;
        rgcn256<<<dim3(10, 33, 1), 512, 0, stream>>>(
            emc, WrelT, hall4, idx + c * CH, cnts + c);
        rgcn_gather4<<<dim3(CH), 256, 0, stream>>>(hall4, enorm, spk, b_rgcn, h1, c * CH);
    }

    // ---- 4. anh1 = concat(window-sum(h1), h1); h2 -> em[:, 1024:1536)   [256^2 engine]
    build_anh1<<<dim3(Nc), 256, 0, stream>>>(h1, anh1);
    gemm256<true, false, true, false><<<dim3(2, 64, 1), 512, 0, stream>>>(
        anh1, WgcT, em + 1024, b_gc, 1024, 1024, 1024, DHc);

    // ---- 5. merged: xt = em @ W_match + b_match  AND  emWT = (em @ W_lin + b_lin)^T per conv
    gemm256_mw<<<dim3(8, 64, 1), 512, 0, stream>>>(
        em, WmatchT, xt, emWT, b_match, b_lin);

    // ---- 6. S_b = xt_b @ em_b^T  (z = 64 convs)
    gemm_as<false, false, false, false><<<dim3(2, 2, 64), 256, 0, stream>>>(
        xt, em, S, nullptr, DHc, DHc, DHc, 256, 393216, 393216, 65536);

    // ---- 7. a = softmax(tanh(S))
    tanh_softmax_rows<<<dim3(Nc), 256, 0, stream>>>(S, ac);

    // ---- 9. hidden = relu(a @ emW)  (z = 64 convs, bf16 out)
    gemm_as<true, false, false, true><<<dim3(4, 2, 64), 256, 0, stream>>>(
        ac, emWT, hidden, nullptr, 256, 256, 256, 512, 65536, 131072, 131072);

    // ---- 10. logits + log_softmax
    out_kernel<<<dim3(Nc / 4), 256, 0, stream>>>(hidden, W_fc, b_fc, (float*)d_out);
}